// Round 1
// baseline (339.010 us; speedup 1.0000x reference)
//
#include <hip/hip_runtime.h>
#include <hip/hip_bf16.h>

typedef unsigned short ushort_t;
typedef __bf16 bf16x8 __attribute__((ext_vector_type(8)));
typedef float f32x4 __attribute__((ext_vector_type(4)));

typedef unsigned int u32;
typedef u32 __attribute__((address_space(1))) global_u32;
typedef u32 __attribute__((address_space(3))) lds_u32;

#define D_ 1024
#define L_ 2048
#define B_ 2
#define H_ 16
#define DH_ 64
#define FF_ 2048
#define ADA_ 6144
#define BHL_ (B_ * H_ * L_)

#define MFMA __builtin_amdgcn_mfma_f32_16x16x32_bf16

__device__ __forceinline__ ushort_t f2bf(float f) {
    union { float f; u32 u; } v; v.f = f;
    u32 r = v.u + 0x7fffu + ((v.u >> 16) & 1u);
    return (ushort_t)(r >> 16);
}

// packed 2xf32 -> 2xbf16 (v_cvt_pk_bf16_f32)
__device__ __forceinline__ u32 pk_bf16(float a, float b) {
    float2 f; f.x = a; f.y = b;
    __hip_bfloat162 t = __float22bfloat162_rn(f);
    union { __hip_bfloat162 b2; u32 u; } v; v.b2 = t; return v.u;
}

__device__ __forceinline__ void llds16(const ushort_t* src, ushort_t* dst) {
    __builtin_amdgcn_global_load_lds((global_u32*)src, (lds_u32*)dst, 16, 0, 0);
}

// ------- fused weight transpose+convert: all 6 weights, one dispatch ---------
__global__ void transpose_w_all(
    const float* __restrict__ Wq, const float* __restrict__ Wk,
    const float* __restrict__ Wv, const float* __restrict__ Wo,
    const float* __restrict__ W1, const float* __restrict__ W2,
    ushort_t* __restrict__ Wqkv, ushort_t* __restrict__ Wo_t,
    ushort_t* __restrict__ W1_t, ushort_t* __restrict__ W2_t) {
    __shared__ float tile[64][65];
    int id = blockIdx.x;
    const float* W; ushort_t* Wt; int K, N, ntx, lid;
    if (id < 1024) {
        int which = id >> 8; lid = id & 255; K = 1024; N = 1024; ntx = 16;
        W  = which == 0 ? Wq : which == 1 ? Wk : which == 2 ? Wv : Wo;
        Wt = which == 3 ? Wo_t : Wqkv + (size_t)which * 1024 * 1024;
    } else if (id < 1536) {
        lid = id - 1024; W = W1; Wt = W1_t; K = 1024; N = 2048; ntx = 32;
    } else {
        lid = id - 1536; W = W2; Wt = W2_t; K = 2048; N = 1024; ntx = 16;
    }
    int n0 = (lid % ntx) * 64, k0 = (lid / ntx) * 64;
    int t = threadIdx.x;
    for (int p = 0; p < 4; ++p) {
        int k = p * 16 + (t >> 4), nn = (t & 15) * 4;
        float4 v = *(const float4*)(W + (size_t)(k0 + k) * N + n0 + nn);
        tile[k][nn] = v.x; tile[k][nn + 1] = v.y; tile[k][nn + 2] = v.z; tile[k][nn + 3] = v.w;
    }
    __syncthreads();
    for (int p = 0; p < 4; ++p) {
        int n = p * 16 + (t >> 4), kk = (t & 15) * 4;
        ushort4 o;
        o.x = f2bf(tile[kk][n]); o.y = f2bf(tile[kk + 1][n]);
        o.z = f2bf(tile[kk + 2][n]); o.w = f2bf(tile[kk + 3][n]);
        *(ushort4*)(Wt + (size_t)(n0 + n) * K + k0 + kk) = o;
    }
}

// ---------------- V transpose: (BH, L, DH) bf16 -> (BH, DH, L) bf16 ----------
__global__ void transpose_v(const ushort_t* __restrict__ V, ushort_t* __restrict__ Vt) {
    __shared__ ushort_t tile[64][72];
    int bh = blockIdx.y, l0 = blockIdx.x * 64;
    const ushort_t* Vb = V + ((size_t)bh * L_ + l0) * DH_;
    ushort_t* Vtb = Vt + (size_t)bh * DH_ * L_;
    int t = threadIdx.x;
    for (int p = 0; p < 2; ++p) {
        int i = p * 32 + (t >> 3), d0 = (t & 7) * 8;
        ushort4 v0 = *(const ushort4*)(Vb + (size_t)i * DH_ + d0);
        ushort4 v1 = *(const ushort4*)(Vb + (size_t)i * DH_ + d0 + 4);
        tile[d0 + 0][i] = v0.x; tile[d0 + 1][i] = v0.y; tile[d0 + 2][i] = v0.z; tile[d0 + 3][i] = v0.w;
        tile[d0 + 4][i] = v1.x; tile[d0 + 5][i] = v1.y; tile[d0 + 6][i] = v1.z; tile[d0 + 7][i] = v1.w;
    }
    __syncthreads();
    for (int p = 0; p < 2; ++p) {
        int dh = p * 32 + (t >> 3), j0 = (t & 7) * 8;
        ushort4 o0, o1;
        o0.x = tile[dh][j0 + 0]; o0.y = tile[dh][j0 + 1]; o0.z = tile[dh][j0 + 2]; o0.w = tile[dh][j0 + 3];
        o1.x = tile[dh][j0 + 4]; o1.y = tile[dh][j0 + 5]; o1.z = tile[dh][j0 + 6]; o1.w = tile[dh][j0 + 7];
        *(ushort4*)(Vtb + (size_t)dh * L_ + l0 + j0) = o0;
        *(ushort4*)(Vtb + (size_t)dh * L_ + l0 + j0 + 4) = o1;
    }
}

// ---------------- ada = silu(c) @ Wada + bada: split-k GEMV ------------------
__global__ void ada_gemv(const float* __restrict__ c, const float* __restrict__ Wada,
                         float* __restrict__ partial) {
    int ks = blockIdx.y;
    int j = blockIdx.x * 256 + threadIdx.x;
    __shared__ float s0[64], s1[64];
    if (threadIdx.x < 64) {
        float v = c[ks * 64 + threadIdx.x];
        s0[threadIdx.x] = v / (1.f + __expf(-v));
        v = c[D_ + ks * 64 + threadIdx.x];
        s1[threadIdx.x] = v / (1.f + __expf(-v));
    }
    __syncthreads();
    float a0 = 0.f, a1 = 0.f;
#pragma unroll 8
    for (int d = 0; d < 64; ++d) {
        float w = Wada[(size_t)(ks * 64 + d) * ADA_ + j];
        a0 = fmaf(s0[d], w, a0);
        a1 = fmaf(s1[d], w, a1);
    }
    partial[(size_t)(ks * 2 + 0) * ADA_ + j] = a0;
    partial[(size_t)(ks * 2 + 1) * ADA_ + j] = a1;
}

__global__ void ada_reduce(const float* __restrict__ partial,
                           const float* __restrict__ bada, float* __restrict__ ada) {
    int j = blockIdx.x * 256 + threadIdx.x;
    float a0 = bada[j], a1 = bada[j];
#pragma unroll
    for (int ks = 0; ks < 16; ++ks) {
        a0 += partial[(size_t)(ks * 2 + 0) * ADA_ + j];
        a1 += partial[(size_t)(ks * 2 + 1) * ADA_ + j];
    }
    ada[j] = a0;
    ada[ADA_ + j] = a1;
}

// ---------------- LayerNorm + modulation -> bf16 -----------------------------
__global__ void ln_mod(const float* __restrict__ x, const float* __restrict__ ada,
                       int so, int co, ushort_t* __restrict__ out) {
    int row = blockIdx.x;
    int b = row >> 11;
    float4 v = ((const float4*)(x + (size_t)row * D_))[threadIdx.x];
    float sum = v.x + v.y + v.z + v.w;
    float sq = v.x * v.x + v.y * v.y + v.z * v.z + v.w * v.w;
    for (int off = 32; off; off >>= 1) { sum += __shfl_down(sum, off); sq += __shfl_down(sq, off); }
    __shared__ float sa[4], sb[4];
    int wave = threadIdx.x >> 6, lane = threadIdx.x & 63;
    if (lane == 0) { sa[wave] = sum; sb[wave] = sq; }
    __syncthreads();
    sum = sa[0] + sa[1] + sa[2] + sa[3];
    sq = sb[0] + sb[1] + sb[2] + sb[3];
    float mean = sum * (1.f / 1024.f);
    float var = sq * (1.f / 1024.f) - mean * mean;
    float rstd = rsqrtf(var + 1e-6f);
    int d = threadIdx.x * 4;
    const float* shf = ada + (size_t)b * ADA_ + so;
    const float* scf = ada + (size_t)b * ADA_ + co;
    uint2 ov;
    ov.x = pk_bf16((v.x - mean) * rstd * (1.f + scf[d + 0]) + shf[d + 0],
                   (v.y - mean) * rstd * (1.f + scf[d + 1]) + shf[d + 1]);
    ov.y = pk_bf16((v.z - mean) * rstd * (1.f + scf[d + 2]) + shf[d + 2],
                   (v.w - mean) * rstd * (1.f + scf[d + 3]) + shf[d + 3]);
    *(uint2*)(out + (size_t)row * D_ + d) = ov;
}

// ---------------- GEMM epilogues ---------------------------------------------
struct EpiArgs {
    const float* bias0; const float* bias1; const float* bias2;
    ushort_t* o0; ushort_t* o1; ushort_t* o2;
    const float* resid; const float* gate;
    float* fout;
};

template <int EPI>
__device__ __forceinline__ void epi_store(float v, int m, int n, int N, const EpiArgs& e) {
    if (EPI == 0) {  // QKV -> (B,H,L,DH) bf16; Q pre-scaled by log2(e)/8
        int which = n >> 10, cc = n & 1023;
        const float* bias = which == 0 ? e.bias0 : which == 1 ? e.bias1 : e.bias2;
        ushort_t* ob = which == 0 ? e.o0 : which == 1 ? e.o1 : e.o2;
        v += bias[cc];
        if (which == 0) v *= 0.18033688f;  // (1/8) * log2(e): softmax uses exp2
        int b = m >> 11, l = m & 2047, h = cc >> 6, dh = cc & 63;
        ob[(((size_t)(b * H_ + h) * L_) + l) * DH_ + dh] = f2bf(v);
    } else if (EPI == 1) {  // bias + exact GELU -> bf16
        v += e.bias0[n];
        v = 0.5f * v * (1.f + erff(v * 0.70710678118f));
        e.o0[(size_t)m * N + n] = f2bf(v);
    } else {  // residual + gate -> fp32
        int b = m >> 11;
        e.fout[(size_t)m * N + n] =
            e.resid[(size_t)m * N + n] + e.gate[(size_t)b * ADA_ + n] * (v + e.bias0[n]);
    }
}

template <int EPI>
__device__ __forceinline__ void st4(const f32x4& cc, int mb, int n, int N, const EpiArgs& e) {
#pragma unroll
    for (int r = 0; r < 4; ++r) epi_store<EPI>(cc[r], mb + r, n, N, e);
}

// ---------------- GEMM 128x128 tile (QKV) ------------------------------------
template <int EPI>
__global__ __launch_bounds__(256, 2) void gemm_bt(
    const ushort_t* __restrict__ A, const ushort_t* __restrict__ Bt,
    int M, int N, int K, EpiArgs e) {
    __shared__ ushort_t As[128 * 64];
    __shared__ ushort_t Bs[128 * 64];
    int m0 = blockIdx.x * 128, n0 = blockIdx.y * 128;
    int tid = threadIdx.x, wave = tid >> 6, lane = tid & 63;
    int quad = lane >> 4, lc = lane & 15;
    int wm = (wave & 1) * 64, wn = (wave >> 1) * 64;
    int srow = lane >> 3, sg = lane & 7;
    int sw = lc & 7;

    const ushort_t* stp[8];
    ushort_t* stl[8];
#pragma unroll
    for (int i = 0; i < 8; ++i) {
        int chunk = wave * 8 + i;
        int c = chunk & 15;
        int row = c * 8 + srow;
        stp[i] = (chunk < 16 ? A + (size_t)(m0 + row) * K
                             : Bt + (size_t)(n0 + row) * K) + (sg ^ srow) * 8;
        stl[i] = (chunk < 16 ? As : Bs) + c * 512 + lane * 8;
    }

    f32x4 c00 = {}, c01 = {}, c02 = {}, c03 = {};
    f32x4 c10 = {}, c11 = {}, c12 = {}, c13 = {};
    f32x4 c20 = {}, c21 = {}, c22 = {}, c23 = {};
    f32x4 c30 = {}, c31 = {}, c32 = {}, c33 = {};

    for (int k0 = 0; k0 < K; k0 += 64) {
#pragma unroll
        for (int i = 0; i < 8; ++i) { llds16(stp[i], stl[i]); stp[i] += 64; }
        __syncthreads();
#pragma unroll
        for (int kk = 0; kk < 2; ++kk) {
            int off = ((kk * 4 + quad) ^ sw) * 8;
            bf16x8 a0 = *(const bf16x8*)&As[(wm +  0 + lc) * 64 + off];
            bf16x8 a1 = *(const bf16x8*)&As[(wm + 16 + lc) * 64 + off];
            bf16x8 a2 = *(const bf16x8*)&As[(wm + 32 + lc) * 64 + off];
            bf16x8 a3 = *(const bf16x8*)&As[(wm + 48 + lc) * 64 + off];
            bf16x8 b0 = *(const bf16x8*)&Bs[(wn +  0 + lc) * 64 + off];
            bf16x8 b1 = *(const bf16x8*)&Bs[(wn + 16 + lc) * 64 + off];
            bf16x8 b2 = *(const bf16x8*)&Bs[(wn + 32 + lc) * 64 + off];
            bf16x8 b3 = *(const bf16x8*)&Bs[(wn + 48 + lc) * 64 + off];
            c00 = MFMA(a0, b0, c00, 0, 0, 0); c01 = MFMA(a0, b1, c01, 0, 0, 0);
            c02 = MFMA(a0, b2, c02, 0, 0, 0); c03 = MFMA(a0, b3, c03, 0, 0, 0);
            c10 = MFMA(a1, b0, c10, 0, 0, 0); c11 = MFMA(a1, b1, c11, 0, 0, 0);
            c12 = MFMA(a1, b2, c12, 0, 0, 0); c13 = MFMA(a1, b3, c13, 0, 0, 0);
            c20 = MFMA(a2, b0, c20, 0, 0, 0); c21 = MFMA(a2, b1, c21, 0, 0, 0);
            c22 = MFMA(a2, b2, c22, 0, 0, 0); c23 = MFMA(a2, b3, c23, 0, 0, 0);
            c30 = MFMA(a3, b0, c30, 0, 0, 0); c31 = MFMA(a3, b1, c31, 0, 0, 0);
            c32 = MFMA(a3, b2, c32, 0, 0, 0); c33 = MFMA(a3, b3, c33, 0, 0, 0);
        }
        __syncthreads();
    }

    int mb = m0 + wm + quad * 4, nb = n0 + wn + lc;
    st4<EPI>(c00, mb +  0, nb +  0, N, e); st4<EPI>(c01, mb +  0, nb + 16, N, e);
    st4<EPI>(c02, mb +  0, nb + 32, N, e); st4<EPI>(c03, mb +  0, nb + 48, N, e);
    st4<EPI>(c10, mb + 16, nb +  0, N, e); st4<EPI>(c11, mb + 16, nb + 16, N, e);
    st4<EPI>(c12, mb + 16, nb + 32, N, e); st4<EPI>(c13, mb + 16, nb + 48, N, e);
    st4<EPI>(c20, mb + 32, nb +  0, N, e); st4<EPI>(c21, mb + 32, nb + 16, N, e);
    st4<EPI>(c22, mb + 32, nb + 32, N, e); st4<EPI>(c23, mb + 32, nb + 48, N, e);
    st4<EPI>(c30, mb + 48, nb +  0, N, e); st4<EPI>(c31, mb + 48, nb + 16, N, e);
    st4<EPI>(c32, mb + 48, nb + 32, N, e); st4<EPI>(c33, mb + 48, nb + 48, N, e);
}

// ---------------- GEMM 64x128 tile: small-N GEMMs need more blocks -----------
template <int EPI>
__global__ __launch_bounds__(256, 2) void gemm_bt64(
    const ushort_t* __restrict__ A, const ushort_t* __restrict__ Bt,
    int M, int N, int K, EpiArgs e) {
    __shared__ ushort_t As[64 * 64];    // 8 KB
    __shared__ ushort_t Bs[128 * 64];   // 16 KB
    int m0 = blockIdx.x * 64, n0 = blockIdx.y * 128;
    int tid = threadIdx.x, wave = tid >> 6, lane = tid & 63;
    int quad = lane >> 4, lc = lane & 15;
    int wn = wave * 32;
    int srow = lane >> 3, sg = lane & 7;
    int sw = lc & 7;

    const ushort_t* stp[6];
    ushort_t* stl[6];
#pragma unroll
    for (int i = 0; i < 6; ++i) {
        int chunk = wave * 6 + i;
        if (chunk < 8) {
            int row = chunk * 8 + srow;
            stp[i] = A + (size_t)(m0 + row) * K + (sg ^ srow) * 8;
            stl[i] = &As[chunk * 512 + lane * 8];
        } else {
            int c = chunk - 8;
            int row = c * 8 + srow;
            stp[i] = Bt + (size_t)(n0 + row) * K + (sg ^ srow) * 8;
            stl[i] = &Bs[c * 512 + lane * 8];
        }
    }

    f32x4 c00 = {}, c01 = {};
    f32x4 c10 = {}, c11 = {};
    f32x4 c20 = {}, c21 = {};
    f32x4 c30 = {}, c31 = {};

    for (int k0 = 0; k0 < K; k0 += 64) {
#pragma unroll
        for (int i = 0; i < 6; ++i) { llds16(stp[i], stl[i]); stp[i] += 64; }
        __syncthreads();
#pragma unroll
        for (int kk = 0; kk < 2; ++kk) {
            int off = ((kk * 4 + quad) ^ sw) * 8;
            bf16x8 a0 = *(const bf16x8*)&As[( 0 + lc) * 64 + off];
            bf16x8 a1 = *(const bf16x8*)&As[(16 + lc) * 64 + off];
            bf16x8 a2 = *(const bf16x8*)&As[(32 + lc) * 64 + off];
            bf16x8 a3 = *(const bf16x8*)&As[(48 + lc) * 64 + off];
            bf16x8 b0 = *(const bf16x8*)&Bs[(wn +  0 + lc) * 64 + off];
            bf16x8 b1 = *(const bf16x8*)&Bs[(wn + 16 + lc) * 64 + off];
            c00 = MFMA(a0, b0, c00, 0, 0, 0); c01 = MFMA(a0, b1, c01, 0, 0, 0);
            c10 = MFMA(a1, b0, c10, 0, 0, 0); c11 = MFMA(a1, b1, c11, 0, 0, 0);
            c20 = MFMA(a2, b0, c20, 0, 0, 0); c21 = MFMA(a2, b1, c21, 0, 0, 0);
            c30 = MFMA(a3, b0, c30, 0, 0, 0); c31 = MFMA(a3, b1, c31, 0, 0, 0);
        }
        __syncthreads();
    }

    int mb = m0 + quad * 4, nb = n0 + wn + lc;
    st4<EPI>(c00, mb +  0, nb + 0, N, e); st4<EPI>(c01, mb +  0, nb + 16, N, e);
    st4<EPI>(c10, mb + 16, nb + 0, N, e); st4<EPI>(c11, mb + 16, nb + 16, N, e);
    st4<EPI>(c20, mb + 32, nb + 0, N, e); st4<EPI>(c21, mb + 32, nb + 16, N, e);
    st4<EPI>(c30, mb + 48, nb + 0, N, e); st4<EPI>(c31, mb + 48, nb + 16, N, e);
}

// ---------------- flash attention v10: KV-split-4 + dbuf prefetch ------------
// grid 2048: bits[4:0] bh (XCD-spread), [6:5] kv-quarter, [10:7] q-tile.
// Each block: 128 q-rows x 512 kv (4 tiles). v10 vs v9: double-buffered K/V
// (LDS 48->80 KB, 2 blocks/CU); tile t+1's global_load_lds issued before
// compute(t); raw s_barrier + counted s_waitcnt vmcnt(8) keeps the 8 prefetch
// loads/lane in flight across the barrier (never drains to 0 in-loop);
// s_setprio(1) around MFMA clusters (QK^T, PV).
__global__ __launch_bounds__(256, 2) void attn(
    const ushort_t* __restrict__ Q, const ushort_t* __restrict__ Kx,
    const ushort_t* __restrict__ Vt,
    ushort_t* __restrict__ Op0, ushort_t* __restrict__ Op1,
    ushort_t* __restrict__ Op2, ushort_t* __restrict__ Op3,
    float* __restrict__ lsum) {
    __shared__ ushort_t Ks[2][128 * 64];  // 2 x 16 KB
    __shared__ ushort_t Vs[2][64 * 128];  // 2 x 16 KB
    __shared__ ushort_t Ps[4 * 16 * 128]; // 16 KB, per-wave 16 x 128 XOR-swizzled
    int id = blockIdx.x;
    int bh = ((id & 7) << 2) + ((id >> 3) & 3);  // 4 bh per XCD class
    int quarter = (id >> 5) & 3;                 // kv quarter (512 kv)
    int qt = id >> 7;                            // 16 q-tiles of 128 rows
    const ushort_t* Qg = Q + ((size_t)bh * L_ + qt * 128) * DH_;
    const ushort_t* Kg = Kx + (size_t)bh * L_ * DH_;
    const ushort_t* Vg = Vt + (size_t)bh * DH_ * L_;
    int tid = threadIdx.x, wave = tid >> 6, lane = tid & 63;
    int quad = lane >> 4, lc = lane & 15;
    int sw = lc & 7;
    int srow = lane >> 3, sg = lane & 7;

    // hoisted staging: waves 0,1 stage K (chunks 0..15); waves 2,3 stage V
    const ushort_t* stp[8];
    ushort_t* stl[8];
    int stinc;
    if (wave < 2) {
        stinc = 128 * DH_;
#pragma unroll
        for (int i = 0; i < 8; ++i) {
            int chunk = wave * 8 + i;
            int row = chunk * 8 + srow;    // row&7 == srow
            stp[i] = Kg + (size_t)(quarter * 512 + row) * DH_ + (sg ^ srow) * 8;
            stl[i] = &Ks[0][chunk * 512 + lane * 8];
        }
    } else {
        stinc = 128;
#pragma unroll
        for (int i = 0; i < 8; ++i) {
            int c2 = (wave - 2) * 8 + i;
            int row = c2 * 4 + (lane >> 4);
            int g = (lane & 15) ^ (row & 15);
            stp[i] = Vg + (size_t)row * L_ + quarter * 512 + g * 8;
            stl[i] = &Vs[0][c2 * 512 + lane * 8];
        }
    }

    // prologue: stage tile 0 into buf 0 (stays in flight under Q loads)
#pragma unroll
    for (int i = 0; i < 8; ++i) { llds16(stp[i], stl[i]); stp[i] += stinc; }

    // Q fragments straight from global (block-private, read once)
    const ushort_t* qp = Qg + (size_t)(wave * 32 + lc) * DH_ + quad * 8;
    bf16x8 q00 = *(const bf16x8*)(qp);                  // pass0 kk0
    bf16x8 q01 = *(const bf16x8*)(qp + 32);             // pass0 kk1
    bf16x8 q10 = *(const bf16x8*)(qp + 16 * DH_);       // pass1 kk0
    bf16x8 q11 = *(const bf16x8*)(qp + 16 * DH_ + 32);  // pass1 kk1

    f32x4 o00 = {}, o01 = {}, o02 = {}, o03 = {};
    f32x4 o10 = {}, o11 = {}, o12 = {}, o13 = {};
    float lrow0 = 0.f, lrow1 = 0.f;
    ushort_t* Pw = &Ps[wave * 16 * 128];

    for (int t = 0; t < 4; ++t) {
        // issue tile t+1 into the other buffer, then wait only for tile t's
        // loads: 8 newest per lane (the prefetch) stay outstanding
        if (t < 3) {
            int nbuf = (t + 1) & 1;
#pragma unroll
            for (int i = 0; i < 8; ++i) { llds16(stp[i], stl[i] + nbuf * 8192); stp[i] += stinc; }
            asm volatile("s_waitcnt vmcnt(8)" ::: "memory");
        } else {
            asm volatile("s_waitcnt vmcnt(0)" ::: "memory");
        }
        __builtin_amdgcn_s_barrier();
        asm volatile("" ::: "memory");
        const ushort_t* Ksb = &Ks[t & 1][0];
        const ushort_t* Vsb = &Vs[t & 1][0];

        // S^T = K Q^T: C[kv][q], lane holds q=lc, kv = ni*16 + quad*4 + r
        f32x4 s[2][8];
        __builtin_amdgcn_s_setprio(1);
#pragma unroll
        for (int kk = 0; kk < 2; ++kk) {
            int off = ((kk * 4 + quad) ^ sw) * 8;
            bf16x8 aq0 = kk == 0 ? q00 : q01;
            bf16x8 aq1 = kk == 0 ? q10 : q11;
#pragma unroll
            for (int ni = 0; ni < 8; ++ni) {
                bf16x8 bk = *(const bf16x8*)&Ksb[(ni * 16 + lc) * 64 + off];
                if (kk == 0) {
                    f32x4 z = {0.f, 0.f, 0.f, 0.f};
                    s[0][ni] = MFMA(bk, aq0, z, 0, 0, 0);
                    s[1][ni] = MFMA(bk, aq1, z, 0, 0, 0);
                } else {
                    s[0][ni] = MFMA(bk, aq0, s[0][ni], 0, 0, 0);
                    s[1][ni] = MFMA(bk, aq1, s[1][ni], 0, 0, 0);
                }
            }
        }
        __builtin_amdgcn_s_setprio(0);

        // two 16-q passes: p = exp2(s), row-sum, XOR-swizzled P store, PV
#pragma unroll
        for (int pi = 0; pi < 2; ++pi) {
            float acc = 0.f;
#pragma unroll
            for (int ni = 0; ni < 8; ++ni) {
                float p0 = __builtin_amdgcn_exp2f(s[pi][ni][0]);
                float p1 = __builtin_amdgcn_exp2f(s[pi][ni][1]);
                float p2 = __builtin_amdgcn_exp2f(s[pi][ni][2]);
                float p3 = __builtin_amdgcn_exp2f(s[pi][ni][3]);
                acc += (p0 + p1) + (p2 + p3);
                uint2 pk; pk.x = pk_bf16(p0, p1); pk.y = pk_bf16(p2, p3);
                int cg = ni * 2 + (quad >> 1);           // 16B group of kv
                *(uint2*)&Pw[lc * 128 + ((cg ^ lc) & 15) * 8 + (quad & 1) * 4] = pk;
            }
            acc += __shfl_xor(acc, 16);
            acc += __shfl_xor(acc, 32);
            if (pi == 0) lrow0 += acc; else lrow1 += acc;

            // O[pi] += P V  (Pw wave-private; in-wave LDS ordering)
            __builtin_amdgcn_s_setprio(1);
#pragma unroll
            for (int kk = 0; kk < 4; ++kk) {
                int gq = kk * 4 + quad;
                bf16x8 ap  = *(const bf16x8*)&Pw[lc * 128 + ((gq ^ lc) & 15) * 8];
                bf16x8 bv0 = *(const bf16x8*)&Vsb[( 0 + lc) * 128 + ((gq ^ lc) * 8)];
                bf16x8 bv1 = *(const bf16x8*)&Vsb[(16 + lc) * 128 + ((gq ^ lc) * 8)];
                bf16x8 bv2 = *(const bf16x8*)&Vsb[(32 + lc) * 128 + ((gq ^ lc) * 8)];
                bf16x8 bv3 = *(const bf16x8*)&Vsb[(48 + lc) * 128 + ((gq ^ lc) * 8)];
                if (pi == 0) {
                    o00 = MFMA(ap, bv0, o00, 0, 0, 0); o01 = MFMA(ap, bv1, o01, 0, 0, 0);
                    o02 = MFMA(ap, bv2, o02, 0, 0, 0); o03 = MFMA(ap, bv3, o03, 0, 0, 0);
                } else {
                    o10 = MFMA(ap, bv0, o10, 0, 0, 0); o11 = MFMA(ap, bv1, o11, 0, 0, 0);
                    o12 = MFMA(ap, bv2, o12, 0, 0, 0); o13 = MFMA(ap, bv3, o13, 0, 0, 0);
                }
            }
            __builtin_amdgcn_s_setprio(0);
        }
        // all waves done reading buf (t&1) before it is restaged at t+2
        asm volatile("" ::: "memory");
        __builtin_amdgcn_s_barrier();
    }

    // write unnormalized partial O (bf16); PV C-layout rows = quad*4+r
    ushort_t* Op = quarter == 0 ? Op0 : quarter == 1 ? Op1 : quarter == 2 ? Op2 : Op3;
#pragma unroll
    for (int pi = 0; pi < 2; ++pi) {
#pragma unroll
        for (int nio = 0; nio < 4; ++nio) {
            const f32x4& ov = pi == 0 ? (nio == 0 ? o00 : nio == 1 ? o01 : nio == 2 ? o02 : o03)
                                      : (nio == 0 ? o10 : nio == 1 ? o11 : nio == 2 ? o12 : o13);
#pragma unroll
            for (int r = 0; r < 4; ++r) {
                int row = qt * 128 + wave * 32 + pi * 16 + quad * 4 + r;
                Op[((size_t)bh * L_ + row) * DH_ + nio * 16 + lc] = f2bf(ov[r]);
            }
        }
    }
    // l per q-row (lane lc holds row q=lc of each pass; all quads agree)
    if (quad == 0) {
        int base = qt * 128 + wave * 32;
        lsum[(size_t)quarter * BHL_ + (size_t)bh * L_ + base + lc] = lrow0;
        lsum[(size_t)quarter * BHL_ + (size_t)bh * L_ + base + 16 + lc] = lrow1;
    }
}

// ---------------- merge four KV-quarter partials -> final O bf16 -------------
__global__ void attn_merge(const ushort_t* __restrict__ Op0,
                           const ushort_t* __restrict__ Op1,
                           const ushort_t* __restrict__ Op2,
                           const ushort_t* __restrict__ Op3,
                           const float* __restrict__ lsum,
                           ushort_t* __restrict__ O) {
    int gid = blockIdx.x * 256 + threadIdx.x;   // 524288 total
    int row = gid >> 3, j = gid & 7;
    float inv = 1.f / (lsum[row] + lsum[BHL_ + row] +
                       lsum[2 * BHL_ + row] + lsum[3 * BHL_ + row]);
    bf16x8 v0 = *(const bf16x8*)(Op0 + (size_t)row * DH_ + j * 8);
    bf16x8 v1 = *(const bf16x8*)(Op1 + (size_t)row * DH_ + j * 8);
    bf16x8 v2 = *(const bf16x8*)(Op2 + (size_t)row * DH_ + j * 8);
    bf16x8 v3 = *(const bf16x8*)(Op3 + (size_t)row * DH_ + j * 8);
    uint4 o;
    float r0, r1;
#pragma unroll
    for (int k = 0; k < 4; ++k) {
        r0 = ((float)v0[2 * k] + (float)v1[2 * k] + (float)v2[2 * k] + (float)v3[2 * k]) * inv;
        r1 = ((float)v0[2 * k + 1] + (float)v1[2 * k + 1] + (float)v2[2 * k + 1] + (float)v3[2 * k + 1]) * inv;
        ((u32*)&o)[k] = pk_bf16(r0, r1);
    }
    *(uint4*)(O + (size_t)row * DH_ + j * 8) = o;
}

// -----------------------------------------------------------------------------
extern "C" void kernel_launch(void* const* d_in, const int* in_sizes, int n_in,
                              void* d_out, int out_size, void* d_ws, size_t ws_size,
                              hipStream_t stream) {
    (void)in_sizes; (void)n_in; (void)out_size; (void)ws_size;
    const float* x    = (const float*)d_in[0];
    const float* c    = (const float*)d_in[1];
    const float* Wq   = (const float*)d_in[2];
    const float* bq   = (const float*)d_in[3];
    const float* Wk   = (const float*)d_in[4];
    const float* bk   = (const float*)d_in[5];
    const float* Wv   = (const float*)d_in[6];
    const float* bv   = (const float*)d_in[7];
    const float* Wo   = (const float*)d_in[8];
    const float* bo   = (const float*)d_in[9];
    const float* W1   = (const float*)d_in[10];
    const float* b1   = (const float*)d_in[11];
    const float* W2   = (const float*)d_in[12];
    const float* b2   = (const float*)d_in[13];
    const float* Wada = (const float*)d_in[14];
    const float* bada = (const float*)d_in[15];

    char* w = (char*)d_ws;
    float*    ada  = (float*)(w + 0);                     // 49152 B
    ushort_t* Wqkv = (ushort_t*)(w + 49152);              // 6 MiB (lsum after QKV gemm)
    ushort_t* Wo_t = (ushort_t*)(w + 6340608);            // 2 MiB
    ushort_t* W1_t = (ushort_t*)(w + 8437760);            // 4 MiB
    ushort_t* W2_t = (ushort_t*)(w + 12632064);           // 4 MiB
    ushort_t* h    = (ushort_t*)(w + 16826368);           // 8 MiB (h / partial1 / h2)
    ushort_t* Qb   = (ushort_t*)(w + 25214976);           // 8 MiB (Q, then merged O)
    ushort_t* Kb   = (ushort_t*)(w + 33603584);           // 8 MiB
    ushort_t* Vb   = (ushort_t*)(w + 41992192);           // 8 MiB (V, then partial0)
    ushort_t* Vtb  = (ushort_t*)(w + 50380800);           // 8 MiB (ada partials, then V^T)
    float*    x1   = (float*)(w + 58769408);              // 16 MiB (partials 2+3, then x1)
    ushort_t* Ob   = Qb;          // merged O overwrites Q (dead post-attn)
    ushort_t* m1   = Qb;          // MLP hidden (16 MiB = Qb+Kb, dead post O-proj)
    float*    lsb  = (float*)Wqkv;  // 1 MiB l per quarter; Wqkv dead after QKV gemm
    float*    adap = (float*)Vtb;   // 786 KB split-k partials; dead before transpose_v
    ushort_t* p2   = (ushort_t*)x1;                         // partial2 (8 MiB)
    ushort_t* p3   = (ushort_t*)((char*)x1 + 8388608);      // partial3 (8 MiB)

    const int M = B_ * L_;  // 4096

    transpose_w_all<<<2048, 256, 0, stream>>>(Wq, Wk, Wv, Wo, W1, W2,
                                              Wqkv, Wo_t, W1_t, W2_t);

    ada_gemv<<<dim3(24, 16), 256, 0, stream>>>(c, Wada, adap);
    ada_reduce<<<24, 256, 0, stream>>>(adap, bada, ada);
    ln_mod<<<M, 256, 0, stream>>>(x, ada, 0, 1024, h);

    EpiArgs e0 = {bq, bk, bv, Qb, Kb, Vb, nullptr, nullptr, nullptr};
    gemm_bt<0><<<dim3(32, 24), 256, 0, stream>>>(h, Wqkv, M, 3072, D_, e0);

    transpose_v<<<dim3(32, 32), 256, 0, stream>>>(Vb, Vtb);

    // KV-split-4 attention: partials -> Vb, h, x1-lo, x1-hi (all dead regions)
    attn<<<2048, 256, 0, stream>>>(Qb, Kb, Vtb, Vb, h, p2, p3, lsb);
    attn_merge<<<2048, 256, 0, stream>>>(Vb, h, p2, p3, lsb, Ob);

    EpiArgs e1 = {bo, nullptr, nullptr, nullptr, nullptr, nullptr, x, ada + 2048, x1};
    gemm_bt64<2><<<dim3(64, 8), 256, 0, stream>>>(Ob, Wo_t, M, D_, D_, e1);

    ln_mod<<<M, 256, 0, stream>>>(x1, ada, 3072, 4096, h);

    EpiArgs e2 = {b1, nullptr, nullptr, m1, nullptr, nullptr, nullptr, nullptr, nullptr};
    gemm_bt64<1><<<dim3(64, 16), 256, 0, stream>>>(h, W1_t, M, FF_, D_, e2);

    EpiArgs e3 = {b2, nullptr, nullptr, nullptr, nullptr, nullptr, x1, ada + 5120, (float*)d_out};
    gemm_bt64<2><<<dim3(64, 8), 256, 0, stream>>>(m1, W2_t, M, D_, FF_, e3);
}

// Round 2
// 324.298 us; speedup vs baseline: 1.0454x; 1.0454x over previous
//
#include <hip/hip_runtime.h>
#include <hip/hip_bf16.h>

typedef unsigned short ushort_t;
typedef __bf16 bf16x8 __attribute__((ext_vector_type(8)));
typedef float f32x4 __attribute__((ext_vector_type(4)));

typedef unsigned int u32;
typedef u32 __attribute__((address_space(1))) global_u32;
typedef u32 __attribute__((address_space(3))) lds_u32;

#define D_ 1024
#define L_ 2048
#define B_ 2
#define H_ 16
#define DH_ 64
#define FF_ 2048
#define ADA_ 6144
#define BHL_ (B_ * H_ * L_)

#define MFMA __builtin_amdgcn_mfma_f32_16x16x32_bf16

__device__ __forceinline__ ushort_t f2bf(float f) {
    union { float f; u32 u; } v; v.f = f;
    u32 r = v.u + 0x7fffu + ((v.u >> 16) & 1u);
    return (ushort_t)(r >> 16);
}

// packed 2xf32 -> 2xbf16 (v_cvt_pk_bf16_f32)
__device__ __forceinline__ u32 pk_bf16(float a, float b) {
    float2 f; f.x = a; f.y = b;
    __hip_bfloat162 t = __float22bfloat162_rn(f);
    union { __hip_bfloat162 b2; u32 u; } v; v.b2 = t; return v.u;
}

__device__ __forceinline__ void llds16(const ushort_t* src, ushort_t* dst) {
    __builtin_amdgcn_global_load_lds((global_u32*)src, (lds_u32*)dst, 16, 0, 0);
}

// ------- fused weight transpose+convert: all 6 weights, one dispatch ---------
__global__ void transpose_w_all(
    const float* __restrict__ Wq, const float* __restrict__ Wk,
    const float* __restrict__ Wv, const float* __restrict__ Wo,
    const float* __restrict__ W1, const float* __restrict__ W2,
    ushort_t* __restrict__ Wqkv, ushort_t* __restrict__ Wo_t,
    ushort_t* __restrict__ W1_t, ushort_t* __restrict__ W2_t) {
    __shared__ float tile[64][65];
    int id = blockIdx.x;
    const float* W; ushort_t* Wt; int K, N, ntx, lid;
    if (id < 1024) {
        int which = id >> 8; lid = id & 255; K = 1024; N = 1024; ntx = 16;
        W  = which == 0 ? Wq : which == 1 ? Wk : which == 2 ? Wv : Wo;
        Wt = which == 3 ? Wo_t : Wqkv + (size_t)which * 1024 * 1024;
    } else if (id < 1536) {
        lid = id - 1024; W = W1; Wt = W1_t; K = 1024; N = 2048; ntx = 32;
    } else {
        lid = id - 1536; W = W2; Wt = W2_t; K = 2048; N = 1024; ntx = 16;
    }
    int n0 = (lid % ntx) * 64, k0 = (lid / ntx) * 64;
    int t = threadIdx.x;
    for (int p = 0; p < 4; ++p) {
        int k = p * 16 + (t >> 4), nn = (t & 15) * 4;
        float4 v = *(const float4*)(W + (size_t)(k0 + k) * N + n0 + nn);
        tile[k][nn] = v.x; tile[k][nn + 1] = v.y; tile[k][nn + 2] = v.z; tile[k][nn + 3] = v.w;
    }
    __syncthreads();
    for (int p = 0; p < 4; ++p) {
        int n = p * 16 + (t >> 4), kk = (t & 15) * 4;
        ushort4 o;
        o.x = f2bf(tile[kk][n]); o.y = f2bf(tile[kk + 1][n]);
        o.z = f2bf(tile[kk + 2][n]); o.w = f2bf(tile[kk + 3][n]);
        *(ushort4*)(Wt + (size_t)(n0 + n) * K + k0 + kk) = o;
    }
}

// ---------------- V transpose: (BH, L, DH) bf16 -> (BH, DH, L) bf16 ----------
__global__ void transpose_v(const ushort_t* __restrict__ V, ushort_t* __restrict__ Vt) {
    __shared__ ushort_t tile[64][72];
    int bh = blockIdx.y, l0 = blockIdx.x * 64;
    const ushort_t* Vb = V + ((size_t)bh * L_ + l0) * DH_;
    ushort_t* Vtb = Vt + (size_t)bh * DH_ * L_;
    int t = threadIdx.x;
    for (int p = 0; p < 2; ++p) {
        int i = p * 32 + (t >> 3), d0 = (t & 7) * 8;
        ushort4 v0 = *(const ushort4*)(Vb + (size_t)i * DH_ + d0);
        ushort4 v1 = *(const ushort4*)(Vb + (size_t)i * DH_ + d0 + 4);
        tile[d0 + 0][i] = v0.x; tile[d0 + 1][i] = v0.y; tile[d0 + 2][i] = v0.z; tile[d0 + 3][i] = v0.w;
        tile[d0 + 4][i] = v1.x; tile[d0 + 5][i] = v1.y; tile[d0 + 6][i] = v1.z; tile[d0 + 7][i] = v1.w;
    }
    __syncthreads();
    for (int p = 0; p < 2; ++p) {
        int dh = p * 32 + (t >> 3), j0 = (t & 7) * 8;
        ushort4 o0, o1;
        o0.x = tile[dh][j0 + 0]; o0.y = tile[dh][j0 + 1]; o0.z = tile[dh][j0 + 2]; o0.w = tile[dh][j0 + 3];
        o1.x = tile[dh][j0 + 4]; o1.y = tile[dh][j0 + 5]; o1.z = tile[dh][j0 + 6]; o1.w = tile[dh][j0 + 7];
        *(ushort4*)(Vtb + (size_t)dh * L_ + l0 + j0) = o0;
        *(ushort4*)(Vtb + (size_t)dh * L_ + l0 + j0 + 4) = o1;
    }
}

// ---------------- ada = silu(c) @ Wada + bada: split-k GEMV ------------------
__global__ void ada_gemv(const float* __restrict__ c, const float* __restrict__ Wada,
                         float* __restrict__ partial) {
    int ks = blockIdx.y;
    int j = blockIdx.x * 256 + threadIdx.x;
    __shared__ float s0[64], s1[64];
    if (threadIdx.x < 64) {
        float v = c[ks * 64 + threadIdx.x];
        s0[threadIdx.x] = v / (1.f + __expf(-v));
        v = c[D_ + ks * 64 + threadIdx.x];
        s1[threadIdx.x] = v / (1.f + __expf(-v));
    }
    __syncthreads();
    float a0 = 0.f, a1 = 0.f;
#pragma unroll 8
    for (int d = 0; d < 64; ++d) {
        float w = Wada[(size_t)(ks * 64 + d) * ADA_ + j];
        a0 = fmaf(s0[d], w, a0);
        a1 = fmaf(s1[d], w, a1);
    }
    partial[(size_t)(ks * 2 + 0) * ADA_ + j] = a0;
    partial[(size_t)(ks * 2 + 1) * ADA_ + j] = a1;
}

__global__ void ada_reduce(const float* __restrict__ partial,
                           const float* __restrict__ bada, float* __restrict__ ada) {
    int j = blockIdx.x * 256 + threadIdx.x;
    float a0 = bada[j], a1 = bada[j];
#pragma unroll
    for (int ks = 0; ks < 16; ++ks) {
        a0 += partial[(size_t)(ks * 2 + 0) * ADA_ + j];
        a1 += partial[(size_t)(ks * 2 + 1) * ADA_ + j];
    }
    ada[j] = a0;
    ada[ADA_ + j] = a1;
}

// ---------------- LayerNorm + modulation -> bf16 -----------------------------
__global__ void ln_mod(const float* __restrict__ x, const float* __restrict__ ada,
                       int so, int co, ushort_t* __restrict__ out) {
    int row = blockIdx.x;
    int b = row >> 11;
    float4 v = ((const float4*)(x + (size_t)row * D_))[threadIdx.x];
    float sum = v.x + v.y + v.z + v.w;
    float sq = v.x * v.x + v.y * v.y + v.z * v.z + v.w * v.w;
    for (int off = 32; off; off >>= 1) { sum += __shfl_down(sum, off); sq += __shfl_down(sq, off); }
    __shared__ float sa[4], sb[4];
    int wave = threadIdx.x >> 6, lane = threadIdx.x & 63;
    if (lane == 0) { sa[wave] = sum; sb[wave] = sq; }
    __syncthreads();
    sum = sa[0] + sa[1] + sa[2] + sa[3];
    sq = sb[0] + sb[1] + sb[2] + sb[3];
    float mean = sum * (1.f / 1024.f);
    float var = sq * (1.f / 1024.f) - mean * mean;
    float rstd = rsqrtf(var + 1e-6f);
    int d = threadIdx.x * 4;
    const float* shf = ada + (size_t)b * ADA_ + so;
    const float* scf = ada + (size_t)b * ADA_ + co;
    uint2 ov;
    ov.x = pk_bf16((v.x - mean) * rstd * (1.f + scf[d + 0]) + shf[d + 0],
                   (v.y - mean) * rstd * (1.f + scf[d + 1]) + shf[d + 1]);
    ov.y = pk_bf16((v.z - mean) * rstd * (1.f + scf[d + 2]) + shf[d + 2],
                   (v.w - mean) * rstd * (1.f + scf[d + 3]) + shf[d + 3]);
    *(uint2*)(out + (size_t)row * D_ + d) = ov;
}

// ---------------- GEMM epilogues ---------------------------------------------
struct EpiArgs {
    const float* bias0; const float* bias1; const float* bias2;
    ushort_t* o0; ushort_t* o1; ushort_t* o2;
    const float* resid; const float* gate;
    float* fout;
};

template <int EPI>
__device__ __forceinline__ void epi_store(float v, int m, int n, int N, const EpiArgs& e) {
    if (EPI == 0) {  // QKV -> (B,H,L,DH) bf16; Q pre-scaled by log2(e)/8
        int which = n >> 10, cc = n & 1023;
        const float* bias = which == 0 ? e.bias0 : which == 1 ? e.bias1 : e.bias2;
        ushort_t* ob = which == 0 ? e.o0 : which == 1 ? e.o1 : e.o2;
        v += bias[cc];
        if (which == 0) v *= 0.18033688f;  // (1/8) * log2(e): softmax uses exp2
        int b = m >> 11, l = m & 2047, h = cc >> 6, dh = cc & 63;
        ob[(((size_t)(b * H_ + h) * L_) + l) * DH_ + dh] = f2bf(v);
    } else if (EPI == 1) {  // bias + exact GELU -> bf16
        v += e.bias0[n];
        v = 0.5f * v * (1.f + erff(v * 0.70710678118f));
        e.o0[(size_t)m * N + n] = f2bf(v);
    } else {  // residual + gate -> fp32
        int b = m >> 11;
        e.fout[(size_t)m * N + n] =
            e.resid[(size_t)m * N + n] + e.gate[(size_t)b * ADA_ + n] * (v + e.bias0[n]);
    }
}

template <int EPI>
__device__ __forceinline__ void st4(const f32x4& cc, int mb, int n, int N, const EpiArgs& e) {
#pragma unroll
    for (int r = 0; r < 4; ++r) epi_store<EPI>(cc[r], mb + r, n, N, e);
}

// ---------------- GEMM 128x128 tile (QKV) ------------------------------------
template <int EPI>
__global__ __launch_bounds__(256, 2) void gemm_bt(
    const ushort_t* __restrict__ A, const ushort_t* __restrict__ Bt,
    int M, int N, int K, EpiArgs e) {
    __shared__ ushort_t As[128 * 64];
    __shared__ ushort_t Bs[128 * 64];
    int m0 = blockIdx.x * 128, n0 = blockIdx.y * 128;
    int tid = threadIdx.x, wave = tid >> 6, lane = tid & 63;
    int quad = lane >> 4, lc = lane & 15;
    int wm = (wave & 1) * 64, wn = (wave >> 1) * 64;
    int srow = lane >> 3, sg = lane & 7;
    int sw = lc & 7;

    const ushort_t* stp[8];
    ushort_t* stl[8];
#pragma unroll
    for (int i = 0; i < 8; ++i) {
        int chunk = wave * 8 + i;
        int c = chunk & 15;
        int row = c * 8 + srow;
        stp[i] = (chunk < 16 ? A + (size_t)(m0 + row) * K
                             : Bt + (size_t)(n0 + row) * K) + (sg ^ srow) * 8;
        stl[i] = (chunk < 16 ? As : Bs) + c * 512 + lane * 8;
    }

    f32x4 c00 = {}, c01 = {}, c02 = {}, c03 = {};
    f32x4 c10 = {}, c11 = {}, c12 = {}, c13 = {};
    f32x4 c20 = {}, c21 = {}, c22 = {}, c23 = {};
    f32x4 c30 = {}, c31 = {}, c32 = {}, c33 = {};

    for (int k0 = 0; k0 < K; k0 += 64) {
#pragma unroll
        for (int i = 0; i < 8; ++i) { llds16(stp[i], stl[i]); stp[i] += 64; }
        __syncthreads();
#pragma unroll
        for (int kk = 0; kk < 2; ++kk) {
            int off = ((kk * 4 + quad) ^ sw) * 8;
            bf16x8 a0 = *(const bf16x8*)&As[(wm +  0 + lc) * 64 + off];
            bf16x8 a1 = *(const bf16x8*)&As[(wm + 16 + lc) * 64 + off];
            bf16x8 a2 = *(const bf16x8*)&As[(wm + 32 + lc) * 64 + off];
            bf16x8 a3 = *(const bf16x8*)&As[(wm + 48 + lc) * 64 + off];
            bf16x8 b0 = *(const bf16x8*)&Bs[(wn +  0 + lc) * 64 + off];
            bf16x8 b1 = *(const bf16x8*)&Bs[(wn + 16 + lc) * 64 + off];
            bf16x8 b2 = *(const bf16x8*)&Bs[(wn + 32 + lc) * 64 + off];
            bf16x8 b3 = *(const bf16x8*)&Bs[(wn + 48 + lc) * 64 + off];
            c00 = MFMA(a0, b0, c00, 0, 0, 0); c01 = MFMA(a0, b1, c01, 0, 0, 0);
            c02 = MFMA(a0, b2, c02, 0, 0, 0); c03 = MFMA(a0, b3, c03, 0, 0, 0);
            c10 = MFMA(a1, b0, c10, 0, 0, 0); c11 = MFMA(a1, b1, c11, 0, 0, 0);
            c12 = MFMA(a1, b2, c12, 0, 0, 0); c13 = MFMA(a1, b3, c13, 0, 0, 0);
            c20 = MFMA(a2, b0, c20, 0, 0, 0); c21 = MFMA(a2, b1, c21, 0, 0, 0);
            c22 = MFMA(a2, b2, c22, 0, 0, 0); c23 = MFMA(a2, b3, c23, 0, 0, 0);
            c30 = MFMA(a3, b0, c30, 0, 0, 0); c31 = MFMA(a3, b1, c31, 0, 0, 0);
            c32 = MFMA(a3, b2, c32, 0, 0, 0); c33 = MFMA(a3, b3, c33, 0, 0, 0);
        }
        __syncthreads();
    }

    int mb = m0 + wm + quad * 4, nb = n0 + wn + lc;
    st4<EPI>(c00, mb +  0, nb +  0, N, e); st4<EPI>(c01, mb +  0, nb + 16, N, e);
    st4<EPI>(c02, mb +  0, nb + 32, N, e); st4<EPI>(c03, mb +  0, nb + 48, N, e);
    st4<EPI>(c10, mb + 16, nb +  0, N, e); st4<EPI>(c11, mb + 16, nb + 16, N, e);
    st4<EPI>(c12, mb + 16, nb + 32, N, e); st4<EPI>(c13, mb + 16, nb + 48, N, e);
    st4<EPI>(c20, mb + 32, nb +  0, N, e); st4<EPI>(c21, mb + 32, nb + 16, N, e);
    st4<EPI>(c22, mb + 32, nb + 32, N, e); st4<EPI>(c23, mb + 32, nb + 48, N, e);
    st4<EPI>(c30, mb + 48, nb +  0, N, e); st4<EPI>(c31, mb + 48, nb + 16, N, e);
    st4<EPI>(c32, mb + 48, nb + 32, N, e); st4<EPI>(c33, mb + 48, nb + 48, N, e);
}

// ---------------- GEMM 64x128 tile: small-N GEMMs need more blocks -----------
template <int EPI>
__global__ __launch_bounds__(256, 2) void gemm_bt64(
    const ushort_t* __restrict__ A, const ushort_t* __restrict__ Bt,
    int M, int N, int K, EpiArgs e) {
    __shared__ ushort_t As[64 * 64];    // 8 KB
    __shared__ ushort_t Bs[128 * 64];   // 16 KB
    int m0 = blockIdx.x * 64, n0 = blockIdx.y * 128;
    int tid = threadIdx.x, wave = tid >> 6, lane = tid & 63;
    int quad = lane >> 4, lc = lane & 15;
    int wn = wave * 32;
    int srow = lane >> 3, sg = lane & 7;
    int sw = lc & 7;

    const ushort_t* stp[6];
    ushort_t* stl[6];
#pragma unroll
    for (int i = 0; i < 6; ++i) {
        int chunk = wave * 6 + i;
        if (chunk < 8) {
            int row = chunk * 8 + srow;
            stp[i] = A + (size_t)(m0 + row) * K + (sg ^ srow) * 8;
            stl[i] = &As[chunk * 512 + lane * 8];
        } else {
            int c = chunk - 8;
            int row = c * 8 + srow;
            stp[i] = Bt + (size_t)(n0 + row) * K + (sg ^ srow) * 8;
            stl[i] = &Bs[c * 512 + lane * 8];
        }
    }

    f32x4 c00 = {}, c01 = {};
    f32x4 c10 = {}, c11 = {};
    f32x4 c20 = {}, c21 = {};
    f32x4 c30 = {}, c31 = {};

    for (int k0 = 0; k0 < K; k0 += 64) {
#pragma unroll
        for (int i = 0; i < 6; ++i) { llds16(stp[i], stl[i]); stp[i] += 64; }
        __syncthreads();
#pragma unroll
        for (int kk = 0; kk < 2; ++kk) {
            int off = ((kk * 4 + quad) ^ sw) * 8;
            bf16x8 a0 = *(const bf16x8*)&As[( 0 + lc) * 64 + off];
            bf16x8 a1 = *(const bf16x8*)&As[(16 + lc) * 64 + off];
            bf16x8 a2 = *(const bf16x8*)&As[(32 + lc) * 64 + off];
            bf16x8 a3 = *(const bf16x8*)&As[(48 + lc) * 64 + off];
            bf16x8 b0 = *(const bf16x8*)&Bs[(wn +  0 + lc) * 64 + off];
            bf16x8 b1 = *(const bf16x8*)&Bs[(wn + 16 + lc) * 64 + off];
            c00 = MFMA(a0, b0, c00, 0, 0, 0); c01 = MFMA(a0, b1, c01, 0, 0, 0);
            c10 = MFMA(a1, b0, c10, 0, 0, 0); c11 = MFMA(a1, b1, c11, 0, 0, 0);
            c20 = MFMA(a2, b0, c20, 0, 0, 0); c21 = MFMA(a2, b1, c21, 0, 0, 0);
            c30 = MFMA(a3, b0, c30, 0, 0, 0); c31 = MFMA(a3, b1, c31, 0, 0, 0);
        }
        __syncthreads();
    }

    int mb = m0 + quad * 4, nb = n0 + wn + lc;
    st4<EPI>(c00, mb +  0, nb + 0, N, e); st4<EPI>(c01, mb +  0, nb + 16, N, e);
    st4<EPI>(c10, mb + 16, nb + 0, N, e); st4<EPI>(c11, mb + 16, nb + 16, N, e);
    st4<EPI>(c20, mb + 32, nb + 0, N, e); st4<EPI>(c21, mb + 32, nb + 16, N, e);
    st4<EPI>(c30, mb + 48, nb + 0, N, e); st4<EPI>(c31, mb + 48, nb + 16, N, e);
}

// ---------------- flash attention v11: in-register P via K-row permutation ---
// grid 2048: bits[4:0] bh (XCD-spread), [6:5] kv-quarter, [10:7] q-tile.
// Each block: 128 q-rows x 512 kv (4 tiles). v11 vs v9: K rows are staged into
// LDS through the within-32 permutation sig(s) = 8*((s&15)>>2)+(s&3)+4*(s>>4),
// chosen so the QK^T C-layout slots a lane holds (ni*16+quad*4+r) map to the
// exact kv runs (32k+8*quad+j) the PV A-fragment needs. The lane's own packed
// exp2 outputs ARE the PV A-operand: P never touches LDS (was 16 KB + 24 KB/
// wave-tile of traffic), and one V-fragment read now feeds both 16-q passes
// (V reads halved). LDS 48->32 KB.
__global__ __launch_bounds__(256, 2) void attn(
    const ushort_t* __restrict__ Q, const ushort_t* __restrict__ Kx,
    const ushort_t* __restrict__ Vt,
    ushort_t* __restrict__ Op0, ushort_t* __restrict__ Op1,
    ushort_t* __restrict__ Op2, ushort_t* __restrict__ Op3,
    float* __restrict__ lsum) {
    __shared__ ushort_t Ks[128 * 64];     // 16 KB
    __shared__ ushort_t Vs[64 * 128];     // 16 KB
    int id = blockIdx.x;
    int bh = ((id & 7) << 2) + ((id >> 3) & 3);  // 4 bh per XCD class
    int quarter = (id >> 5) & 3;                 // kv quarter (512 kv)
    int qt = id >> 7;                            // 16 q-tiles of 128 rows
    const ushort_t* Qg = Q + ((size_t)bh * L_ + qt * 128) * DH_;
    const ushort_t* Kg = Kx + (size_t)bh * L_ * DH_;
    const ushort_t* Vg = Vt + (size_t)bh * DH_ * L_;
    int tid = threadIdx.x, wave = tid >> 6, lane = tid & 63;
    int quad = lane >> 4, lc = lane & 15;
    int sw = lc & 7;
    int srow = lane >> 3, sg = lane & 7;

    // hoisted staging: waves 0,1 stage K (sig-permuted rows); waves 2,3 stage V
    const ushort_t* stp[8];
    ushort_t* stl[8];
    int stinc;
    if (wave < 2) {
        stinc = 128 * DH_;
#pragma unroll
        for (int i = 0; i < 8; ++i) {
            int chunk = wave * 8 + i;
            int slot = chunk * 8 + srow;         // LDS row (slot)
            int s5 = slot & 31;                  // within-32 position
            int sig = (slot & ~31) + ((s5 & 15) >> 2) * 8 + (s5 & 3) + (s5 >> 4) * 4;
            stp[i] = Kg + (size_t)(quarter * 512 + sig) * DH_ + (sg ^ srow) * 8;
            stl[i] = &Ks[chunk * 512 + lane * 8];
        }
    } else {
        stinc = 128;
#pragma unroll
        for (int i = 0; i < 8; ++i) {
            int c2 = (wave - 2) * 8 + i;
            int row = c2 * 4 + (lane >> 4);
            int g = (lane & 15) ^ (row & 15);
            stp[i] = Vg + (size_t)row * L_ + quarter * 512 + g * 8;
            stl[i] = &Vs[c2 * 512 + lane * 8];
        }
    }

    // Q fragments straight from global (block-private, read once)
    const ushort_t* qp = Qg + (size_t)(wave * 32 + lc) * DH_ + quad * 8;
    bf16x8 q00 = *(const bf16x8*)(qp);                  // pass0 kk0
    bf16x8 q01 = *(const bf16x8*)(qp + 32);             // pass0 kk1
    bf16x8 q10 = *(const bf16x8*)(qp + 16 * DH_);       // pass1 kk0
    bf16x8 q11 = *(const bf16x8*)(qp + 16 * DH_ + 32);  // pass1 kk1

    f32x4 o00 = {}, o01 = {}, o02 = {}, o03 = {};
    f32x4 o10 = {}, o11 = {}, o12 = {}, o13 = {};
    float lrow0 = 0.f, lrow1 = 0.f;

    for (int t = 0; t < 4; ++t) {
#pragma unroll
        for (int i = 0; i < 8; ++i) { llds16(stp[i], stl[i]); stp[i] += stinc; }
        __syncthreads();

        // S^T = K Q^T: C[slot][q], lane holds q=lc, slot = ni*16 + quad*4 + r;
        // via sig-permuted staging, slot maps to kv so that lane-local packed
        // values form the PV A-fragment directly.
        f32x4 s[2][8];
#pragma unroll
        for (int kk = 0; kk < 2; ++kk) {
            int off = ((kk * 4 + quad) ^ sw) * 8;
            bf16x8 aq0 = kk == 0 ? q00 : q01;
            bf16x8 aq1 = kk == 0 ? q10 : q11;
#pragma unroll
            for (int ni = 0; ni < 8; ++ni) {
                bf16x8 bk = *(const bf16x8*)&Ks[(ni * 16 + lc) * 64 + off];
                if (kk == 0) {
                    f32x4 z = {0.f, 0.f, 0.f, 0.f};
                    s[0][ni] = MFMA(bk, aq0, z, 0, 0, 0);
                    s[1][ni] = MFMA(bk, aq1, z, 0, 0, 0);
                } else {
                    s[0][ni] = MFMA(bk, aq0, s[0][ni], 0, 0, 0);
                    s[1][ni] = MFMA(bk, aq1, s[1][ni], 0, 0, 0);
                }
            }
        }

        // softmax numerator: p = exp2(s), row-sum, pack to bf16 pairs in regs
        u32 px[2][8], py[2][8];
#pragma unroll
        for (int pi = 0; pi < 2; ++pi) {
            float acc = 0.f;
#pragma unroll
            for (int ni = 0; ni < 8; ++ni) {
                float p0 = __builtin_amdgcn_exp2f(s[pi][ni][0]);
                float p1 = __builtin_amdgcn_exp2f(s[pi][ni][1]);
                float p2 = __builtin_amdgcn_exp2f(s[pi][ni][2]);
                float p3 = __builtin_amdgcn_exp2f(s[pi][ni][3]);
                acc += (p0 + p1) + (p2 + p3);
                px[pi][ni] = pk_bf16(p0, p1);
                py[pi][ni] = pk_bf16(p2, p3);
            }
            acc += __shfl_xor(acc, 16);
            acc += __shfl_xor(acc, 32);
            if (pi == 0) lrow0 += acc; else lrow1 += acc;
        }

        // PV: A-fragment for kv-chunk kk is {px[2kk],py[2kk],px[2kk+1],py[2kk+1]}
        // (lane-local, thanks to sig). One V read feeds both passes.
#pragma unroll
        for (int kk = 0; kk < 4; ++kk) {
            int gq = kk * 4 + quad;
            bf16x8 bv0 = *(const bf16x8*)&Vs[( 0 + lc) * 128 + ((gq ^ lc) * 8)];
            bf16x8 bv1 = *(const bf16x8*)&Vs[(16 + lc) * 128 + ((gq ^ lc) * 8)];
            bf16x8 bv2 = *(const bf16x8*)&Vs[(32 + lc) * 128 + ((gq ^ lc) * 8)];
            bf16x8 bv3 = *(const bf16x8*)&Vs[(48 + lc) * 128 + ((gq ^ lc) * 8)];
            union { u32 u[4]; bf16x8 v; } a0, a1;
            a0.u[0] = px[0][2 * kk]; a0.u[1] = py[0][2 * kk];
            a0.u[2] = px[0][2 * kk + 1]; a0.u[3] = py[0][2 * kk + 1];
            a1.u[0] = px[1][2 * kk]; a1.u[1] = py[1][2 * kk];
            a1.u[2] = px[1][2 * kk + 1]; a1.u[3] = py[1][2 * kk + 1];
            o00 = MFMA(a0.v, bv0, o00, 0, 0, 0); o01 = MFMA(a0.v, bv1, o01, 0, 0, 0);
            o02 = MFMA(a0.v, bv2, o02, 0, 0, 0); o03 = MFMA(a0.v, bv3, o03, 0, 0, 0);
            o10 = MFMA(a1.v, bv0, o10, 0, 0, 0); o11 = MFMA(a1.v, bv1, o11, 0, 0, 0);
            o12 = MFMA(a1.v, bv2, o12, 0, 0, 0); o13 = MFMA(a1.v, bv3, o13, 0, 0, 0);
        }
        __syncthreads();  // Ks/Vs consumed before next tile's staging
    }

    // write unnormalized partial O (bf16); PV C-layout rows = quad*4+r
    ushort_t* Op = quarter == 0 ? Op0 : quarter == 1 ? Op1 : quarter == 2 ? Op2 : Op3;
#pragma unroll
    for (int pi = 0; pi < 2; ++pi) {
#pragma unroll
        for (int nio = 0; nio < 4; ++nio) {
            const f32x4& ov = pi == 0 ? (nio == 0 ? o00 : nio == 1 ? o01 : nio == 2 ? o02 : o03)
                                      : (nio == 0 ? o10 : nio == 1 ? o11 : nio == 2 ? o12 : o13);
#pragma unroll
            for (int r = 0; r < 4; ++r) {
                int row = qt * 128 + wave * 32 + pi * 16 + quad * 4 + r;
                Op[((size_t)bh * L_ + row) * DH_ + nio * 16 + lc] = f2bf(ov[r]);
            }
        }
    }
    // l per q-row (lane lc holds row q=lc of each pass; all quads agree)
    if (quad == 0) {
        int base = qt * 128 + wave * 32;
        lsum[(size_t)quarter * BHL_ + (size_t)bh * L_ + base + lc] = lrow0;
        lsum[(size_t)quarter * BHL_ + (size_t)bh * L_ + base + 16 + lc] = lrow1;
    }
}

// ---------------- merge four KV-quarter partials -> final O bf16 -------------
__global__ void attn_merge(const ushort_t* __restrict__ Op0,
                           const ushort_t* __restrict__ Op1,
                           const ushort_t* __restrict__ Op2,
                           const ushort_t* __restrict__ Op3,
                           const float* __restrict__ lsum,
                           ushort_t* __restrict__ O) {
    int gid = blockIdx.x * 256 + threadIdx.x;   // 524288 total
    int row = gid >> 3, j = gid & 7;
    float inv = 1.f / (lsum[row] + lsum[BHL_ + row] +
                       lsum[2 * BHL_ + row] + lsum[3 * BHL_ + row]);
    bf16x8 v0 = *(const bf16x8*)(Op0 + (size_t)row * DH_ + j * 8);
    bf16x8 v1 = *(const bf16x8*)(Op1 + (size_t)row * DH_ + j * 8);
    bf16x8 v2 = *(const bf16x8*)(Op2 + (size_t)row * DH_ + j * 8);
    bf16x8 v3 = *(const bf16x8*)(Op3 + (size_t)row * DH_ + j * 8);
    uint4 o;
    float r0, r1;
#pragma unroll
    for (int k = 0; k < 4; ++k) {
        r0 = ((float)v0[2 * k] + (float)v1[2 * k] + (float)v2[2 * k] + (float)v3[2 * k]) * inv;
        r1 = ((float)v0[2 * k + 1] + (float)v1[2 * k + 1] + (float)v2[2 * k + 1] + (float)v3[2 * k + 1]) * inv;
        ((u32*)&o)[k] = pk_bf16(r0, r1);
    }
    *(uint4*)(O + (size_t)row * DH_ + j * 8) = o;
}

// -----------------------------------------------------------------------------
extern "C" void kernel_launch(void* const* d_in, const int* in_sizes, int n_in,
                              void* d_out, int out_size, void* d_ws, size_t ws_size,
                              hipStream_t stream) {
    (void)in_sizes; (void)n_in; (void)out_size; (void)ws_size;
    const float* x    = (const float*)d_in[0];
    const float* c    = (const float*)d_in[1];
    const float* Wq   = (const float*)d_in[2];
    const float* bq   = (const float*)d_in[3];
    const float* Wk   = (const float*)d_in[4];
    const float* bk   = (const float*)d_in[5];
    const float* Wv   = (const float*)d_in[6];
    const float* bv   = (const float*)d_in[7];
    const float* Wo   = (const float*)d_in[8];
    const float* bo   = (const float*)d_in[9];
    const float* W1   = (const float*)d_in[10];
    const float* b1   = (const float*)d_in[11];
    const float* W2   = (const float*)d_in[12];
    const float* b2   = (const float*)d_in[13];
    const float* Wada = (const float*)d_in[14];
    const float* bada = (const float*)d_in[15];

    char* w = (char*)d_ws;
    float*    ada  = (float*)(w + 0);                     // 49152 B
    ushort_t* Wqkv = (ushort_t*)(w + 49152);              // 6 MiB (lsum after QKV gemm)
    ushort_t* Wo_t = (ushort_t*)(w + 6340608);            // 2 MiB
    ushort_t* W1_t = (ushort_t*)(w + 8437760);            // 4 MiB
    ushort_t* W2_t = (ushort_t*)(w + 12632064);           // 4 MiB
    ushort_t* h    = (ushort_t*)(w + 16826368);           // 8 MiB (h / partial1 / h2)
    ushort_t* Qb   = (ushort_t*)(w + 25214976);           // 8 MiB (Q, then merged O)
    ushort_t* Kb   = (ushort_t*)(w + 33603584);           // 8 MiB
    ushort_t* Vb   = (ushort_t*)(w + 41992192);           // 8 MiB (V, then partial0)
    ushort_t* Vtb  = (ushort_t*)(w + 50380800);           // 8 MiB (ada partials, then V^T)
    float*    x1   = (float*)(w + 58769408);              // 16 MiB (partials 2+3, then x1)
    ushort_t* Ob   = Qb;          // merged O overwrites Q (dead post-attn)
    ushort_t* m1   = Qb;          // MLP hidden (16 MiB = Qb+Kb, dead post O-proj)
    float*    lsb  = (float*)Wqkv;  // 1 MiB l per quarter; Wqkv dead after QKV gemm
    float*    adap = (float*)Vtb;   // 786 KB split-k partials; dead before transpose_v
    ushort_t* p2   = (ushort_t*)x1;                         // partial2 (8 MiB)
    ushort_t* p3   = (ushort_t*)((char*)x1 + 8388608);      // partial3 (8 MiB)

    const int M = B_ * L_;  // 4096

    transpose_w_all<<<2048, 256, 0, stream>>>(Wq, Wk, Wv, Wo, W1, W2,
                                              Wqkv, Wo_t, W1_t, W2_t);

    ada_gemv<<<dim3(24, 16), 256, 0, stream>>>(c, Wada, adap);
    ada_reduce<<<24, 256, 0, stream>>>(adap, bada, ada);
    ln_mod<<<M, 256, 0, stream>>>(x, ada, 0, 1024, h);

    EpiArgs e0 = {bq, bk, bv, Qb, Kb, Vb, nullptr, nullptr, nullptr};
    gemm_bt<0><<<dim3(32, 24), 256, 0, stream>>>(h, Wqkv, M, 3072, D_, e0);

    transpose_v<<<dim3(32, 32), 256, 0, stream>>>(Vb, Vtb);

    // KV-split-4 attention: partials -> Vb, h, x1-lo, x1-hi (all dead regions)
    attn<<<2048, 256, 0, stream>>>(Qb, Kb, Vtb, Vb, h, p2, p3, lsb);
    attn_merge<<<2048, 256, 0, stream>>>(Vb, h, p2, p3, lsb, Ob);

    EpiArgs e1 = {bo, nullptr, nullptr, nullptr, nullptr, nullptr, x, ada + 2048, x1};
    gemm_bt64<2><<<dim3(64, 8), 256, 0, stream>>>(Ob, Wo_t, M, D_, D_, e1);

    ln_mod<<<M, 256, 0, stream>>>(x1, ada, 3072, 4096, h);

    EpiArgs e2 = {b1, nullptr, nullptr, m1, nullptr, nullptr, nullptr, nullptr, nullptr};
    gemm_bt64<1><<<dim3(64, 16), 256, 0, stream>>>(h, W1_t, M, FF_, D_, e2);

    EpiArgs e3 = {b2, nullptr, nullptr, nullptr, nullptr, nullptr, x1, ada + 5120, (float*)d_out};
    gemm_bt64<2><<<dim3(64, 8), 256, 0, stream>>>(m1, W2_t, M, D_, FF_, e3);
}

// Round 3
// 321.353 us; speedup vs baseline: 1.0549x; 1.0092x over previous
//
#include <hip/hip_runtime.h>
#include <hip/hip_bf16.h>

typedef unsigned short ushort_t;
typedef __bf16 bf16x8 __attribute__((ext_vector_type(8)));
typedef float f32x4 __attribute__((ext_vector_type(4)));

typedef unsigned int u32;
typedef u32 __attribute__((address_space(1))) global_u32;
typedef u32 __attribute__((address_space(3))) lds_u32;

#define D_ 1024
#define L_ 2048
#define B_ 2
#define H_ 16
#define DH_ 64
#define FF_ 2048
#define ADA_ 6144
#define BHL_ (B_ * H_ * L_)

#define MFMA __builtin_amdgcn_mfma_f32_16x16x32_bf16

__device__ __forceinline__ ushort_t f2bf(float f) {
    union { float f; u32 u; } v; v.f = f;
    u32 r = v.u + 0x7fffu + ((v.u >> 16) & 1u);
    return (ushort_t)(r >> 16);
}

// packed 2xf32 -> 2xbf16 (v_cvt_pk_bf16_f32)
__device__ __forceinline__ u32 pk_bf16(float a, float b) {
    float2 f; f.x = a; f.y = b;
    __hip_bfloat162 t = __float22bfloat162_rn(f);
    union { __hip_bfloat162 b2; u32 u; } v; v.b2 = t; return v.u;
}

__device__ __forceinline__ void llds16(const ushort_t* src, ushort_t* dst) {
    __builtin_amdgcn_global_load_lds((global_u32*)src, (lds_u32*)dst, 16, 0, 0);
}

// ------- fused weight transpose+convert: all 6 weights, one dispatch ---------
__global__ void transpose_w_all(
    const float* __restrict__ Wq, const float* __restrict__ Wk,
    const float* __restrict__ Wv, const float* __restrict__ Wo,
    const float* __restrict__ W1, const float* __restrict__ W2,
    ushort_t* __restrict__ Wqkv, ushort_t* __restrict__ Wo_t,
    ushort_t* __restrict__ W1_t, ushort_t* __restrict__ W2_t) {
    __shared__ float tile[64][65];
    int id = blockIdx.x;
    const float* W; ushort_t* Wt; int K, N, ntx, lid;
    if (id < 1024) {
        int which = id >> 8; lid = id & 255; K = 1024; N = 1024; ntx = 16;
        W  = which == 0 ? Wq : which == 1 ? Wk : which == 2 ? Wv : Wo;
        Wt = which == 3 ? Wo_t : Wqkv + (size_t)which * 1024 * 1024;
    } else if (id < 1536) {
        lid = id - 1024; W = W1; Wt = W1_t; K = 1024; N = 2048; ntx = 32;
    } else {
        lid = id - 1536; W = W2; Wt = W2_t; K = 2048; N = 1024; ntx = 16;
    }
    int n0 = (lid % ntx) * 64, k0 = (lid / ntx) * 64;
    int t = threadIdx.x;
    for (int p = 0; p < 4; ++p) {
        int k = p * 16 + (t >> 4), nn = (t & 15) * 4;
        float4 v = *(const float4*)(W + (size_t)(k0 + k) * N + n0 + nn);
        tile[k][nn] = v.x; tile[k][nn + 1] = v.y; tile[k][nn + 2] = v.z; tile[k][nn + 3] = v.w;
    }
    __syncthreads();
    for (int p = 0; p < 4; ++p) {
        int n = p * 16 + (t >> 4), kk = (t & 15) * 4;
        ushort4 o;
        o.x = f2bf(tile[kk][n]); o.y = f2bf(tile[kk + 1][n]);
        o.z = f2bf(tile[kk + 2][n]); o.w = f2bf(tile[kk + 3][n]);
        *(ushort4*)(Wt + (size_t)(n0 + n) * K + k0 + kk) = o;
    }
}

// ---------------- V transpose: (BH, L, DH) bf16 -> (BH, DH, L) bf16 ----------
__global__ void transpose_v(const ushort_t* __restrict__ V, ushort_t* __restrict__ Vt) {
    __shared__ ushort_t tile[64][72];
    int bh = blockIdx.y, l0 = blockIdx.x * 64;
    const ushort_t* Vb = V + ((size_t)bh * L_ + l0) * DH_;
    ushort_t* Vtb = Vt + (size_t)bh * DH_ * L_;
    int t = threadIdx.x;
    for (int p = 0; p < 2; ++p) {
        int i = p * 32 + (t >> 3), d0 = (t & 7) * 8;
        ushort4 v0 = *(const ushort4*)(Vb + (size_t)i * DH_ + d0);
        ushort4 v1 = *(const ushort4*)(Vb + (size_t)i * DH_ + d0 + 4);
        tile[d0 + 0][i] = v0.x; tile[d0 + 1][i] = v0.y; tile[d0 + 2][i] = v0.z; tile[d0 + 3][i] = v0.w;
        tile[d0 + 4][i] = v1.x; tile[d0 + 5][i] = v1.y; tile[d0 + 6][i] = v1.z; tile[d0 + 7][i] = v1.w;
    }
    __syncthreads();
    for (int p = 0; p < 2; ++p) {
        int dh = p * 32 + (t >> 3), j0 = (t & 7) * 8;
        ushort4 o0, o1;
        o0.x = tile[dh][j0 + 0]; o0.y = tile[dh][j0 + 1]; o0.z = tile[dh][j0 + 2]; o0.w = tile[dh][j0 + 3];
        o1.x = tile[dh][j0 + 4]; o1.y = tile[dh][j0 + 5]; o1.z = tile[dh][j0 + 6]; o1.w = tile[dh][j0 + 7];
        *(ushort4*)(Vtb + (size_t)dh * L_ + l0 + j0) = o0;
        *(ushort4*)(Vtb + (size_t)dh * L_ + l0 + j0 + 4) = o1;
    }
}

// ---------------- ada = silu(c) @ Wada + bada: split-k GEMV ------------------
__global__ void ada_gemv(const float* __restrict__ c, const float* __restrict__ Wada,
                         float* __restrict__ partial) {
    int ks = blockIdx.y;
    int j = blockIdx.x * 256 + threadIdx.x;
    __shared__ float s0[64], s1[64];
    if (threadIdx.x < 64) {
        float v = c[ks * 64 + threadIdx.x];
        s0[threadIdx.x] = v / (1.f + __expf(-v));
        v = c[D_ + ks * 64 + threadIdx.x];
        s1[threadIdx.x] = v / (1.f + __expf(-v));
    }
    __syncthreads();
    float a0 = 0.f, a1 = 0.f;
#pragma unroll 8
    for (int d = 0; d < 64; ++d) {
        float w = Wada[(size_t)(ks * 64 + d) * ADA_ + j];
        a0 = fmaf(s0[d], w, a0);
        a1 = fmaf(s1[d], w, a1);
    }
    partial[(size_t)(ks * 2 + 0) * ADA_ + j] = a0;
    partial[(size_t)(ks * 2 + 1) * ADA_ + j] = a1;
}

__global__ void ada_reduce(const float* __restrict__ partial,
                           const float* __restrict__ bada, float* __restrict__ ada) {
    int j = blockIdx.x * 256 + threadIdx.x;
    float a0 = bada[j], a1 = bada[j];
#pragma unroll
    for (int ks = 0; ks < 16; ++ks) {
        a0 += partial[(size_t)(ks * 2 + 0) * ADA_ + j];
        a1 += partial[(size_t)(ks * 2 + 1) * ADA_ + j];
    }
    ada[j] = a0;
    ada[ADA_ + j] = a1;
}

// ---------------- LayerNorm + modulation -> bf16 -----------------------------
__global__ void ln_mod(const float* __restrict__ x, const float* __restrict__ ada,
                       int so, int co, ushort_t* __restrict__ out) {
    int row = blockIdx.x;
    int b = row >> 11;
    float4 v = ((const float4*)(x + (size_t)row * D_))[threadIdx.x];
    float sum = v.x + v.y + v.z + v.w;
    float sq = v.x * v.x + v.y * v.y + v.z * v.z + v.w * v.w;
    for (int off = 32; off; off >>= 1) { sum += __shfl_down(sum, off); sq += __shfl_down(sq, off); }
    __shared__ float sa[4], sb[4];
    int wave = threadIdx.x >> 6, lane = threadIdx.x & 63;
    if (lane == 0) { sa[wave] = sum; sb[wave] = sq; }
    __syncthreads();
    sum = sa[0] + sa[1] + sa[2] + sa[3];
    sq = sb[0] + sb[1] + sb[2] + sb[3];
    float mean = sum * (1.f / 1024.f);
    float var = sq * (1.f / 1024.f) - mean * mean;
    float rstd = rsqrtf(var + 1e-6f);
    int d = threadIdx.x * 4;
    const float* shf = ada + (size_t)b * ADA_ + so;
    const float* scf = ada + (size_t)b * ADA_ + co;
    uint2 ov;
    ov.x = pk_bf16((v.x - mean) * rstd * (1.f + scf[d + 0]) + shf[d + 0],
                   (v.y - mean) * rstd * (1.f + scf[d + 1]) + shf[d + 1]);
    ov.y = pk_bf16((v.z - mean) * rstd * (1.f + scf[d + 2]) + shf[d + 2],
                   (v.w - mean) * rstd * (1.f + scf[d + 3]) + shf[d + 3]);
    *(uint2*)(out + (size_t)row * D_ + d) = ov;
}

// ---------------- GEMM epilogues ---------------------------------------------
struct EpiArgs {
    const float* bias0; const float* bias1; const float* bias2;
    ushort_t* o0; ushort_t* o1; ushort_t* o2;
    const float* resid; const float* gate;
    float* fout;
};

template <int EPI>
__device__ __forceinline__ void epi_store(float v, int m, int n, int N, const EpiArgs& e) {
    if (EPI == 0) {  // QKV -> (B,H,L,DH) bf16; Q pre-scaled by log2(e)/8
        int which = n >> 10, cc = n & 1023;
        const float* bias = which == 0 ? e.bias0 : which == 1 ? e.bias1 : e.bias2;
        ushort_t* ob = which == 0 ? e.o0 : which == 1 ? e.o1 : e.o2;
        v += bias[cc];
        if (which == 0) v *= 0.18033688f;  // (1/8) * log2(e): softmax uses exp2
        int b = m >> 11, l = m & 2047, h = cc >> 6, dh = cc & 63;
        ob[(((size_t)(b * H_ + h) * L_) + l) * DH_ + dh] = f2bf(v);
    } else if (EPI == 1) {  // bias + exact GELU -> bf16
        v += e.bias0[n];
        v = 0.5f * v * (1.f + erff(v * 0.70710678118f));
        e.o0[(size_t)m * N + n] = f2bf(v);
    } else {  // residual + gate -> fp32
        int b = m >> 11;
        e.fout[(size_t)m * N + n] =
            e.resid[(size_t)m * N + n] + e.gate[(size_t)b * ADA_ + n] * (v + e.bias0[n]);
    }
}

template <int EPI>
__device__ __forceinline__ void st4(const f32x4& cc, int mb, int n, int N, const EpiArgs& e) {
#pragma unroll
    for (int r = 0; r < 4; ++r) epi_store<EPI>(cc[r], mb + r, n, N, e);
}

// ---------------- GEMM 128x128 tile (QKV) ------------------------------------
template <int EPI>
__global__ __launch_bounds__(256, 2) void gemm_bt(
    const ushort_t* __restrict__ A, const ushort_t* __restrict__ Bt,
    int M, int N, int K, EpiArgs e) {
    __shared__ ushort_t As[128 * 64];
    __shared__ ushort_t Bs[128 * 64];
    int m0 = blockIdx.x * 128, n0 = blockIdx.y * 128;
    int tid = threadIdx.x, wave = tid >> 6, lane = tid & 63;
    int quad = lane >> 4, lc = lane & 15;
    int wm = (wave & 1) * 64, wn = (wave >> 1) * 64;
    int srow = lane >> 3, sg = lane & 7;
    int sw = lc & 7;

    const ushort_t* stp[8];
    ushort_t* stl[8];
#pragma unroll
    for (int i = 0; i < 8; ++i) {
        int chunk = wave * 8 + i;
        int c = chunk & 15;
        int row = c * 8 + srow;
        stp[i] = (chunk < 16 ? A + (size_t)(m0 + row) * K
                             : Bt + (size_t)(n0 + row) * K) + (sg ^ srow) * 8;
        stl[i] = (chunk < 16 ? As : Bs) + c * 512 + lane * 8;
    }

    f32x4 c00 = {}, c01 = {}, c02 = {}, c03 = {};
    f32x4 c10 = {}, c11 = {}, c12 = {}, c13 = {};
    f32x4 c20 = {}, c21 = {}, c22 = {}, c23 = {};
    f32x4 c30 = {}, c31 = {}, c32 = {}, c33 = {};

    for (int k0 = 0; k0 < K; k0 += 64) {
#pragma unroll
        for (int i = 0; i < 8; ++i) { llds16(stp[i], stl[i]); stp[i] += 64; }
        __syncthreads();
#pragma unroll
        for (int kk = 0; kk < 2; ++kk) {
            int off = ((kk * 4 + quad) ^ sw) * 8;
            bf16x8 a0 = *(const bf16x8*)&As[(wm +  0 + lc) * 64 + off];
            bf16x8 a1 = *(const bf16x8*)&As[(wm + 16 + lc) * 64 + off];
            bf16x8 a2 = *(const bf16x8*)&As[(wm + 32 + lc) * 64 + off];
            bf16x8 a3 = *(const bf16x8*)&As[(wm + 48 + lc) * 64 + off];
            bf16x8 b0 = *(const bf16x8*)&Bs[(wn +  0 + lc) * 64 + off];
            bf16x8 b1 = *(const bf16x8*)&Bs[(wn + 16 + lc) * 64 + off];
            bf16x8 b2 = *(const bf16x8*)&Bs[(wn + 32 + lc) * 64 + off];
            bf16x8 b3 = *(const bf16x8*)&Bs[(wn + 48 + lc) * 64 + off];
            c00 = MFMA(a0, b0, c00, 0, 0, 0); c01 = MFMA(a0, b1, c01, 0, 0, 0);
            c02 = MFMA(a0, b2, c02, 0, 0, 0); c03 = MFMA(a0, b3, c03, 0, 0, 0);
            c10 = MFMA(a1, b0, c10, 0, 0, 0); c11 = MFMA(a1, b1, c11, 0, 0, 0);
            c12 = MFMA(a1, b2, c12, 0, 0, 0); c13 = MFMA(a1, b3, c13, 0, 0, 0);
            c20 = MFMA(a2, b0, c20, 0, 0, 0); c21 = MFMA(a2, b1, c21, 0, 0, 0);
            c22 = MFMA(a2, b2, c22, 0, 0, 0); c23 = MFMA(a2, b3, c23, 0, 0, 0);
            c30 = MFMA(a3, b0, c30, 0, 0, 0); c31 = MFMA(a3, b1, c31, 0, 0, 0);
            c32 = MFMA(a3, b2, c32, 0, 0, 0); c33 = MFMA(a3, b3, c33, 0, 0, 0);
        }
        __syncthreads();
    }

    int mb = m0 + wm + quad * 4, nb = n0 + wn + lc;
    st4<EPI>(c00, mb +  0, nb +  0, N, e); st4<EPI>(c01, mb +  0, nb + 16, N, e);
    st4<EPI>(c02, mb +  0, nb + 32, N, e); st4<EPI>(c03, mb +  0, nb + 48, N, e);
    st4<EPI>(c10, mb + 16, nb +  0, N, e); st4<EPI>(c11, mb + 16, nb + 16, N, e);
    st4<EPI>(c12, mb + 16, nb + 32, N, e); st4<EPI>(c13, mb + 16, nb + 48, N, e);
    st4<EPI>(c20, mb + 32, nb +  0, N, e); st4<EPI>(c21, mb + 32, nb + 16, N, e);
    st4<EPI>(c22, mb + 32, nb + 32, N, e); st4<EPI>(c23, mb + 32, nb + 48, N, e);
    st4<EPI>(c30, mb + 48, nb +  0, N, e); st4<EPI>(c31, mb + 48, nb + 16, N, e);
    st4<EPI>(c32, mb + 48, nb + 32, N, e); st4<EPI>(c33, mb + 48, nb + 48, N, e);
}

// ---------------- GEMM 64x128 tile: small-N GEMMs need more blocks -----------
template <int EPI>
__global__ __launch_bounds__(256, 2) void gemm_bt64(
    const ushort_t* __restrict__ A, const ushort_t* __restrict__ Bt,
    int M, int N, int K, EpiArgs e) {
    __shared__ ushort_t As[64 * 64];    // 8 KB
    __shared__ ushort_t Bs[128 * 64];   // 16 KB
    int m0 = blockIdx.x * 64, n0 = blockIdx.y * 128;
    int tid = threadIdx.x, wave = tid >> 6, lane = tid & 63;
    int quad = lane >> 4, lc = lane & 15;
    int wn = wave * 32;
    int srow = lane >> 3, sg = lane & 7;
    int sw = lc & 7;

    const ushort_t* stp[6];
    ushort_t* stl[6];
#pragma unroll
    for (int i = 0; i < 6; ++i) {
        int chunk = wave * 6 + i;
        if (chunk < 8) {
            int row = chunk * 8 + srow;
            stp[i] = A + (size_t)(m0 + row) * K + (sg ^ srow) * 8;
            stl[i] = &As[chunk * 512 + lane * 8];
        } else {
            int c = chunk - 8;
            int row = c * 8 + srow;
            stp[i] = Bt + (size_t)(n0 + row) * K + (sg ^ srow) * 8;
            stl[i] = &Bs[c * 512 + lane * 8];
        }
    }

    f32x4 c00 = {}, c01 = {};
    f32x4 c10 = {}, c11 = {};
    f32x4 c20 = {}, c21 = {};
    f32x4 c30 = {}, c31 = {};

    for (int k0 = 0; k0 < K; k0 += 64) {
#pragma unroll
        for (int i = 0; i < 6; ++i) { llds16(stp[i], stl[i]); stp[i] += 64; }
        __syncthreads();
#pragma unroll
        for (int kk = 0; kk < 2; ++kk) {
            int off = ((kk * 4 + quad) ^ sw) * 8;
            bf16x8 a0 = *(const bf16x8*)&As[( 0 + lc) * 64 + off];
            bf16x8 a1 = *(const bf16x8*)&As[(16 + lc) * 64 + off];
            bf16x8 a2 = *(const bf16x8*)&As[(32 + lc) * 64 + off];
            bf16x8 a3 = *(const bf16x8*)&As[(48 + lc) * 64 + off];
            bf16x8 b0 = *(const bf16x8*)&Bs[(wn +  0 + lc) * 64 + off];
            bf16x8 b1 = *(const bf16x8*)&Bs[(wn + 16 + lc) * 64 + off];
            c00 = MFMA(a0, b0, c00, 0, 0, 0); c01 = MFMA(a0, b1, c01, 0, 0, 0);
            c10 = MFMA(a1, b0, c10, 0, 0, 0); c11 = MFMA(a1, b1, c11, 0, 0, 0);
            c20 = MFMA(a2, b0, c20, 0, 0, 0); c21 = MFMA(a2, b1, c21, 0, 0, 0);
            c30 = MFMA(a3, b0, c30, 0, 0, 0); c31 = MFMA(a3, b1, c31, 0, 0, 0);
        }
        __syncthreads();
    }

    int mb = m0 + quad * 4, nb = n0 + wn + lc;
    st4<EPI>(c00, mb +  0, nb + 0, N, e); st4<EPI>(c01, mb +  0, nb + 16, N, e);
    st4<EPI>(c10, mb + 16, nb + 0, N, e); st4<EPI>(c11, mb + 16, nb + 16, N, e);
    st4<EPI>(c20, mb + 32, nb + 0, N, e); st4<EPI>(c21, mb + 32, nb + 16, N, e);
    st4<EPI>(c30, mb + 48, nb + 0, N, e); st4<EPI>(c31, mb + 48, nb + 16, N, e);
}

// ---------------- flash attention v12: in-reg P + MFMA rowsum + setprio ------
// grid 2048: bits[4:0] bh (XCD-spread), [6:5] kv-quarter, [10:7] q-tile.
// v12 vs v11: (1) softmax denominators computed by MFMA against a synthesized
// all-ones B operand (rowsum rides the PV A-fragments) -- removes ~66 v_add +
// 4 cross-lane DS ops per wave-tile; lsum written from lc==0 lanes of the
// f32x4 sum accumulators. (2) s_setprio(1) around the QK^T and PV MFMA
// clusters (m191: +4-7% attn when waves de-phase between VALU and MFMA).
__global__ __launch_bounds__(256, 2) void attn(
    const ushort_t* __restrict__ Q, const ushort_t* __restrict__ Kx,
    const ushort_t* __restrict__ Vt,
    ushort_t* __restrict__ Op0, ushort_t* __restrict__ Op1,
    ushort_t* __restrict__ Op2, ushort_t* __restrict__ Op3,
    float* __restrict__ lsum) {
    __shared__ ushort_t Ks[128 * 64];     // 16 KB
    __shared__ ushort_t Vs[64 * 128];     // 16 KB
    int id = blockIdx.x;
    int bh = ((id & 7) << 2) + ((id >> 3) & 3);  // 4 bh per XCD class
    int quarter = (id >> 5) & 3;                 // kv quarter (512 kv)
    int qt = id >> 7;                            // 16 q-tiles of 128 rows
    const ushort_t* Qg = Q + ((size_t)bh * L_ + qt * 128) * DH_;
    const ushort_t* Kg = Kx + (size_t)bh * L_ * DH_;
    const ushort_t* Vg = Vt + (size_t)bh * DH_ * L_;
    int tid = threadIdx.x, wave = tid >> 6, lane = tid & 63;
    int quad = lane >> 4, lc = lane & 15;
    int sw = lc & 7;
    int srow = lane >> 3, sg = lane & 7;

    // hoisted staging: waves 0,1 stage K (sig-permuted rows); waves 2,3 stage V
    const ushort_t* stp[8];
    ushort_t* stl[8];
    int stinc;
    if (wave < 2) {
        stinc = 128 * DH_;
#pragma unroll
        for (int i = 0; i < 8; ++i) {
            int chunk = wave * 8 + i;
            int slot = chunk * 8 + srow;         // LDS row (slot)
            int s5 = slot & 31;                  // within-32 position
            int sig = (slot & ~31) + ((s5 & 15) >> 2) * 8 + (s5 & 3) + (s5 >> 4) * 4;
            stp[i] = Kg + (size_t)(quarter * 512 + sig) * DH_ + (sg ^ srow) * 8;
            stl[i] = &Ks[chunk * 512 + lane * 8];
        }
    } else {
        stinc = 128;
#pragma unroll
        for (int i = 0; i < 8; ++i) {
            int c2 = (wave - 2) * 8 + i;
            int row = c2 * 4 + (lane >> 4);
            int g = (lane & 15) ^ (row & 15);
            stp[i] = Vg + (size_t)row * L_ + quarter * 512 + g * 8;
            stl[i] = &Vs[c2 * 512 + lane * 8];
        }
    }

    // Q fragments straight from global (block-private, read once)
    const ushort_t* qp = Qg + (size_t)(wave * 32 + lc) * DH_ + quad * 8;
    bf16x8 q00 = *(const bf16x8*)(qp);                  // pass0 kk0
    bf16x8 q01 = *(const bf16x8*)(qp + 32);             // pass0 kk1
    bf16x8 q10 = *(const bf16x8*)(qp + 16 * DH_);       // pass1 kk0
    bf16x8 q11 = *(const bf16x8*)(qp + 16 * DH_ + 32);  // pass1 kk1

    // all-ones bf16 B operand for MFMA row-sums (1.0bf16 = 0x3F80)
    union { u32 u[4]; bf16x8 v; } ones;
    ones.u[0] = ones.u[1] = ones.u[2] = ones.u[3] = 0x3F803F80u;

    f32x4 o00 = {}, o01 = {}, o02 = {}, o03 = {};
    f32x4 o10 = {}, o11 = {}, o12 = {}, o13 = {};
    f32x4 osum0 = {}, osum1 = {};   // rowsum accumulators (cols redundant)

    for (int t = 0; t < 4; ++t) {
#pragma unroll
        for (int i = 0; i < 8; ++i) { llds16(stp[i], stl[i]); stp[i] += stinc; }
        __syncthreads();

        // S^T = K Q^T: C[slot][q], lane holds q=lc, slot = ni*16 + quad*4 + r;
        // via sig-permuted staging, slot maps to kv so that lane-local packed
        // values form the PV A-fragment directly.
        f32x4 s[2][8];
        __builtin_amdgcn_s_setprio(1);
#pragma unroll
        for (int kk = 0; kk < 2; ++kk) {
            int off = ((kk * 4 + quad) ^ sw) * 8;
            bf16x8 aq0 = kk == 0 ? q00 : q01;
            bf16x8 aq1 = kk == 0 ? q10 : q11;
#pragma unroll
            for (int ni = 0; ni < 8; ++ni) {
                bf16x8 bk = *(const bf16x8*)&Ks[(ni * 16 + lc) * 64 + off];
                if (kk == 0) {
                    f32x4 z = {0.f, 0.f, 0.f, 0.f};
                    s[0][ni] = MFMA(bk, aq0, z, 0, 0, 0);
                    s[1][ni] = MFMA(bk, aq1, z, 0, 0, 0);
                } else {
                    s[0][ni] = MFMA(bk, aq0, s[0][ni], 0, 0, 0);
                    s[1][ni] = MFMA(bk, aq1, s[1][ni], 0, 0, 0);
                }
            }
        }
        __builtin_amdgcn_s_setprio(0);

        // softmax numerator: p = exp2(s), pack to bf16 pairs in regs
        u32 px[2][8], py[2][8];
#pragma unroll
        for (int pi = 0; pi < 2; ++pi) {
#pragma unroll
            for (int ni = 0; ni < 8; ++ni) {
                float p0 = __builtin_amdgcn_exp2f(s[pi][ni][0]);
                float p1 = __builtin_amdgcn_exp2f(s[pi][ni][1]);
                float p2 = __builtin_amdgcn_exp2f(s[pi][ni][2]);
                float p3 = __builtin_amdgcn_exp2f(s[pi][ni][3]);
                px[pi][ni] = pk_bf16(p0, p1);
                py[pi][ni] = pk_bf16(p2, p3);
            }
        }

        // PV: A-fragment for kv-chunk kk is {px[2kk],py[2kk],px[2kk+1],py[2kk+1]}
        // (lane-local, thanks to sig). One V read feeds both passes. Rowsums
        // ride the same A-fragments against the ones operand.
        __builtin_amdgcn_s_setprio(1);
#pragma unroll
        for (int kk = 0; kk < 4; ++kk) {
            int gq = kk * 4 + quad;
            bf16x8 bv0 = *(const bf16x8*)&Vs[( 0 + lc) * 128 + ((gq ^ lc) * 8)];
            bf16x8 bv1 = *(const bf16x8*)&Vs[(16 + lc) * 128 + ((gq ^ lc) * 8)];
            bf16x8 bv2 = *(const bf16x8*)&Vs[(32 + lc) * 128 + ((gq ^ lc) * 8)];
            bf16x8 bv3 = *(const bf16x8*)&Vs[(48 + lc) * 128 + ((gq ^ lc) * 8)];
            union { u32 u[4]; bf16x8 v; } a0, a1;
            a0.u[0] = px[0][2 * kk]; a0.u[1] = py[0][2 * kk];
            a0.u[2] = px[0][2 * kk + 1]; a0.u[3] = py[0][2 * kk + 1];
            a1.u[0] = px[1][2 * kk]; a1.u[1] = py[1][2 * kk];
            a1.u[2] = px[1][2 * kk + 1]; a1.u[3] = py[1][2 * kk + 1];
            o00 = MFMA(a0.v, bv0, o00, 0, 0, 0); o01 = MFMA(a0.v, bv1, o01, 0, 0, 0);
            o02 = MFMA(a0.v, bv2, o02, 0, 0, 0); o03 = MFMA(a0.v, bv3, o03, 0, 0, 0);
            o10 = MFMA(a1.v, bv0, o10, 0, 0, 0); o11 = MFMA(a1.v, bv1, o11, 0, 0, 0);
            o12 = MFMA(a1.v, bv2, o12, 0, 0, 0); o13 = MFMA(a1.v, bv3, o13, 0, 0, 0);
            osum0 = MFMA(a0.v, ones.v, osum0, 0, 0, 0);
            osum1 = MFMA(a1.v, ones.v, osum1, 0, 0, 0);
        }
        __builtin_amdgcn_s_setprio(0);
        __syncthreads();  // Ks/Vs consumed before next tile's staging
    }

    // write unnormalized partial O (bf16); PV C-layout rows = quad*4+r
    ushort_t* Op = quarter == 0 ? Op0 : quarter == 1 ? Op1 : quarter == 2 ? Op2 : Op3;
#pragma unroll
    for (int pi = 0; pi < 2; ++pi) {
#pragma unroll
        for (int nio = 0; nio < 4; ++nio) {
            const f32x4& ov = pi == 0 ? (nio == 0 ? o00 : nio == 1 ? o01 : nio == 2 ? o02 : o03)
                                      : (nio == 0 ? o10 : nio == 1 ? o11 : nio == 2 ? o12 : o13);
#pragma unroll
            for (int r = 0; r < 4; ++r) {
                int row = qt * 128 + wave * 32 + pi * 16 + quad * 4 + r;
                Op[((size_t)bh * L_ + row) * DH_ + nio * 16 + lc] = f2bf(ov[r]);
            }
        }
    }
    // l per q-row via MFMA rowsum: lane (quad, lc) holds rows pi*16+quad*4+r,
    // identical across lc -> lc==0 lanes write
    if (lc == 0) {
        int base = qt * 128 + wave * 32 + quad * 4;
#pragma unroll
        for (int r = 0; r < 4; ++r) {
            lsum[(size_t)quarter * BHL_ + (size_t)bh * L_ + base + r] = osum0[r];
            lsum[(size_t)quarter * BHL_ + (size_t)bh * L_ + base + 16 + r] = osum1[r];
        }
    }
}

// ---------------- merge four KV-quarter partials -> final O bf16 -------------
__global__ void attn_merge(const ushort_t* __restrict__ Op0,
                           const ushort_t* __restrict__ Op1,
                           const ushort_t* __restrict__ Op2,
                           const ushort_t* __restrict__ Op3,
                           const float* __restrict__ lsum,
                           ushort_t* __restrict__ O) {
    int gid = blockIdx.x * 256 + threadIdx.x;   // 524288 total
    int row = gid >> 3, j = gid & 7;
    float inv = 1.f / (lsum[row] + lsum[BHL_ + row] +
                       lsum[2 * BHL_ + row] + lsum[3 * BHL_ + row]);
    bf16x8 v0 = *(const bf16x8*)(Op0 + (size_t)row * DH_ + j * 8);
    bf16x8 v1 = *(const bf16x8*)(Op1 + (size_t)row * DH_ + j * 8);
    bf16x8 v2 = *(const bf16x8*)(Op2 + (size_t)row * DH_ + j * 8);
    bf16x8 v3 = *(const bf16x8*)(Op3 + (size_t)row * DH_ + j * 8);
    uint4 o;
    float r0, r1;
#pragma unroll
    for (int k = 0; k < 4; ++k) {
        r0 = ((float)v0[2 * k] + (float)v1[2 * k] + (float)v2[2 * k] + (float)v3[2 * k]) * inv;
        r1 = ((float)v0[2 * k + 1] + (float)v1[2 * k + 1] + (float)v2[2 * k + 1] + (float)v3[2 * k + 1]) * inv;
        ((u32*)&o)[k] = pk_bf16(r0, r1);
    }
    *(uint4*)(O + (size_t)row * DH_ + j * 8) = o;
}

// -----------------------------------------------------------------------------
extern "C" void kernel_launch(void* const* d_in, const int* in_sizes, int n_in,
                              void* d_out, int out_size, void* d_ws, size_t ws_size,
                              hipStream_t stream) {
    (void)in_sizes; (void)n_in; (void)out_size; (void)ws_size;
    const float* x    = (const float*)d_in[0];
    const float* c    = (const float*)d_in[1];
    const float* Wq   = (const float*)d_in[2];
    const float* bq   = (const float*)d_in[3];
    const float* Wk   = (const float*)d_in[4];
    const float* bk   = (const float*)d_in[5];
    const float* Wv   = (const float*)d_in[6];
    const float* bv   = (const float*)d_in[7];
    const float* Wo   = (const float*)d_in[8];
    const float* bo   = (const float*)d_in[9];
    const float* W1   = (const float*)d_in[10];
    const float* b1   = (const float*)d_in[11];
    const float* W2   = (const float*)d_in[12];
    const float* b2   = (const float*)d_in[13];
    const float* Wada = (const float*)d_in[14];
    const float* bada = (const float*)d_in[15];

    char* w = (char*)d_ws;
    float*    ada  = (float*)(w + 0);                     // 49152 B
    ushort_t* Wqkv = (ushort_t*)(w + 49152);              // 6 MiB (lsum after QKV gemm)
    ushort_t* Wo_t = (ushort_t*)(w + 6340608);            // 2 MiB
    ushort_t* W1_t = (ushort_t*)(w + 8437760);            // 4 MiB
    ushort_t* W2_t = (ushort_t*)(w + 12632064);           // 4 MiB
    ushort_t* h    = (ushort_t*)(w + 16826368);           // 8 MiB (h / partial1 / h2)
    ushort_t* Qb   = (ushort_t*)(w + 25214976);           // 8 MiB (Q, then merged O)
    ushort_t* Kb   = (ushort_t*)(w + 33603584);           // 8 MiB
    ushort_t* Vb   = (ushort_t*)(w + 41992192);           // 8 MiB (V, then partial0)
    ushort_t* Vtb  = (ushort_t*)(w + 50380800);           // 8 MiB (ada partials, then V^T)
    float*    x1   = (float*)(w + 58769408);              // 16 MiB (partials 2+3, then x1)
    ushort_t* Ob   = Qb;          // merged O overwrites Q (dead post-attn)
    ushort_t* m1   = Qb;          // MLP hidden (16 MiB = Qb+Kb, dead post O-proj)
    float*    lsb  = (float*)Wqkv;  // 1 MiB l per quarter; Wqkv dead after QKV gemm
    float*    adap = (float*)Vtb;   // 786 KB split-k partials; dead before transpose_v
    ushort_t* p2   = (ushort_t*)x1;                         // partial2 (8 MiB)
    ushort_t* p3   = (ushort_t*)((char*)x1 + 8388608);      // partial3 (8 MiB)

    const int M = B_ * L_;  // 4096

    transpose_w_all<<<2048, 256, 0, stream>>>(Wq, Wk, Wv, Wo, W1, W2,
                                              Wqkv, Wo_t, W1_t, W2_t);

    ada_gemv<<<dim3(24, 16), 256, 0, stream>>>(c, Wada, adap);
    ada_reduce<<<24, 256, 0, stream>>>(adap, bada, ada);
    ln_mod<<<M, 256, 0, stream>>>(x, ada, 0, 1024, h);

    EpiArgs e0 = {bq, bk, bv, Qb, Kb, Vb, nullptr, nullptr, nullptr};
    gemm_bt<0><<<dim3(32, 24), 256, 0, stream>>>(h, Wqkv, M, 3072, D_, e0);

    transpose_v<<<dim3(32, 32), 256, 0, stream>>>(Vb, Vtb);

    // KV-split-4 attention: partials -> Vb, h, x1-lo, x1-hi (all dead regions)
    attn<<<2048, 256, 0, stream>>>(Qb, Kb, Vtb, Vb, h, p2, p3, lsb);
    attn_merge<<<2048, 256, 0, stream>>>(Vb, h, p2, p3, lsb, Ob);

    EpiArgs e1 = {bo, nullptr, nullptr, nullptr, nullptr, nullptr, x, ada + 2048, x1};
    gemm_bt64<2><<<dim3(64, 8), 256, 0, stream>>>(Ob, Wo_t, M, D_, D_, e1);

    ln_mod<<<M, 256, 0, stream>>>(x1, ada, 3072, 4096, h);

    EpiArgs e2 = {b1, nullptr, nullptr, m1, nullptr, nullptr, nullptr, nullptr, nullptr};
    gemm_bt64<1><<<dim3(64, 16), 256, 0, stream>>>(h, W1_t, M, FF_, D_, e2);

    EpiArgs e3 = {b2, nullptr, nullptr, nullptr, nullptr, nullptr, x1, ada + 5120, (float*)d_out};
    gemm_bt64<2><<<dim3(64, 8), 256, 0, stream>>>(m1, W2_t, M, D_, FF_, e3);
}

// Round 4
// 314.701 us; speedup vs baseline: 1.0772x; 1.0211x over previous
//
#include <hip/hip_runtime.h>
#include <hip/hip_bf16.h>

typedef unsigned short ushort_t;
typedef __bf16 bf16x8 __attribute__((ext_vector_type(8)));
typedef float f32x4 __attribute__((ext_vector_type(4)));

typedef unsigned int u32;
typedef u32 __attribute__((address_space(1))) global_u32;
typedef u32 __attribute__((address_space(3))) lds_u32;

#define D_ 1024
#define L_ 2048
#define B_ 2
#define H_ 16
#define DH_ 64
#define FF_ 2048
#define ADA_ 6144
#define BHL_ (B_ * H_ * L_)

#define MFMA __builtin_amdgcn_mfma_f32_16x16x32_bf16

__device__ __forceinline__ ushort_t f2bf(float f) {
    union { float f; u32 u; } v; v.f = f;
    u32 r = v.u + 0x7fffu + ((v.u >> 16) & 1u);
    return (ushort_t)(r >> 16);
}

// packed 2xf32 -> 2xbf16 (v_cvt_pk_bf16_f32)
__device__ __forceinline__ u32 pk_bf16(float a, float b) {
    float2 f; f.x = a; f.y = b;
    __hip_bfloat162 t = __float22bfloat162_rn(f);
    union { __hip_bfloat162 b2; u32 u; } v; v.b2 = t; return v.u;
}

__device__ __forceinline__ void llds16(const ushort_t* src, ushort_t* dst) {
    __builtin_amdgcn_global_load_lds((global_u32*)src, (lds_u32*)dst, 16, 0, 0);
}

// ------- fused weight transpose+convert: all 6 weights, one dispatch ---------
__global__ void transpose_w_all(
    const float* __restrict__ Wq, const float* __restrict__ Wk,
    const float* __restrict__ Wv, const float* __restrict__ Wo,
    const float* __restrict__ W1, const float* __restrict__ W2,
    ushort_t* __restrict__ Wqkv, ushort_t* __restrict__ Wo_t,
    ushort_t* __restrict__ W1_t, ushort_t* __restrict__ W2_t) {
    __shared__ float tile[64][65];
    int id = blockIdx.x;
    const float* W; ushort_t* Wt; int K, N, ntx, lid;
    if (id < 1024) {
        int which = id >> 8; lid = id & 255; K = 1024; N = 1024; ntx = 16;
        W  = which == 0 ? Wq : which == 1 ? Wk : which == 2 ? Wv : Wo;
        Wt = which == 3 ? Wo_t : Wqkv + (size_t)which * 1024 * 1024;
    } else if (id < 1536) {
        lid = id - 1024; W = W1; Wt = W1_t; K = 1024; N = 2048; ntx = 32;
    } else {
        lid = id - 1536; W = W2; Wt = W2_t; K = 2048; N = 1024; ntx = 16;
    }
    int n0 = (lid % ntx) * 64, k0 = (lid / ntx) * 64;
    int t = threadIdx.x;
    for (int p = 0; p < 4; ++p) {
        int k = p * 16 + (t >> 4), nn = (t & 15) * 4;
        float4 v = *(const float4*)(W + (size_t)(k0 + k) * N + n0 + nn);
        tile[k][nn] = v.x; tile[k][nn + 1] = v.y; tile[k][nn + 2] = v.z; tile[k][nn + 3] = v.w;
    }
    __syncthreads();
    for (int p = 0; p < 4; ++p) {
        int n = p * 16 + (t >> 4), kk = (t & 15) * 4;
        ushort4 o;
        o.x = f2bf(tile[kk][n]); o.y = f2bf(tile[kk + 1][n]);
        o.z = f2bf(tile[kk + 2][n]); o.w = f2bf(tile[kk + 3][n]);
        *(ushort4*)(Wt + (size_t)(n0 + n) * K + k0 + kk) = o;
    }
}

// ---------------- ada = silu(c) @ Wada + bada: split-k GEMV ------------------
__global__ void ada_gemv(const float* __restrict__ c, const float* __restrict__ Wada,
                         float* __restrict__ partial) {
    int ks = blockIdx.y;
    int j = blockIdx.x * 256 + threadIdx.x;
    __shared__ float s0[64], s1[64];
    if (threadIdx.x < 64) {
        float v = c[ks * 64 + threadIdx.x];
        s0[threadIdx.x] = v / (1.f + __expf(-v));
        v = c[D_ + ks * 64 + threadIdx.x];
        s1[threadIdx.x] = v / (1.f + __expf(-v));
    }
    __syncthreads();
    float a0 = 0.f, a1 = 0.f;
#pragma unroll 8
    for (int d = 0; d < 64; ++d) {
        float w = Wada[(size_t)(ks * 64 + d) * ADA_ + j];
        a0 = fmaf(s0[d], w, a0);
        a1 = fmaf(s1[d], w, a1);
    }
    partial[(size_t)(ks * 2 + 0) * ADA_ + j] = a0;
    partial[(size_t)(ks * 2 + 1) * ADA_ + j] = a1;
}

__global__ void ada_reduce(const float* __restrict__ partial,
                           const float* __restrict__ bada, float* __restrict__ ada) {
    int j = blockIdx.x * 256 + threadIdx.x;
    float a0 = bada[j], a1 = bada[j];
#pragma unroll
    for (int ks = 0; ks < 16; ++ks) {
        a0 += partial[(size_t)(ks * 2 + 0) * ADA_ + j];
        a1 += partial[(size_t)(ks * 2 + 1) * ADA_ + j];
    }
    ada[j] = a0;
    ada[ADA_ + j] = a1;
}

// ---------------- LayerNorm + modulation -> bf16 -----------------------------
__global__ void ln_mod(const float* __restrict__ x, const float* __restrict__ ada,
                       int so, int co, ushort_t* __restrict__ out) {
    int row = blockIdx.x;
    int b = row >> 11;
    float4 v = ((const float4*)(x + (size_t)row * D_))[threadIdx.x];
    float sum = v.x + v.y + v.z + v.w;
    float sq = v.x * v.x + v.y * v.y + v.z * v.z + v.w * v.w;
    for (int off = 32; off; off >>= 1) { sum += __shfl_down(sum, off); sq += __shfl_down(sq, off); }
    __shared__ float sa[4], sb[4];
    int wave = threadIdx.x >> 6, lane = threadIdx.x & 63;
    if (lane == 0) { sa[wave] = sum; sb[wave] = sq; }
    __syncthreads();
    sum = sa[0] + sa[1] + sa[2] + sa[3];
    sq = sb[0] + sb[1] + sb[2] + sb[3];
    float mean = sum * (1.f / 1024.f);
    float var = sq * (1.f / 1024.f) - mean * mean;
    float rstd = rsqrtf(var + 1e-6f);
    int d = threadIdx.x * 4;
    const float* shf = ada + (size_t)b * ADA_ + so;
    const float* scf = ada + (size_t)b * ADA_ + co;
    uint2 ov;
    ov.x = pk_bf16((v.x - mean) * rstd * (1.f + scf[d + 0]) + shf[d + 0],
                   (v.y - mean) * rstd * (1.f + scf[d + 1]) + shf[d + 1]);
    ov.y = pk_bf16((v.z - mean) * rstd * (1.f + scf[d + 2]) + shf[d + 2],
                   (v.w - mean) * rstd * (1.f + scf[d + 3]) + shf[d + 3]);
    *(uint2*)(out + (size_t)row * D_ + d) = ov;
}

// ---------------- GEMM epilogues ---------------------------------------------
struct EpiArgs {
    const float* bias0; const float* bias1; const float* bias2;
    ushort_t* o0; ushort_t* o1; ushort_t* o2;
    const float* resid; const float* gate;
    float* fout;
};

template <int EPI>
__device__ __forceinline__ void epi_store(float v, int m, int n, int N, const EpiArgs& e) {
    if (EPI == 0) {  // Q/K -> (B,H,L,DH) bf16; Q pre-scaled by log2(e)/8
        int which = n >> 10, cc = n & 1023;
        const float* bias = which == 0 ? e.bias0 : e.bias1;
        ushort_t* ob = which == 0 ? e.o0 : e.o1;
        v += bias[cc];
        if (which == 0) v *= 0.18033688f;  // (1/8) * log2(e): softmax uses exp2
        int b = m >> 11, l = m & 2047, h = cc >> 6, dh = cc & 63;
        ob[(((size_t)(b * H_ + h) * L_) + l) * DH_ + dh] = f2bf(v);
    } else if (EPI == 1) {  // bias + exact GELU -> bf16
        v += e.bias0[n];
        v = 0.5f * v * (1.f + erff(v * 0.70710678118f));
        e.o0[(size_t)m * N + n] = f2bf(v);
    } else {  // residual + gate -> fp32
        int b = m >> 11;
        e.fout[(size_t)m * N + n] =
            e.resid[(size_t)m * N + n] + e.gate[(size_t)b * ADA_ + n] * (v + e.bias0[n]);
    }
}

template <int EPI>
__device__ __forceinline__ void st4(const f32x4& cc, int mb, int n, int N, const EpiArgs& e) {
    if (EPI == 0 && n >= 2048) {
        // V: direct transpose write -> (BH, DH, L) bf16. mb..mb+3 are 4
        // consecutive l within one batch -> contiguous ushort4 in V^T.
        int ccn = n & 1023;
        float b4 = e.bias2[ccn];
        int b = mb >> 11, l0 = mb & 2047, h = ccn >> 6, dh = ccn & 63;
        ushort4 o;
        o.x = f2bf(cc[0] + b4); o.y = f2bf(cc[1] + b4);
        o.z = f2bf(cc[2] + b4); o.w = f2bf(cc[3] + b4);
        *(ushort4*)(e.o2 + ((size_t)(b * H_ + h) * DH_ + dh) * L_ + l0) = o;
        return;
    }
#pragma unroll
    for (int r = 0; r < 4; ++r) epi_store<EPI>(cc[r], mb + r, n, N, e);
}

// ---------------- GEMM 128x128 tile (QKV) ------------------------------------
template <int EPI>
__global__ __launch_bounds__(256, 2) void gemm_bt(
    const ushort_t* __restrict__ A, const ushort_t* __restrict__ Bt,
    int M, int N, int K, EpiArgs e) {
    __shared__ ushort_t As[128 * 64];
    __shared__ ushort_t Bs[128 * 64];
    int m0 = blockIdx.x * 128, n0 = blockIdx.y * 128;
    int tid = threadIdx.x, wave = tid >> 6, lane = tid & 63;
    int quad = lane >> 4, lc = lane & 15;
    int wm = (wave & 1) * 64, wn = (wave >> 1) * 64;
    int srow = lane >> 3, sg = lane & 7;
    int sw = lc & 7;

    const ushort_t* stp[8];
    ushort_t* stl[8];
#pragma unroll
    for (int i = 0; i < 8; ++i) {
        int chunk = wave * 8 + i;
        int c = chunk & 15;
        int row = c * 8 + srow;
        stp[i] = (chunk < 16 ? A + (size_t)(m0 + row) * K
                             : Bt + (size_t)(n0 + row) * K) + (sg ^ srow) * 8;
        stl[i] = (chunk < 16 ? As : Bs) + c * 512 + lane * 8;
    }

    f32x4 c00 = {}, c01 = {}, c02 = {}, c03 = {};
    f32x4 c10 = {}, c11 = {}, c12 = {}, c13 = {};
    f32x4 c20 = {}, c21 = {}, c22 = {}, c23 = {};
    f32x4 c30 = {}, c31 = {}, c32 = {}, c33 = {};

    for (int k0 = 0; k0 < K; k0 += 64) {
#pragma unroll
        for (int i = 0; i < 8; ++i) { llds16(stp[i], stl[i]); stp[i] += 64; }
        __syncthreads();
#pragma unroll
        for (int kk = 0; kk < 2; ++kk) {
            int off = ((kk * 4 + quad) ^ sw) * 8;
            bf16x8 a0 = *(const bf16x8*)&As[(wm +  0 + lc) * 64 + off];
            bf16x8 a1 = *(const bf16x8*)&As[(wm + 16 + lc) * 64 + off];
            bf16x8 a2 = *(const bf16x8*)&As[(wm + 32 + lc) * 64 + off];
            bf16x8 a3 = *(const bf16x8*)&As[(wm + 48 + lc) * 64 + off];
            bf16x8 b0 = *(const bf16x8*)&Bs[(wn +  0 + lc) * 64 + off];
            bf16x8 b1 = *(const bf16x8*)&Bs[(wn + 16 + lc) * 64 + off];
            bf16x8 b2 = *(const bf16x8*)&Bs[(wn + 32 + lc) * 64 + off];
            bf16x8 b3 = *(const bf16x8*)&Bs[(wn + 48 + lc) * 64 + off];
            c00 = MFMA(a0, b0, c00, 0, 0, 0); c01 = MFMA(a0, b1, c01, 0, 0, 0);
            c02 = MFMA(a0, b2, c02, 0, 0, 0); c03 = MFMA(a0, b3, c03, 0, 0, 0);
            c10 = MFMA(a1, b0, c10, 0, 0, 0); c11 = MFMA(a1, b1, c11, 0, 0, 0);
            c12 = MFMA(a1, b2, c12, 0, 0, 0); c13 = MFMA(a1, b3, c13, 0, 0, 0);
            c20 = MFMA(a2, b0, c20, 0, 0, 0); c21 = MFMA(a2, b1, c21, 0, 0, 0);
            c22 = MFMA(a2, b2, c22, 0, 0, 0); c23 = MFMA(a2, b3, c23, 0, 0, 0);
            c30 = MFMA(a3, b0, c30, 0, 0, 0); c31 = MFMA(a3, b1, c31, 0, 0, 0);
            c32 = MFMA(a3, b2, c32, 0, 0, 0); c33 = MFMA(a3, b3, c33, 0, 0, 0);
        }
        __syncthreads();
    }

    int mb = m0 + wm + quad * 4, nb = n0 + wn + lc;
    st4<EPI>(c00, mb +  0, nb +  0, N, e); st4<EPI>(c01, mb +  0, nb + 16, N, e);
    st4<EPI>(c02, mb +  0, nb + 32, N, e); st4<EPI>(c03, mb +  0, nb + 48, N, e);
    st4<EPI>(c10, mb + 16, nb +  0, N, e); st4<EPI>(c11, mb + 16, nb + 16, N, e);
    st4<EPI>(c12, mb + 16, nb + 32, N, e); st4<EPI>(c13, mb + 16, nb + 48, N, e);
    st4<EPI>(c20, mb + 32, nb +  0, N, e); st4<EPI>(c21, mb + 32, nb + 16, N, e);
    st4<EPI>(c22, mb + 32, nb + 32, N, e); st4<EPI>(c23, mb + 32, nb + 48, N, e);
    st4<EPI>(c30, mb + 48, nb +  0, N, e); st4<EPI>(c31, mb + 48, nb + 16, N, e);
    st4<EPI>(c32, mb + 48, nb + 32, N, e); st4<EPI>(c33, mb + 48, nb + 48, N, e);
}

// ---------------- GEMM 64x128 tile: small-N GEMMs need more blocks -----------
template <int EPI>
__global__ __launch_bounds__(256, 2) void gemm_bt64(
    const ushort_t* __restrict__ A, const ushort_t* __restrict__ Bt,
    int M, int N, int K, EpiArgs e) {
    __shared__ ushort_t As[64 * 64];    // 8 KB
    __shared__ ushort_t Bs[128 * 64];   // 16 KB
    int m0 = blockIdx.x * 64, n0 = blockIdx.y * 128;
    int tid = threadIdx.x, wave = tid >> 6, lane = tid & 63;
    int quad = lane >> 4, lc = lane & 15;
    int wn = wave * 32;
    int srow = lane >> 3, sg = lane & 7;
    int sw = lc & 7;

    const ushort_t* stp[6];
    ushort_t* stl[6];
#pragma unroll
    for (int i = 0; i < 6; ++i) {
        int chunk = wave * 6 + i;
        if (chunk < 8) {
            int row = chunk * 8 + srow;
            stp[i] = A + (size_t)(m0 + row) * K + (sg ^ srow) * 8;
            stl[i] = &As[chunk * 512 + lane * 8];
        } else {
            int c = chunk - 8;
            int row = c * 8 + srow;
            stp[i] = Bt + (size_t)(n0 + row) * K + (sg ^ srow) * 8;
            stl[i] = &Bs[c * 512 + lane * 8];
        }
    }

    f32x4 c00 = {}, c01 = {};
    f32x4 c10 = {}, c11 = {};
    f32x4 c20 = {}, c21 = {};
    f32x4 c30 = {}, c31 = {};

    for (int k0 = 0; k0 < K; k0 += 64) {
#pragma unroll
        for (int i = 0; i < 6; ++i) { llds16(stp[i], stl[i]); stp[i] += 64; }
        __syncthreads();
#pragma unroll
        for (int kk = 0; kk < 2; ++kk) {
            int off = ((kk * 4 + quad) ^ sw) * 8;
            bf16x8 a0 = *(const bf16x8*)&As[( 0 + lc) * 64 + off];
            bf16x8 a1 = *(const bf16x8*)&As[(16 + lc) * 64 + off];
            bf16x8 a2 = *(const bf16x8*)&As[(32 + lc) * 64 + off];
            bf16x8 a3 = *(const bf16x8*)&As[(48 + lc) * 64 + off];
            bf16x8 b0 = *(const bf16x8*)&Bs[(wn +  0 + lc) * 64 + off];
            bf16x8 b1 = *(const bf16x8*)&Bs[(wn + 16 + lc) * 64 + off];
            c00 = MFMA(a0, b0, c00, 0, 0, 0); c01 = MFMA(a0, b1, c01, 0, 0, 0);
            c10 = MFMA(a1, b0, c10, 0, 0, 0); c11 = MFMA(a1, b1, c11, 0, 0, 0);
            c20 = MFMA(a2, b0, c20, 0, 0, 0); c21 = MFMA(a2, b1, c21, 0, 0, 0);
            c30 = MFMA(a3, b0, c30, 0, 0, 0); c31 = MFMA(a3, b1, c31, 0, 0, 0);
        }
        __syncthreads();
    }

    int mb = m0 + quad * 4, nb = n0 + wn + lc;
    st4<EPI>(c00, mb +  0, nb + 0, N, e); st4<EPI>(c01, mb +  0, nb + 16, N, e);
    st4<EPI>(c10, mb + 16, nb + 0, N, e); st4<EPI>(c11, mb + 16, nb + 16, N, e);
    st4<EPI>(c20, mb + 32, nb + 0, N, e); st4<EPI>(c21, mb + 32, nb + 16, N, e);
    st4<EPI>(c30, mb + 48, nb + 0, N, e); st4<EPI>(c31, mb + 48, nb + 16, N, e);
}

// ---------------- flash attention v13: full-KV loop, direct final O ----------
// grid 512: bits[4:0] bh (XCD-spread: blocks sharing bh land on one XCD ->
// K/V L2-resident), [8:5] q-tile. Each block: 128 q-rows x full 2048 kv
// (16 tiles of 128). v13 vs v12: KV-split-4 removed -- same 2 blocks/CU
// concurrency (512 blocks = 256 CU x 2), but partial-O writes (25 MB), lsum,
// and the attn_merge kernel all disappear; O is normalized in-register from
// the MFMA rowsums and written once as bf16. f32 accumulation across all kv
// (more accurate than bf16-rounded quarter partials).
__global__ __launch_bounds__(256, 2) void attn(
    const ushort_t* __restrict__ Q, const ushort_t* __restrict__ Kx,
    const ushort_t* __restrict__ Vt, ushort_t* __restrict__ O) {
    __shared__ ushort_t Ks[128 * 64];     // 16 KB
    __shared__ ushort_t Vs[64 * 128];     // 16 KB
    int id = blockIdx.x;
    int bh = ((id & 7) << 2) + ((id >> 3) & 3);  // 4 bh per XCD class
    int qt = id >> 5;                            // 16 q-tiles of 128 rows
    const ushort_t* Qg = Q + ((size_t)bh * L_ + qt * 128) * DH_;
    const ushort_t* Kg = Kx + (size_t)bh * L_ * DH_;
    const ushort_t* Vg = Vt + (size_t)bh * DH_ * L_;
    int tid = threadIdx.x, wave = tid >> 6, lane = tid & 63;
    int quad = lane >> 4, lc = lane & 15;
    int sw = lc & 7;
    int srow = lane >> 3, sg = lane & 7;

    // hoisted staging: waves 0,1 stage K (sig-permuted rows); waves 2,3 stage V
    const ushort_t* stp[8];
    ushort_t* stl[8];
    int stinc;
    if (wave < 2) {
        stinc = 128 * DH_;
#pragma unroll
        for (int i = 0; i < 8; ++i) {
            int chunk = wave * 8 + i;
            int slot = chunk * 8 + srow;         // LDS row (slot)
            int s5 = slot & 31;                  // within-32 position
            int sig = (slot & ~31) + ((s5 & 15) >> 2) * 8 + (s5 & 3) + (s5 >> 4) * 4;
            stp[i] = Kg + (size_t)sig * DH_ + (sg ^ srow) * 8;
            stl[i] = &Ks[chunk * 512 + lane * 8];
        }
    } else {
        stinc = 128;
#pragma unroll
        for (int i = 0; i < 8; ++i) {
            int c2 = (wave - 2) * 8 + i;
            int row = c2 * 4 + (lane >> 4);
            int g = (lane & 15) ^ (row & 15);
            stp[i] = Vg + (size_t)row * L_ + g * 8;
            stl[i] = &Vs[c2 * 512 + lane * 8];
        }
    }

    // Q fragments straight from global (block-private, read once)
    const ushort_t* qp = Qg + (size_t)(wave * 32 + lc) * DH_ + quad * 8;
    bf16x8 q00 = *(const bf16x8*)(qp);                  // pass0 kk0
    bf16x8 q01 = *(const bf16x8*)(qp + 32);             // pass0 kk1
    bf16x8 q10 = *(const bf16x8*)(qp + 16 * DH_);       // pass1 kk0
    bf16x8 q11 = *(const bf16x8*)(qp + 16 * DH_ + 32);  // pass1 kk1

    // all-ones bf16 B operand for MFMA row-sums (1.0bf16 = 0x3F80)
    union { u32 u[4]; bf16x8 v; } ones;
    ones.u[0] = ones.u[1] = ones.u[2] = ones.u[3] = 0x3F803F80u;

    f32x4 o00 = {}, o01 = {}, o02 = {}, o03 = {};
    f32x4 o10 = {}, o11 = {}, o12 = {}, o13 = {};
    f32x4 osum0 = {}, osum1 = {};   // rowsum accumulators (cols redundant)

    for (int t = 0; t < 16; ++t) {
#pragma unroll
        for (int i = 0; i < 8; ++i) { llds16(stp[i], stl[i]); stp[i] += stinc; }
        __syncthreads();

        // S^T = K Q^T: C[slot][q], lane holds q=lc, slot = ni*16 + quad*4 + r;
        // via sig-permuted staging, slot maps to kv so that lane-local packed
        // values form the PV A-fragment directly.
        f32x4 s[2][8];
        __builtin_amdgcn_s_setprio(1);
#pragma unroll
        for (int kk = 0; kk < 2; ++kk) {
            int off = ((kk * 4 + quad) ^ sw) * 8;
            bf16x8 aq0 = kk == 0 ? q00 : q01;
            bf16x8 aq1 = kk == 0 ? q10 : q11;
#pragma unroll
            for (int ni = 0; ni < 8; ++ni) {
                bf16x8 bk = *(const bf16x8*)&Ks[(ni * 16 + lc) * 64 + off];
                if (kk == 0) {
                    f32x4 z = {0.f, 0.f, 0.f, 0.f};
                    s[0][ni] = MFMA(bk, aq0, z, 0, 0, 0);
                    s[1][ni] = MFMA(bk, aq1, z, 0, 0, 0);
                } else {
                    s[0][ni] = MFMA(bk, aq0, s[0][ni], 0, 0, 0);
                    s[1][ni] = MFMA(bk, aq1, s[1][ni], 0, 0, 0);
                }
            }
        }
        __builtin_amdgcn_s_setprio(0);

        // softmax numerator: p = exp2(s), pack to bf16 pairs in regs
        u32 px[2][8], py[2][8];
#pragma unroll
        for (int pi = 0; pi < 2; ++pi) {
#pragma unroll
            for (int ni = 0; ni < 8; ++ni) {
                float p0 = __builtin_amdgcn_exp2f(s[pi][ni][0]);
                float p1 = __builtin_amdgcn_exp2f(s[pi][ni][1]);
                float p2 = __builtin_amdgcn_exp2f(s[pi][ni][2]);
                float p3 = __builtin_amdgcn_exp2f(s[pi][ni][3]);
                px[pi][ni] = pk_bf16(p0, p1);
                py[pi][ni] = pk_bf16(p2, p3);
            }
        }

        // PV: A-fragment for kv-chunk kk is {px[2kk],py[2kk],px[2kk+1],py[2kk+1]}
        // (lane-local, thanks to sig). One V read feeds both passes. Rowsums
        // ride the same A-fragments against the ones operand.
        __builtin_amdgcn_s_setprio(1);
#pragma unroll
        for (int kk = 0; kk < 4; ++kk) {
            int gq = kk * 4 + quad;
            bf16x8 bv0 = *(const bf16x8*)&Vs[( 0 + lc) * 128 + ((gq ^ lc) * 8)];
            bf16x8 bv1 = *(const bf16x8*)&Vs[(16 + lc) * 128 + ((gq ^ lc) * 8)];
            bf16x8 bv2 = *(const bf16x8*)&Vs[(32 + lc) * 128 + ((gq ^ lc) * 8)];
            bf16x8 bv3 = *(const bf16x8*)&Vs[(48 + lc) * 128 + ((gq ^ lc) * 8)];
            union { u32 u[4]; bf16x8 v; } a0, a1;
            a0.u[0] = px[0][2 * kk]; a0.u[1] = py[0][2 * kk];
            a0.u[2] = px[0][2 * kk + 1]; a0.u[3] = py[0][2 * kk + 1];
            a1.u[0] = px[1][2 * kk]; a1.u[1] = py[1][2 * kk];
            a1.u[2] = px[1][2 * kk + 1]; a1.u[3] = py[1][2 * kk + 1];
            o00 = MFMA(a0.v, bv0, o00, 0, 0, 0); o01 = MFMA(a0.v, bv1, o01, 0, 0, 0);
            o02 = MFMA(a0.v, bv2, o02, 0, 0, 0); o03 = MFMA(a0.v, bv3, o03, 0, 0, 0);
            o10 = MFMA(a1.v, bv0, o10, 0, 0, 0); o11 = MFMA(a1.v, bv1, o11, 0, 0, 0);
            o12 = MFMA(a1.v, bv2, o12, 0, 0, 0); o13 = MFMA(a1.v, bv3, o13, 0, 0, 0);
            osum0 = MFMA(a0.v, ones.v, osum0, 0, 0, 0);
            osum1 = MFMA(a1.v, ones.v, osum1, 0, 0, 0);
        }
        __builtin_amdgcn_s_setprio(0);
        __syncthreads();  // Ks/Vs consumed before next tile's staging
    }

    // normalize in-register (rowsum identical across lc lanes) and write final
    // O bf16 in (BH, L, DH) "mix" layout; PV C-layout rows = quad*4+r
    f32x4 inv0, inv1;
#pragma unroll
    for (int r = 0; r < 4; ++r) { inv0[r] = 1.f / osum0[r]; inv1[r] = 1.f / osum1[r]; }
#pragma unroll
    for (int pi = 0; pi < 2; ++pi) {
        const f32x4& iv = pi == 0 ? inv0 : inv1;
#pragma unroll
        for (int nio = 0; nio < 4; ++nio) {
            const f32x4& ov = pi == 0 ? (nio == 0 ? o00 : nio == 1 ? o01 : nio == 2 ? o02 : o03)
                                      : (nio == 0 ? o10 : nio == 1 ? o11 : nio == 2 ? o12 : o13);
#pragma unroll
            for (int r = 0; r < 4; ++r) {
                int row = qt * 128 + wave * 32 + pi * 16 + quad * 4 + r;
                O[((size_t)bh * L_ + row) * DH_ + nio * 16 + lc] = f2bf(ov[r] * iv[r]);
            }
        }
    }
}

// -----------------------------------------------------------------------------
extern "C" void kernel_launch(void* const* d_in, const int* in_sizes, int n_in,
                              void* d_out, int out_size, void* d_ws, size_t ws_size,
                              hipStream_t stream) {
    (void)in_sizes; (void)n_in; (void)out_size; (void)ws_size;
    const float* x    = (const float*)d_in[0];
    const float* c    = (const float*)d_in[1];
    const float* Wq   = (const float*)d_in[2];
    const float* bq   = (const float*)d_in[3];
    const float* Wk   = (const float*)d_in[4];
    const float* bk   = (const float*)d_in[5];
    const float* Wv   = (const float*)d_in[6];
    const float* bv   = (const float*)d_in[7];
    const float* Wo   = (const float*)d_in[8];
    const float* bo   = (const float*)d_in[9];
    const float* W1   = (const float*)d_in[10];
    const float* b1   = (const float*)d_in[11];
    const float* W2   = (const float*)d_in[12];
    const float* b2   = (const float*)d_in[13];
    const float* Wada = (const float*)d_in[14];
    const float* bada = (const float*)d_in[15];

    char* w = (char*)d_ws;
    float*    ada  = (float*)(w + 0);                     // 49152 B
    ushort_t* Wqkv = (ushort_t*)(w + 49152);              // 6 MiB
    ushort_t* Wo_t = (ushort_t*)(w + 6340608);            // 2 MiB
    ushort_t* W1_t = (ushort_t*)(w + 8437760);            // 4 MiB
    ushort_t* W2_t = (ushort_t*)(w + 12632064);           // 4 MiB
    ushort_t* h    = (ushort_t*)(w + 16826368);           // 8 MiB (h / h2)
    ushort_t* Qb   = (ushort_t*)(w + 25214976);           // 8 MiB (Q)
    ushort_t* Kb   = (ushort_t*)(w + 33603584);           // 8 MiB (K)
    ushort_t* Ob   = (ushort_t*)(w + 41992192);           // 8 MiB (final O)
    ushort_t* Vtb  = (ushort_t*)(w + 50380800);           // 8 MiB (ada partials, then V^T)
    float*    x1   = (float*)(w + 58769408);              // 16 MiB (x1)
    ushort_t* m1   = Qb;            // MLP hidden (16 MiB = Qb+Kb, dead post-attn)
    float*    adap = (float*)Vtb;   // 786 KB split-k partials; dead before QKV gemm

    const int M = B_ * L_;  // 4096

    transpose_w_all<<<2048, 256, 0, stream>>>(Wq, Wk, Wv, Wo, W1, W2,
                                              Wqkv, Wo_t, W1_t, W2_t);

    ada_gemv<<<dim3(24, 16), 256, 0, stream>>>(c, Wada, adap);
    ada_reduce<<<24, 256, 0, stream>>>(adap, bada, ada);
    ln_mod<<<M, 256, 0, stream>>>(x, ada, 0, 1024, h);

    // QKV: Q,K -> (B,H,L,DH); V -> V^T (BH,DH,L) directly (transpose_v fused)
    EpiArgs e0 = {bq, bk, bv, Qb, Kb, Vtb, nullptr, nullptr, nullptr};
    gemm_bt<0><<<dim3(32, 24), 256, 0, stream>>>(h, Wqkv, M, 3072, D_, e0);

    // full-KV attention: final O, no partials, no merge
    attn<<<512, 256, 0, stream>>>(Qb, Kb, Vtb, Ob);

    EpiArgs e1 = {bo, nullptr, nullptr, nullptr, nullptr, nullptr, x, ada + 2048, x1};
    gemm_bt64<2><<<dim3(64, 8), 256, 0, stream>>>(Ob, Wo_t, M, D_, D_, e1);

    ln_mod<<<M, 256, 0, stream>>>(x1, ada, 3072, 4096, h);

    EpiArgs e2 = {b1, nullptr, nullptr, m1, nullptr, nullptr, nullptr, nullptr, nullptr};
    gemm_bt64<1><<<dim3(64, 16), 256, 0, stream>>>(h, W1_t, M, FF_, D_, e2);

    EpiArgs e3 = {b2, nullptr, nullptr, nullptr, nullptr, nullptr, x1, ada + 5120, (float*)d_out};
    gemm_bt64<2><<<dim3(64, 8), 256, 0, stream>>>(m1, W2_t, M, D_, FF_, e3);
}

// Round 5
// 309.204 us; speedup vs baseline: 1.0964x; 1.0178x over previous
//
#include <hip/hip_runtime.h>
#include <hip/hip_bf16.h>

typedef unsigned short ushort_t;
typedef __bf16 bf16x8 __attribute__((ext_vector_type(8)));
typedef float f32x4 __attribute__((ext_vector_type(4)));

typedef unsigned int u32;
typedef u32 __attribute__((address_space(1))) global_u32;
typedef u32 __attribute__((address_space(3))) lds_u32;

#define D_ 1024
#define L_ 2048
#define B_ 2
#define H_ 16
#define DH_ 64
#define FF_ 2048
#define ADA_ 6144
#define BHL_ (B_ * H_ * L_)

#define MFMA __builtin_amdgcn_mfma_f32_16x16x32_bf16

__device__ __forceinline__ ushort_t f2bf(float f) {
    union { float f; u32 u; } v; v.f = f;
    u32 r = v.u + 0x7fffu + ((v.u >> 16) & 1u);
    return (ushort_t)(r >> 16);
}

// packed 2xf32 -> 2xbf16 (v_cvt_pk_bf16_f32)
__device__ __forceinline__ u32 pk_bf16(float a, float b) {
    float2 f; f.x = a; f.y = b;
    __hip_bfloat162 t = __float22bfloat162_rn(f);
    union { __hip_bfloat162 b2; u32 u; } v; v.b2 = t; return v.u;
}

__device__ __forceinline__ void llds16(const ushort_t* src, ushort_t* dst) {
    __builtin_amdgcn_global_load_lds((global_u32*)src, (lds_u32*)dst, 16, 0, 0);
}

// ------- fused weight transpose+convert: all 6 weights, one dispatch ---------
__global__ void transpose_w_all(
    const float* __restrict__ Wq, const float* __restrict__ Wk,
    const float* __restrict__ Wv, const float* __restrict__ Wo,
    const float* __restrict__ W1, const float* __restrict__ W2,
    ushort_t* __restrict__ Wqkv, ushort_t* __restrict__ Wo_t,
    ushort_t* __restrict__ W1_t, ushort_t* __restrict__ W2_t) {
    __shared__ float tile[64][65];
    int id = blockIdx.x;
    const float* W; ushort_t* Wt; int K, N, ntx, lid;
    if (id < 1024) {
        int which = id >> 8; lid = id & 255; K = 1024; N = 1024; ntx = 16;
        W  = which == 0 ? Wq : which == 1 ? Wk : which == 2 ? Wv : Wo;
        Wt = which == 3 ? Wo_t : Wqkv + (size_t)which * 1024 * 1024;
    } else if (id < 1536) {
        lid = id - 1024; W = W1; Wt = W1_t; K = 1024; N = 2048; ntx = 32;
    } else {
        lid = id - 1536; W = W2; Wt = W2_t; K = 2048; N = 1024; ntx = 16;
    }
    int n0 = (lid % ntx) * 64, k0 = (lid / ntx) * 64;
    int t = threadIdx.x;
    for (int p = 0; p < 4; ++p) {
        int k = p * 16 + (t >> 4), nn = (t & 15) * 4;
        float4 v = *(const float4*)(W + (size_t)(k0 + k) * N + n0 + nn);
        tile[k][nn] = v.x; tile[k][nn + 1] = v.y; tile[k][nn + 2] = v.z; tile[k][nn + 3] = v.w;
    }
    __syncthreads();
    for (int p = 0; p < 4; ++p) {
        int n = p * 16 + (t >> 4), kk = (t & 15) * 4;
        ushort4 o;
        o.x = f2bf(tile[kk][n]); o.y = f2bf(tile[kk + 1][n]);
        o.z = f2bf(tile[kk + 2][n]); o.w = f2bf(tile[kk + 3][n]);
        *(ushort4*)(Wt + (size_t)(n0 + n) * K + k0 + kk) = o;
    }
}

// ---------------- ada = silu(c) @ Wada + bada: split-k GEMV ------------------
__global__ void ada_gemv(const float* __restrict__ c, const float* __restrict__ Wada,
                         float* __restrict__ partial) {
    int ks = blockIdx.y;
    int j = blockIdx.x * 256 + threadIdx.x;
    __shared__ float s0[64], s1[64];
    if (threadIdx.x < 64) {
        float v = c[ks * 64 + threadIdx.x];
        s0[threadIdx.x] = v / (1.f + __expf(-v));
        v = c[D_ + ks * 64 + threadIdx.x];
        s1[threadIdx.x] = v / (1.f + __expf(-v));
    }
    __syncthreads();
    float a0 = 0.f, a1 = 0.f;
#pragma unroll 8
    for (int d = 0; d < 64; ++d) {
        float w = Wada[(size_t)(ks * 64 + d) * ADA_ + j];
        a0 = fmaf(s0[d], w, a0);
        a1 = fmaf(s1[d], w, a1);
    }
    partial[(size_t)(ks * 2 + 0) * ADA_ + j] = a0;
    partial[(size_t)(ks * 2 + 1) * ADA_ + j] = a1;
}

__global__ void ada_reduce(const float* __restrict__ partial,
                           const float* __restrict__ bada, float* __restrict__ ada) {
    int j = blockIdx.x * 256 + threadIdx.x;
    float a0 = bada[j], a1 = bada[j];
#pragma unroll
    for (int ks = 0; ks < 16; ++ks) {
        a0 += partial[(size_t)(ks * 2 + 0) * ADA_ + j];
        a1 += partial[(size_t)(ks * 2 + 1) * ADA_ + j];
    }
    ada[j] = a0;
    ada[ADA_ + j] = a1;
}

// ---------------- LayerNorm + modulation -> bf16 -----------------------------
__global__ void ln_mod(const float* __restrict__ x, const float* __restrict__ ada,
                       int so, int co, ushort_t* __restrict__ out) {
    int row = blockIdx.x;
    int b = row >> 11;
    float4 v = ((const float4*)(x + (size_t)row * D_))[threadIdx.x];
    float sum = v.x + v.y + v.z + v.w;
    float sq = v.x * v.x + v.y * v.y + v.z * v.z + v.w * v.w;
    for (int off = 32; off; off >>= 1) { sum += __shfl_down(sum, off); sq += __shfl_down(sq, off); }
    __shared__ float sa[4], sb[4];
    int wave = threadIdx.x >> 6, lane = threadIdx.x & 63;
    if (lane == 0) { sa[wave] = sum; sb[wave] = sq; }
    __syncthreads();
    sum = sa[0] + sa[1] + sa[2] + sa[3];
    sq = sb[0] + sb[1] + sb[2] + sb[3];
    float mean = sum * (1.f / 1024.f);
    float var = sq * (1.f / 1024.f) - mean * mean;
    float rstd = rsqrtf(var + 1e-6f);
    int d = threadIdx.x * 4;
    const float* shf = ada + (size_t)b * ADA_ + so;
    const float* scf = ada + (size_t)b * ADA_ + co;
    uint2 ov;
    ov.x = pk_bf16((v.x - mean) * rstd * (1.f + scf[d + 0]) + shf[d + 0],
                   (v.y - mean) * rstd * (1.f + scf[d + 1]) + shf[d + 1]);
    ov.y = pk_bf16((v.z - mean) * rstd * (1.f + scf[d + 2]) + shf[d + 2],
                   (v.w - mean) * rstd * (1.f + scf[d + 3]) + shf[d + 3]);
    *(uint2*)(out + (size_t)row * D_ + d) = ov;
}

// ---------------- GEMM epilogues ---------------------------------------------
struct EpiArgs {
    const float* bias0; const float* bias1; const float* bias2;
    ushort_t* o0; ushort_t* o1; ushort_t* o2;
    const float* resid; const float* gate;
    float* fout;
};

template <int EPI>
__device__ __forceinline__ void epi_store(float v, int m, int n, int N, const EpiArgs& e) {
    if (EPI == 0) {  // Q/K -> (B,H,L,DH) bf16; Q pre-scaled by log2(e)/8
        int which = n >> 10, cc = n & 1023;
        const float* bias = which == 0 ? e.bias0 : e.bias1;
        ushort_t* ob = which == 0 ? e.o0 : e.o1;
        v += bias[cc];
        if (which == 0) v *= 0.18033688f;  // (1/8) * log2(e): softmax uses exp2
        int b = m >> 11, l = m & 2047, h = cc >> 6, dh = cc & 63;
        ob[(((size_t)(b * H_ + h) * L_) + l) * DH_ + dh] = f2bf(v);
    } else if (EPI == 1) {  // bias + exact GELU -> bf16
        v += e.bias0[n];
        v = 0.5f * v * (1.f + erff(v * 0.70710678118f));
        e.o0[(size_t)m * N + n] = f2bf(v);
    } else {  // residual + gate -> fp32
        int b = m >> 11;
        e.fout[(size_t)m * N + n] =
            e.resid[(size_t)m * N + n] + e.gate[(size_t)b * ADA_ + n] * (v + e.bias0[n]);
    }
}

template <int EPI>
__device__ __forceinline__ void st4(const f32x4& cc, int mb, int n, int N, const EpiArgs& e) {
    if (EPI == 0 && n >= 2048) {
        // V: direct transpose write -> (BH, DH, L) bf16. mb..mb+3 are 4
        // consecutive l within one batch -> contiguous ushort4 in V^T.
        int ccn = n & 1023;
        float b4 = e.bias2[ccn];
        int b = mb >> 11, l0 = mb & 2047, h = ccn >> 6, dh = ccn & 63;
        ushort4 o;
        o.x = f2bf(cc[0] + b4); o.y = f2bf(cc[1] + b4);
        o.z = f2bf(cc[2] + b4); o.w = f2bf(cc[3] + b4);
        *(ushort4*)(e.o2 + ((size_t)(b * H_ + h) * DH_ + dh) * L_ + l0) = o;
        return;
    }
#pragma unroll
    for (int r = 0; r < 4; ++r) epi_store<EPI>(cc[r], mb + r, n, N, e);
}

// ---------------- GEMM 128x128 tile (QKV) ------------------------------------
template <int EPI>
__global__ __launch_bounds__(256, 2) void gemm_bt(
    const ushort_t* __restrict__ A, const ushort_t* __restrict__ Bt,
    int M, int N, int K, EpiArgs e) {
    __shared__ ushort_t As[128 * 64];
    __shared__ ushort_t Bs[128 * 64];
    int m0 = blockIdx.x * 128, n0 = blockIdx.y * 128;
    int tid = threadIdx.x, wave = tid >> 6, lane = tid & 63;
    int quad = lane >> 4, lc = lane & 15;
    int wm = (wave & 1) * 64, wn = (wave >> 1) * 64;
    int srow = lane >> 3, sg = lane & 7;
    int sw = lc & 7;

    const ushort_t* stp[8];
    ushort_t* stl[8];
#pragma unroll
    for (int i = 0; i < 8; ++i) {
        int chunk = wave * 8 + i;
        int c = chunk & 15;
        int row = c * 8 + srow;
        stp[i] = (chunk < 16 ? A + (size_t)(m0 + row) * K
                             : Bt + (size_t)(n0 + row) * K) + (sg ^ srow) * 8;
        stl[i] = (chunk < 16 ? As : Bs) + c * 512 + lane * 8;
    }

    f32x4 c00 = {}, c01 = {}, c02 = {}, c03 = {};
    f32x4 c10 = {}, c11 = {}, c12 = {}, c13 = {};
    f32x4 c20 = {}, c21 = {}, c22 = {}, c23 = {};
    f32x4 c30 = {}, c31 = {}, c32 = {}, c33 = {};

    for (int k0 = 0; k0 < K; k0 += 64) {
#pragma unroll
        for (int i = 0; i < 8; ++i) { llds16(stp[i], stl[i]); stp[i] += 64; }
        __syncthreads();
#pragma unroll
        for (int kk = 0; kk < 2; ++kk) {
            int off = ((kk * 4 + quad) ^ sw) * 8;
            bf16x8 a0 = *(const bf16x8*)&As[(wm +  0 + lc) * 64 + off];
            bf16x8 a1 = *(const bf16x8*)&As[(wm + 16 + lc) * 64 + off];
            bf16x8 a2 = *(const bf16x8*)&As[(wm + 32 + lc) * 64 + off];
            bf16x8 a3 = *(const bf16x8*)&As[(wm + 48 + lc) * 64 + off];
            bf16x8 b0 = *(const bf16x8*)&Bs[(wn +  0 + lc) * 64 + off];
            bf16x8 b1 = *(const bf16x8*)&Bs[(wn + 16 + lc) * 64 + off];
            bf16x8 b2 = *(const bf16x8*)&Bs[(wn + 32 + lc) * 64 + off];
            bf16x8 b3 = *(const bf16x8*)&Bs[(wn + 48 + lc) * 64 + off];
            c00 = MFMA(a0, b0, c00, 0, 0, 0); c01 = MFMA(a0, b1, c01, 0, 0, 0);
            c02 = MFMA(a0, b2, c02, 0, 0, 0); c03 = MFMA(a0, b3, c03, 0, 0, 0);
            c10 = MFMA(a1, b0, c10, 0, 0, 0); c11 = MFMA(a1, b1, c11, 0, 0, 0);
            c12 = MFMA(a1, b2, c12, 0, 0, 0); c13 = MFMA(a1, b3, c13, 0, 0, 0);
            c20 = MFMA(a2, b0, c20, 0, 0, 0); c21 = MFMA(a2, b1, c21, 0, 0, 0);
            c22 = MFMA(a2, b2, c22, 0, 0, 0); c23 = MFMA(a2, b3, c23, 0, 0, 0);
            c30 = MFMA(a3, b0, c30, 0, 0, 0); c31 = MFMA(a3, b1, c31, 0, 0, 0);
            c32 = MFMA(a3, b2, c32, 0, 0, 0); c33 = MFMA(a3, b3, c33, 0, 0, 0);
        }
        __syncthreads();
    }

    int mb = m0 + wm + quad * 4, nb = n0 + wn + lc;
    st4<EPI>(c00, mb +  0, nb +  0, N, e); st4<EPI>(c01, mb +  0, nb + 16, N, e);
    st4<EPI>(c02, mb +  0, nb + 32, N, e); st4<EPI>(c03, mb +  0, nb + 48, N, e);
    st4<EPI>(c10, mb + 16, nb +  0, N, e); st4<EPI>(c11, mb + 16, nb + 16, N, e);
    st4<EPI>(c12, mb + 16, nb + 32, N, e); st4<EPI>(c13, mb + 16, nb + 48, N, e);
    st4<EPI>(c20, mb + 32, nb +  0, N, e); st4<EPI>(c21, mb + 32, nb + 16, N, e);
    st4<EPI>(c22, mb + 32, nb + 32, N, e); st4<EPI>(c23, mb + 32, nb + 48, N, e);
    st4<EPI>(c30, mb + 48, nb +  0, N, e); st4<EPI>(c31, mb + 48, nb + 16, N, e);
    st4<EPI>(c32, mb + 48, nb + 32, N, e); st4<EPI>(c33, mb + 48, nb + 48, N, e);
}

// ---------------- GEMM 64x128 tile: small-N GEMMs need more blocks -----------
template <int EPI>
__global__ __launch_bounds__(256, 2) void gemm_bt64(
    const ushort_t* __restrict__ A, const ushort_t* __restrict__ Bt,
    int M, int N, int K, EpiArgs e) {
    __shared__ ushort_t As[64 * 64];    // 8 KB
    __shared__ ushort_t Bs[128 * 64];   // 16 KB
    int m0 = blockIdx.x * 64, n0 = blockIdx.y * 128;
    int tid = threadIdx.x, wave = tid >> 6, lane = tid & 63;
    int quad = lane >> 4, lc = lane & 15;
    int wn = wave * 32;
    int srow = lane >> 3, sg = lane & 7;
    int sw = lc & 7;

    const ushort_t* stp[6];
    ushort_t* stl[6];
#pragma unroll
    for (int i = 0; i < 6; ++i) {
        int chunk = wave * 6 + i;
        if (chunk < 8) {
            int row = chunk * 8 + srow;
            stp[i] = A + (size_t)(m0 + row) * K + (sg ^ srow) * 8;
            stl[i] = &As[chunk * 512 + lane * 8];
        } else {
            int c = chunk - 8;
            int row = c * 8 + srow;
            stp[i] = Bt + (size_t)(n0 + row) * K + (sg ^ srow) * 8;
            stl[i] = &Bs[c * 512 + lane * 8];
        }
    }

    f32x4 c00 = {}, c01 = {};
    f32x4 c10 = {}, c11 = {};
    f32x4 c20 = {}, c21 = {};
    f32x4 c30 = {}, c31 = {};

    for (int k0 = 0; k0 < K; k0 += 64) {
#pragma unroll
        for (int i = 0; i < 6; ++i) { llds16(stp[i], stl[i]); stp[i] += 64; }
        __syncthreads();
#pragma unroll
        for (int kk = 0; kk < 2; ++kk) {
            int off = ((kk * 4 + quad) ^ sw) * 8;
            bf16x8 a0 = *(const bf16x8*)&As[( 0 + lc) * 64 + off];
            bf16x8 a1 = *(const bf16x8*)&As[(16 + lc) * 64 + off];
            bf16x8 a2 = *(const bf16x8*)&As[(32 + lc) * 64 + off];
            bf16x8 a3 = *(const bf16x8*)&As[(48 + lc) * 64 + off];
            bf16x8 b0 = *(const bf16x8*)&Bs[(wn +  0 + lc) * 64 + off];
            bf16x8 b1 = *(const bf16x8*)&Bs[(wn + 16 + lc) * 64 + off];
            c00 = MFMA(a0, b0, c00, 0, 0, 0); c01 = MFMA(a0, b1, c01, 0, 0, 0);
            c10 = MFMA(a1, b0, c10, 0, 0, 0); c11 = MFMA(a1, b1, c11, 0, 0, 0);
            c20 = MFMA(a2, b0, c20, 0, 0, 0); c21 = MFMA(a2, b1, c21, 0, 0, 0);
            c30 = MFMA(a3, b0, c30, 0, 0, 0); c31 = MFMA(a3, b1, c31, 0, 0, 0);
        }
        __syncthreads();
    }

    int mb = m0 + quad * 4, nb = n0 + wn + lc;
    st4<EPI>(c00, mb +  0, nb + 0, N, e); st4<EPI>(c01, mb +  0, nb + 16, N, e);
    st4<EPI>(c10, mb + 16, nb + 0, N, e); st4<EPI>(c11, mb + 16, nb + 16, N, e);
    st4<EPI>(c20, mb + 32, nb + 0, N, e); st4<EPI>(c21, mb + 32, nb + 16, N, e);
    st4<EPI>(c30, mb + 48, nb + 0, N, e); st4<EPI>(c31, mb + 48, nb + 16, N, e);
}

// ---------------- flash attention v14: 8-wave blocks (TLP) -------------------
// grid 512: bits[4:0] bh (XCD-spread: blocks sharing bh land on one XCD ->
// K/V L2-resident), [8:5] q-tile. Each block: 512 threads (8 waves), 128
// q-rows x full 2048 kv (16 tiles of 128). v14 vs v13: each wave owns 16
// q-rows (one pass) instead of 32 (two passes); K/V staging per block is
// unchanged (32 chunks spread 4-per-wave). Per-CU residency doubles to 16
// waves -> cross-wave overlap hides the per-tile serial chain (QK^T -> exp2/
// pack -> PV) that capped v13 at 16% occupancy / 31% MfmaUtil.
__global__ __launch_bounds__(512, 4) void attn(
    const ushort_t* __restrict__ Q, const ushort_t* __restrict__ Kx,
    const ushort_t* __restrict__ Vt, ushort_t* __restrict__ O) {
    __shared__ ushort_t Ks[128 * 64];     // 16 KB
    __shared__ ushort_t Vs[64 * 128];     // 16 KB
    int id = blockIdx.x;
    int bh = ((id & 7) << 2) + ((id >> 3) & 3);  // 4 bh per XCD class
    int qt = id >> 5;                            // 16 q-tiles of 128 rows
    const ushort_t* Qg = Q + ((size_t)bh * L_ + qt * 128) * DH_;
    const ushort_t* Kg = Kx + (size_t)bh * L_ * DH_;
    const ushort_t* Vg = Vt + (size_t)bh * DH_ * L_;
    int tid = threadIdx.x, wave = tid >> 6, lane = tid & 63;
    int quad = lane >> 4, lc = lane & 15;
    int sw = lc & 7;
    int srow = lane >> 3, sg = lane & 7;

    // staging: waves 0-3 stage K (16 chunks, sig-permuted rows); waves 4-7
    // stage V (16 chunks); 4 chunks per wave
    const ushort_t* stp[4];
    ushort_t* stl[4];
    int stinc;
    if (wave < 4) {
        stinc = 128 * DH_;
#pragma unroll
        for (int i = 0; i < 4; ++i) {
            int chunk = wave * 4 + i;            // 0..15
            int slot = chunk * 8 + srow;         // LDS row (slot)
            int s5 = slot & 31;                  // within-32 position
            int sig = (slot & ~31) + ((s5 & 15) >> 2) * 8 + (s5 & 3) + (s5 >> 4) * 4;
            stp[i] = Kg + (size_t)sig * DH_ + (sg ^ srow) * 8;
            stl[i] = &Ks[chunk * 512 + lane * 8];
        }
    } else {
        stinc = 128;
#pragma unroll
        for (int i = 0; i < 4; ++i) {
            int c2 = (wave - 4) * 4 + i;         // 0..15
            int row = c2 * 4 + (lane >> 4);
            int g = (lane & 15) ^ (row & 15);
            stp[i] = Vg + (size_t)row * L_ + g * 8;
            stl[i] = &Vs[c2 * 512 + lane * 8];
        }
    }

    // Q fragments straight from global (block-private, read once); wave owns
    // q-rows [wave*16, wave*16+16)
    const ushort_t* qp = Qg + (size_t)(wave * 16 + lc) * DH_ + quad * 8;
    bf16x8 q0 = *(const bf16x8*)(qp);        // kk0: dh 0..31 (quad-sliced)
    bf16x8 q1 = *(const bf16x8*)(qp + 32);   // kk1: dh 32..63

    // all-ones bf16 B operand for MFMA row-sums (1.0bf16 = 0x3F80)
    union { u32 u[4]; bf16x8 v; } ones;
    ones.u[0] = ones.u[1] = ones.u[2] = ones.u[3] = 0x3F803F80u;

    f32x4 o0 = {}, o1 = {}, o2 = {}, o3 = {};
    f32x4 osum = {};   // rowsum accumulator (cols redundant)

    for (int t = 0; t < 16; ++t) {
#pragma unroll
        for (int i = 0; i < 4; ++i) { llds16(stp[i], stl[i]); stp[i] += stinc; }
        __syncthreads();

        // S^T = K Q^T: C[slot][q], lane holds q=lc, slot = ni*16 + quad*4 + r;
        // via sig-permuted staging, slot maps to kv so that lane-local packed
        // values form the PV A-fragment directly.
        f32x4 s[8];
        __builtin_amdgcn_s_setprio(1);
#pragma unroll
        for (int kk = 0; kk < 2; ++kk) {
            int off = ((kk * 4 + quad) ^ sw) * 8;
            bf16x8 aq = kk == 0 ? q0 : q1;
#pragma unroll
            for (int ni = 0; ni < 8; ++ni) {
                bf16x8 bk = *(const bf16x8*)&Ks[(ni * 16 + lc) * 64 + off];
                if (kk == 0) {
                    f32x4 z = {0.f, 0.f, 0.f, 0.f};
                    s[ni] = MFMA(bk, aq, z, 0, 0, 0);
                } else {
                    s[ni] = MFMA(bk, aq, s[ni], 0, 0, 0);
                }
            }
        }
        __builtin_amdgcn_s_setprio(0);

        // softmax numerator: p = exp2(s), pack to bf16 pairs in regs
        u32 px[8], py[8];
#pragma unroll
        for (int ni = 0; ni < 8; ++ni) {
            float p0 = __builtin_amdgcn_exp2f(s[ni][0]);
            float p1 = __builtin_amdgcn_exp2f(s[ni][1]);
            float p2 = __builtin_amdgcn_exp2f(s[ni][2]);
            float p3 = __builtin_amdgcn_exp2f(s[ni][3]);
            px[ni] = pk_bf16(p0, p1);
            py[ni] = pk_bf16(p2, p3);
        }

        // PV: A-fragment for kv-chunk kk is {px[2kk],py[2kk],px[2kk+1],py[2kk+1]}
        // (lane-local, thanks to sig). Rowsum rides the same A-fragment.
        __builtin_amdgcn_s_setprio(1);
#pragma unroll
        for (int kk = 0; kk < 4; ++kk) {
            int gq = kk * 4 + quad;
            bf16x8 bv0 = *(const bf16x8*)&Vs[( 0 + lc) * 128 + ((gq ^ lc) * 8)];
            bf16x8 bv1 = *(const bf16x8*)&Vs[(16 + lc) * 128 + ((gq ^ lc) * 8)];
            bf16x8 bv2 = *(const bf16x8*)&Vs[(32 + lc) * 128 + ((gq ^ lc) * 8)];
            bf16x8 bv3 = *(const bf16x8*)&Vs[(48 + lc) * 128 + ((gq ^ lc) * 8)];
            union { u32 u[4]; bf16x8 v; } a;
            a.u[0] = px[2 * kk]; a.u[1] = py[2 * kk];
            a.u[2] = px[2 * kk + 1]; a.u[3] = py[2 * kk + 1];
            o0 = MFMA(a.v, bv0, o0, 0, 0, 0); o1 = MFMA(a.v, bv1, o1, 0, 0, 0);
            o2 = MFMA(a.v, bv2, o2, 0, 0, 0); o3 = MFMA(a.v, bv3, o3, 0, 0, 0);
            osum = MFMA(a.v, ones.v, osum, 0, 0, 0);
        }
        __builtin_amdgcn_s_setprio(0);
        __syncthreads();  // Ks/Vs consumed before next tile's staging
    }

    // normalize in-register (rowsum identical across lc lanes) and write final
    // O bf16 in (BH, L, DH) "mix" layout; PV C-layout rows = quad*4+r
    f32x4 inv;
#pragma unroll
    for (int r = 0; r < 4; ++r) inv[r] = 1.f / osum[r];
#pragma unroll
    for (int nio = 0; nio < 4; ++nio) {
        const f32x4& ov = nio == 0 ? o0 : nio == 1 ? o1 : nio == 2 ? o2 : o3;
#pragma unroll
        for (int r = 0; r < 4; ++r) {
            int row = qt * 128 + wave * 16 + quad * 4 + r;
            O[((size_t)bh * L_ + row) * DH_ + nio * 16 + lc] = f2bf(ov[r] * inv[r]);
        }
    }
}

// -----------------------------------------------------------------------------
extern "C" void kernel_launch(void* const* d_in, const int* in_sizes, int n_in,
                              void* d_out, int out_size, void* d_ws, size_t ws_size,
                              hipStream_t stream) {
    (void)in_sizes; (void)n_in; (void)out_size; (void)ws_size;
    const float* x    = (const float*)d_in[0];
    const float* c    = (const float*)d_in[1];
    const float* Wq   = (const float*)d_in[2];
    const float* bq   = (const float*)d_in[3];
    const float* Wk   = (const float*)d_in[4];
    const float* bk   = (const float*)d_in[5];
    const float* Wv   = (const float*)d_in[6];
    const float* bv   = (const float*)d_in[7];
    const float* Wo   = (const float*)d_in[8];
    const float* bo   = (const float*)d_in[9];
    const float* W1   = (const float*)d_in[10];
    const float* b1   = (const float*)d_in[11];
    const float* W2   = (const float*)d_in[12];
    const float* b2   = (const float*)d_in[13];
    const float* Wada = (const float*)d_in[14];
    const float* bada = (const float*)d_in[15];

    char* w = (char*)d_ws;
    float*    ada  = (float*)(w + 0);                     // 49152 B
    ushort_t* Wqkv = (ushort_t*)(w + 49152);              // 6 MiB
    ushort_t* Wo_t = (ushort_t*)(w + 6340608);            // 2 MiB
    ushort_t* W1_t = (ushort_t*)(w + 8437760);            // 4 MiB
    ushort_t* W2_t = (ushort_t*)(w + 12632064);           // 4 MiB
    ushort_t* h    = (ushort_t*)(w + 16826368);           // 8 MiB (h / h2)
    ushort_t* Qb   = (ushort_t*)(w + 25214976);           // 8 MiB (Q)
    ushort_t* Kb   = (ushort_t*)(w + 33603584);           // 8 MiB (K)
    ushort_t* Ob   = (ushort_t*)(w + 41992192);           // 8 MiB (final O)
    ushort_t* Vtb  = (ushort_t*)(w + 50380800);           // 8 MiB (ada partials, then V^T)
    float*    x1   = (float*)(w + 58769408);              // 16 MiB (x1)
    ushort_t* m1   = Qb;            // MLP hidden (16 MiB = Qb+Kb, dead post-attn)
    float*    adap = (float*)Vtb;   // 786 KB split-k partials; dead before QKV gemm

    const int M = B_ * L_;  // 4096

    transpose_w_all<<<2048, 256, 0, stream>>>(Wq, Wk, Wv, Wo, W1, W2,
                                              Wqkv, Wo_t, W1_t, W2_t);

    ada_gemv<<<dim3(24, 16), 256, 0, stream>>>(c, Wada, adap);
    ada_reduce<<<24, 256, 0, stream>>>(adap, bada, ada);
    ln_mod<<<M, 256, 0, stream>>>(x, ada, 0, 1024, h);

    // QKV: Q,K -> (B,H,L,DH); V -> V^T (BH,DH,L) directly (transpose_v fused)
    EpiArgs e0 = {bq, bk, bv, Qb, Kb, Vtb, nullptr, nullptr, nullptr};
    gemm_bt<0><<<dim3(32, 24), 256, 0, stream>>>(h, Wqkv, M, 3072, D_, e0);

    // full-KV attention: final O, no partials, no merge; 8-wave blocks
    attn<<<512, 512, 0, stream>>>(Qb, Kb, Vtb, Ob);

    EpiArgs e1 = {bo, nullptr, nullptr, nullptr, nullptr, nullptr, x, ada + 2048, x1};
    gemm_bt64<2><<<dim3(64, 8), 256, 0, stream>>>(Ob, Wo_t, M, D_, D_, e1);

    ln_mod<<<M, 256, 0, stream>>>(x1, ada, 3072, 4096, h);

    EpiArgs e2 = {b1, nullptr, nullptr, m1, nullptr, nullptr, nullptr, nullptr, nullptr};
    gemm_bt64<1><<<dim3(64, 16), 256, 0, stream>>>(h, W1_t, M, FF_, D_, e2);

    EpiArgs e3 = {b2, nullptr, nullptr, nullptr, nullptr, nullptr, x1, ada + 5120, (float*)d_out};
    gemm_bt64<2><<<dim3(64, 8), 256, 0, stream>>>(m1, W2_t, M, D_, FF_, e3);
}

// Round 6
// 303.674 us; speedup vs baseline: 1.1164x; 1.0182x over previous
//
#include <hip/hip_runtime.h>
#include <hip/hip_bf16.h>

typedef unsigned short ushort_t;
typedef __bf16 bf16x8 __attribute__((ext_vector_type(8)));
typedef float f32x4 __attribute__((ext_vector_type(4)));

typedef unsigned int u32;
typedef u32 __attribute__((address_space(1))) global_u32;
typedef u32 __attribute__((address_space(3))) lds_u32;

#define D_ 1024
#define L_ 2048
#define B_ 2
#define H_ 16
#define DH_ 64
#define FF_ 2048
#define ADA_ 6144
#define BHL_ (B_ * H_ * L_)

#define MFMA __builtin_amdgcn_mfma_f32_16x16x32_bf16

__device__ __forceinline__ ushort_t f2bf(float f) {
    union { float f; u32 u; } v; v.f = f;
    u32 r = v.u + 0x7fffu + ((v.u >> 16) & 1u);
    return (ushort_t)(r >> 16);
}

// packed 2xf32 -> 2xbf16 (v_cvt_pk_bf16_f32)
__device__ __forceinline__ u32 pk_bf16(float a, float b) {
    float2 f; f.x = a; f.y = b;
    __hip_bfloat162 t = __float22bfloat162_rn(f);
    union { __hip_bfloat162 b2; u32 u; } v; v.b2 = t; return v.u;
}

__device__ __forceinline__ void llds16(const ushort_t* src, ushort_t* dst) {
    __builtin_amdgcn_global_load_lds((global_u32*)src, (lds_u32*)dst, 16, 0, 0);
}

// ------- fused weight transpose+convert: all 6 weights, one dispatch ---------
__global__ void transpose_w_all(
    const float* __restrict__ Wq, const float* __restrict__ Wk,
    const float* __restrict__ Wv, const float* __restrict__ Wo,
    const float* __restrict__ W1, const float* __restrict__ W2,
    ushort_t* __restrict__ Wqkv, ushort_t* __restrict__ Wo_t,
    ushort_t* __restrict__ W1_t, ushort_t* __restrict__ W2_t) {
    __shared__ float tile[64][65];
    int id = blockIdx.x;
    const float* W; ushort_t* Wt; int K, N, ntx, lid;
    if (id < 1024) {
        int which = id >> 8; lid = id & 255; K = 1024; N = 1024; ntx = 16;
        W  = which == 0 ? Wq : which == 1 ? Wk : which == 2 ? Wv : Wo;
        Wt = which == 3 ? Wo_t : Wqkv + (size_t)which * 1024 * 1024;
    } else if (id < 1536) {
        lid = id - 1024; W = W1; Wt = W1_t; K = 1024; N = 2048; ntx = 32;
    } else {
        lid = id - 1536; W = W2; Wt = W2_t; K = 2048; N = 1024; ntx = 16;
    }
    int n0 = (lid % ntx) * 64, k0 = (lid / ntx) * 64;
    int t = threadIdx.x;
    for (int p = 0; p < 4; ++p) {
        int k = p * 16 + (t >> 4), nn = (t & 15) * 4;
        float4 v = *(const float4*)(W + (size_t)(k0 + k) * N + n0 + nn);
        tile[k][nn] = v.x; tile[k][nn + 1] = v.y; tile[k][nn + 2] = v.z; tile[k][nn + 3] = v.w;
    }
    __syncthreads();
    for (int p = 0; p < 4; ++p) {
        int n = p * 16 + (t >> 4), kk = (t & 15) * 4;
        ushort4 o;
        o.x = f2bf(tile[kk][n]); o.y = f2bf(tile[kk + 1][n]);
        o.z = f2bf(tile[kk + 2][n]); o.w = f2bf(tile[kk + 3][n]);
        *(ushort4*)(Wt + (size_t)(n0 + n) * K + k0 + kk) = o;
    }
}

// ---------------- ada = silu(c) @ Wada + bada: split-k GEMV ------------------
__global__ void ada_gemv(const float* __restrict__ c, const float* __restrict__ Wada,
                         float* __restrict__ partial) {
    int ks = blockIdx.y;
    int j = blockIdx.x * 256 + threadIdx.x;
    __shared__ float s0[64], s1[64];
    if (threadIdx.x < 64) {
        float v = c[ks * 64 + threadIdx.x];
        s0[threadIdx.x] = v / (1.f + __expf(-v));
        v = c[D_ + ks * 64 + threadIdx.x];
        s1[threadIdx.x] = v / (1.f + __expf(-v));
    }
    __syncthreads();
    float a0 = 0.f, a1 = 0.f;
#pragma unroll 8
    for (int d = 0; d < 64; ++d) {
        float w = Wada[(size_t)(ks * 64 + d) * ADA_ + j];
        a0 = fmaf(s0[d], w, a0);
        a1 = fmaf(s1[d], w, a1);
    }
    partial[(size_t)(ks * 2 + 0) * ADA_ + j] = a0;
    partial[(size_t)(ks * 2 + 1) * ADA_ + j] = a1;
}

__global__ void ada_reduce(const float* __restrict__ partial,
                           const float* __restrict__ bada, float* __restrict__ ada) {
    int j = blockIdx.x * 256 + threadIdx.x;
    float a0 = bada[j], a1 = bada[j];
#pragma unroll
    for (int ks = 0; ks < 16; ++ks) {
        a0 += partial[(size_t)(ks * 2 + 0) * ADA_ + j];
        a1 += partial[(size_t)(ks * 2 + 1) * ADA_ + j];
    }
    ada[j] = a0;
    ada[ADA_ + j] = a1;
}

// ---------------- LayerNorm + modulation -> bf16 -----------------------------
__global__ void ln_mod(const float* __restrict__ x, const float* __restrict__ ada,
                       int so, int co, ushort_t* __restrict__ out) {
    int row = blockIdx.x;
    int b = row >> 11;
    float4 v = ((const float4*)(x + (size_t)row * D_))[threadIdx.x];
    float sum = v.x + v.y + v.z + v.w;
    float sq = v.x * v.x + v.y * v.y + v.z * v.z + v.w * v.w;
    for (int off = 32; off; off >>= 1) { sum += __shfl_down(sum, off); sq += __shfl_down(sq, off); }
    __shared__ float sa[4], sb[4];
    int wave = threadIdx.x >> 6, lane = threadIdx.x & 63;
    if (lane == 0) { sa[wave] = sum; sb[wave] = sq; }
    __syncthreads();
    sum = sa[0] + sa[1] + sa[2] + sa[3];
    sq = sb[0] + sb[1] + sb[2] + sb[3];
    float mean = sum * (1.f / 1024.f);
    float var = sq * (1.f / 1024.f) - mean * mean;
    float rstd = rsqrtf(var + 1e-6f);
    int d = threadIdx.x * 4;
    const float* shf = ada + (size_t)b * ADA_ + so;
    const float* scf = ada + (size_t)b * ADA_ + co;
    uint2 ov;
    ov.x = pk_bf16((v.x - mean) * rstd * (1.f + scf[d + 0]) + shf[d + 0],
                   (v.y - mean) * rstd * (1.f + scf[d + 1]) + shf[d + 1]);
    ov.y = pk_bf16((v.z - mean) * rstd * (1.f + scf[d + 2]) + shf[d + 2],
                   (v.w - mean) * rstd * (1.f + scf[d + 3]) + shf[d + 3]);
    *(uint2*)(out + (size_t)row * D_ + d) = ov;
}

// ---------------- GEMM epilogues ---------------------------------------------
struct EpiArgs {
    const float* bias0; const float* bias1; const float* bias2;
    ushort_t* o0; ushort_t* o1; ushort_t* o2;
    const float* resid; const float* gate;
    float* fout;
};

template <int EPI>
__device__ __forceinline__ void epi_store(float v, int m, int n, int N, const EpiArgs& e) {
    if (EPI == 0) {  // Q/K -> (B,H,L,DH) bf16; Q pre-scaled by log2(e)/8
        int which = n >> 10, cc = n & 1023;
        const float* bias = which == 0 ? e.bias0 : e.bias1;
        ushort_t* ob = which == 0 ? e.o0 : e.o1;
        v += bias[cc];
        if (which == 0) v *= 0.18033688f;  // (1/8) * log2(e): softmax uses exp2
        int b = m >> 11, l = m & 2047, h = cc >> 6, dh = cc & 63;
        ob[(((size_t)(b * H_ + h) * L_) + l) * DH_ + dh] = f2bf(v);
    } else if (EPI == 1) {  // bias + exact GELU -> bf16
        v += e.bias0[n];
        v = 0.5f * v * (1.f + erff(v * 0.70710678118f));
        e.o0[(size_t)m * N + n] = f2bf(v);
    } else {  // residual + gate -> fp32
        int b = m >> 11;
        e.fout[(size_t)m * N + n] =
            e.resid[(size_t)m * N + n] + e.gate[(size_t)b * ADA_ + n] * (v + e.bias0[n]);
    }
}

template <int EPI>
__device__ __forceinline__ void st4(const f32x4& cc, int mb, int n, int N, const EpiArgs& e) {
    if (EPI == 0 && n >= 2048) {
        // V: direct transpose write -> (BH, DH, L) bf16. mb..mb+3 are 4
        // consecutive l within one batch -> contiguous ushort4 in V^T.
        int ccn = n & 1023;
        float b4 = e.bias2[ccn];
        int b = mb >> 11, l0 = mb & 2047, h = ccn >> 6, dh = ccn & 63;
        ushort4 o;
        o.x = f2bf(cc[0] + b4); o.y = f2bf(cc[1] + b4);
        o.z = f2bf(cc[2] + b4); o.w = f2bf(cc[3] + b4);
        *(ushort4*)(e.o2 + ((size_t)(b * H_ + h) * DH_ + dh) * L_ + l0) = o;
        return;
    }
#pragma unroll
    for (int r = 0; r < 4; ++r) epi_store<EPI>(cc[r], mb + r, n, N, e);
}

// ---------------- GEMM 128x128 tile (QKV) ------------------------------------
template <int EPI>
__global__ __launch_bounds__(256, 2) void gemm_bt(
    const ushort_t* __restrict__ A, const ushort_t* __restrict__ Bt,
    int M, int N, int K, EpiArgs e) {
    __shared__ ushort_t As[128 * 64];
    __shared__ ushort_t Bs[128 * 64];
    int m0 = blockIdx.x * 128, n0 = blockIdx.y * 128;
    int tid = threadIdx.x, wave = tid >> 6, lane = tid & 63;
    int quad = lane >> 4, lc = lane & 15;
    int wm = (wave & 1) * 64, wn = (wave >> 1) * 64;
    int srow = lane >> 3, sg = lane & 7;
    int sw = lc & 7;

    const ushort_t* stp[8];
    ushort_t* stl[8];
#pragma unroll
    for (int i = 0; i < 8; ++i) {
        int chunk = wave * 8 + i;
        int c = chunk & 15;
        int row = c * 8 + srow;
        stp[i] = (chunk < 16 ? A + (size_t)(m0 + row) * K
                             : Bt + (size_t)(n0 + row) * K) + (sg ^ srow) * 8;
        stl[i] = (chunk < 16 ? As : Bs) + c * 512 + lane * 8;
    }

    f32x4 c00 = {}, c01 = {}, c02 = {}, c03 = {};
    f32x4 c10 = {}, c11 = {}, c12 = {}, c13 = {};
    f32x4 c20 = {}, c21 = {}, c22 = {}, c23 = {};
    f32x4 c30 = {}, c31 = {}, c32 = {}, c33 = {};

    for (int k0 = 0; k0 < K; k0 += 64) {
#pragma unroll
        for (int i = 0; i < 8; ++i) { llds16(stp[i], stl[i]); stp[i] += 64; }
        __syncthreads();
#pragma unroll
        for (int kk = 0; kk < 2; ++kk) {
            int off = ((kk * 4 + quad) ^ sw) * 8;
            bf16x8 a0 = *(const bf16x8*)&As[(wm +  0 + lc) * 64 + off];
            bf16x8 a1 = *(const bf16x8*)&As[(wm + 16 + lc) * 64 + off];
            bf16x8 a2 = *(const bf16x8*)&As[(wm + 32 + lc) * 64 + off];
            bf16x8 a3 = *(const bf16x8*)&As[(wm + 48 + lc) * 64 + off];
            bf16x8 b0 = *(const bf16x8*)&Bs[(wn +  0 + lc) * 64 + off];
            bf16x8 b1 = *(const bf16x8*)&Bs[(wn + 16 + lc) * 64 + off];
            bf16x8 b2 = *(const bf16x8*)&Bs[(wn + 32 + lc) * 64 + off];
            bf16x8 b3 = *(const bf16x8*)&Bs[(wn + 48 + lc) * 64 + off];
            c00 = MFMA(a0, b0, c00, 0, 0, 0); c01 = MFMA(a0, b1, c01, 0, 0, 0);
            c02 = MFMA(a0, b2, c02, 0, 0, 0); c03 = MFMA(a0, b3, c03, 0, 0, 0);
            c10 = MFMA(a1, b0, c10, 0, 0, 0); c11 = MFMA(a1, b1, c11, 0, 0, 0);
            c12 = MFMA(a1, b2, c12, 0, 0, 0); c13 = MFMA(a1, b3, c13, 0, 0, 0);
            c20 = MFMA(a2, b0, c20, 0, 0, 0); c21 = MFMA(a2, b1, c21, 0, 0, 0);
            c22 = MFMA(a2, b2, c22, 0, 0, 0); c23 = MFMA(a2, b3, c23, 0, 0, 0);
            c30 = MFMA(a3, b0, c30, 0, 0, 0); c31 = MFMA(a3, b1, c31, 0, 0, 0);
            c32 = MFMA(a3, b2, c32, 0, 0, 0); c33 = MFMA(a3, b3, c33, 0, 0, 0);
        }
        __syncthreads();
    }

    int mb = m0 + wm + quad * 4, nb = n0 + wn + lc;
    st4<EPI>(c00, mb +  0, nb +  0, N, e); st4<EPI>(c01, mb +  0, nb + 16, N, e);
    st4<EPI>(c02, mb +  0, nb + 32, N, e); st4<EPI>(c03, mb +  0, nb + 48, N, e);
    st4<EPI>(c10, mb + 16, nb +  0, N, e); st4<EPI>(c11, mb + 16, nb + 16, N, e);
    st4<EPI>(c12, mb + 16, nb + 32, N, e); st4<EPI>(c13, mb + 16, nb + 48, N, e);
    st4<EPI>(c20, mb + 32, nb +  0, N, e); st4<EPI>(c21, mb + 32, nb + 16, N, e);
    st4<EPI>(c22, mb + 32, nb + 32, N, e); st4<EPI>(c23, mb + 32, nb + 48, N, e);
    st4<EPI>(c30, mb + 48, nb +  0, N, e); st4<EPI>(c31, mb + 48, nb + 16, N, e);
    st4<EPI>(c32, mb + 48, nb + 32, N, e); st4<EPI>(c33, mb + 48, nb + 48, N, e);
}

// ---------------- GEMM 64x128 tile: small-N GEMMs need more blocks -----------
template <int EPI>
__global__ __launch_bounds__(256, 2) void gemm_bt64(
    const ushort_t* __restrict__ A, const ushort_t* __restrict__ Bt,
    int M, int N, int K, EpiArgs e) {
    __shared__ ushort_t As[64 * 64];    // 8 KB
    __shared__ ushort_t Bs[128 * 64];   // 16 KB
    int m0 = blockIdx.x * 64, n0 = blockIdx.y * 128;
    int tid = threadIdx.x, wave = tid >> 6, lane = tid & 63;
    int quad = lane >> 4, lc = lane & 15;
    int wn = wave * 32;
    int srow = lane >> 3, sg = lane & 7;
    int sw = lc & 7;

    const ushort_t* stp[6];
    ushort_t* stl[6];
#pragma unroll
    for (int i = 0; i < 6; ++i) {
        int chunk = wave * 6 + i;
        if (chunk < 8) {
            int row = chunk * 8 + srow;
            stp[i] = A + (size_t)(m0 + row) * K + (sg ^ srow) * 8;
            stl[i] = &As[chunk * 512 + lane * 8];
        } else {
            int c = chunk - 8;
            int row = c * 8 + srow;
            stp[i] = Bt + (size_t)(n0 + row) * K + (sg ^ srow) * 8;
            stl[i] = &Bs[c * 512 + lane * 8];
        }
    }

    f32x4 c00 = {}, c01 = {};
    f32x4 c10 = {}, c11 = {};
    f32x4 c20 = {}, c21 = {};
    f32x4 c30 = {}, c31 = {};

    for (int k0 = 0; k0 < K; k0 += 64) {
#pragma unroll
        for (int i = 0; i < 6; ++i) { llds16(stp[i], stl[i]); stp[i] += 64; }
        __syncthreads();
#pragma unroll
        for (int kk = 0; kk < 2; ++kk) {
            int off = ((kk * 4 + quad) ^ sw) * 8;
            bf16x8 a0 = *(const bf16x8*)&As[( 0 + lc) * 64 + off];
            bf16x8 a1 = *(const bf16x8*)&As[(16 + lc) * 64 + off];
            bf16x8 a2 = *(const bf16x8*)&As[(32 + lc) * 64 + off];
            bf16x8 a3 = *(const bf16x8*)&As[(48 + lc) * 64 + off];
            bf16x8 b0 = *(const bf16x8*)&Bs[(wn +  0 + lc) * 64 + off];
            bf16x8 b1 = *(const bf16x8*)&Bs[(wn + 16 + lc) * 64 + off];
            c00 = MFMA(a0, b0, c00, 0, 0, 0); c01 = MFMA(a0, b1, c01, 0, 0, 0);
            c10 = MFMA(a1, b0, c10, 0, 0, 0); c11 = MFMA(a1, b1, c11, 0, 0, 0);
            c20 = MFMA(a2, b0, c20, 0, 0, 0); c21 = MFMA(a2, b1, c21, 0, 0, 0);
            c30 = MFMA(a3, b0, c30, 0, 0, 0); c31 = MFMA(a3, b1, c31, 0, 0, 0);
        }
        __syncthreads();
    }

    int mb = m0 + quad * 4, nb = n0 + wn + lc;
    st4<EPI>(c00, mb +  0, nb + 0, N, e); st4<EPI>(c01, mb +  0, nb + 16, N, e);
    st4<EPI>(c10, mb + 16, nb + 0, N, e); st4<EPI>(c11, mb + 16, nb + 16, N, e);
    st4<EPI>(c20, mb + 32, nb + 0, N, e); st4<EPI>(c21, mb + 32, nb + 16, N, e);
    st4<EPI>(c30, mb + 48, nb + 0, N, e); st4<EPI>(c31, mb + 48, nb + 16, N, e);
}

// ---------------- flash attention v15: dbuf K/V + counted vmcnt --------------
// grid 512: bits[4:0] bh (XCD-spread), [8:5] q-tile. 512 threads (8 waves),
// 128 q-rows x full 2048 kv (16 tiles). v15 vs v14: double-buffered K/V
// (LDS 32->64 KB, still 2 blocks/CU); tile t+1's 4 global_load_lds per lane
// are issued BEFORE tile t's compute, and the data-ready barrier uses a
// counted s_waitcnt vmcnt(4) (each wave waits only its own tile-t loads; the
// 4 newest stay in flight across the barrier). This removes the vmcnt(0)
// drain that __syncthreads imposed -- the exposed HBM/L2 latency (~900 cyc/
// tile) that made v13 (4w) and v14 (8w) land at identical 46.8 us.
__global__ __launch_bounds__(512, 4) void attn(
    const ushort_t* __restrict__ Q, const ushort_t* __restrict__ Kx,
    const ushort_t* __restrict__ Vt, ushort_t* __restrict__ O) {
    __shared__ ushort_t Ks[2][128 * 64];  // 2 x 16 KB
    __shared__ ushort_t Vs[2][64 * 128];  // 2 x 16 KB
    int id = blockIdx.x;
    int bh = ((id & 7) << 2) + ((id >> 3) & 3);  // 4 bh per XCD class
    int qt = id >> 5;                            // 16 q-tiles of 128 rows
    const ushort_t* Qg = Q + ((size_t)bh * L_ + qt * 128) * DH_;
    const ushort_t* Kg = Kx + (size_t)bh * L_ * DH_;
    const ushort_t* Vg = Vt + (size_t)bh * DH_ * L_;
    int tid = threadIdx.x, wave = tid >> 6, lane = tid & 63;
    int quad = lane >> 4, lc = lane & 15;
    int sw = lc & 7;
    int srow = lane >> 3, sg = lane & 7;

    // staging: waves 0-3 stage K (16 chunks, sig-permuted rows); waves 4-7
    // stage V (16 chunks); 4 chunks per wave
    const ushort_t* stp[4];
    ushort_t* stl[4];
    int stinc;
    if (wave < 4) {
        stinc = 128 * DH_;
#pragma unroll
        for (int i = 0; i < 4; ++i) {
            int chunk = wave * 4 + i;            // 0..15
            int slot = chunk * 8 + srow;         // LDS row (slot)
            int s5 = slot & 31;                  // within-32 position
            int sig = (slot & ~31) + ((s5 & 15) >> 2) * 8 + (s5 & 3) + (s5 >> 4) * 4;
            stp[i] = Kg + (size_t)sig * DH_ + (sg ^ srow) * 8;
            stl[i] = &Ks[0][chunk * 512 + lane * 8];
        }
    } else {
        stinc = 128;
#pragma unroll
        for (int i = 0; i < 4; ++i) {
            int c2 = (wave - 4) * 4 + i;         // 0..15
            int row = c2 * 4 + (lane >> 4);
            int g = (lane & 15) ^ (row & 15);
            stp[i] = Vg + (size_t)row * L_ + g * 8;
            stl[i] = &Vs[0][c2 * 512 + lane * 8];
        }
    }

    // prologue: stage tile 0 into buf 0 (in flight under the Q loads below)
#pragma unroll
    for (int i = 0; i < 4; ++i) { llds16(stp[i], stl[i]); stp[i] += stinc; }

    // Q fragments straight from global (block-private, read once); wave owns
    // q-rows [wave*16, wave*16+16)
    const ushort_t* qp = Qg + (size_t)(wave * 16 + lc) * DH_ + quad * 8;
    bf16x8 q0 = *(const bf16x8*)(qp);        // kk0: dh 0..31 (quad-sliced)
    bf16x8 q1 = *(const bf16x8*)(qp + 32);   // kk1: dh 32..63

    // all-ones bf16 B operand for MFMA row-sums (1.0bf16 = 0x3F80)
    union { u32 u[4]; bf16x8 v; } ones;
    ones.u[0] = ones.u[1] = ones.u[2] = ones.u[3] = 0x3F803F80u;

    f32x4 o0 = {}, o1 = {}, o2 = {}, o3 = {};
    f32x4 osum = {};   // rowsum accumulator (cols redundant)

    for (int t = 0; t < 16; ++t) {
        // issue tile t+1 into the other buffer, then wait only for tile t's
        // 4 loads (the 4 newest stay outstanding across the barrier)
        if (t < 15) {
            int nbuf = (t + 1) & 1;
#pragma unroll
            for (int i = 0; i < 4; ++i) { llds16(stp[i], stl[i] + nbuf * 8192); stp[i] += stinc; }
            asm volatile("s_waitcnt vmcnt(4)" ::: "memory");
        } else {
            asm volatile("s_waitcnt vmcnt(0)" ::: "memory");
        }
        __builtin_amdgcn_s_barrier();
        asm volatile("" ::: "memory");
        const ushort_t* Ksb = &Ks[t & 1][0];
        const ushort_t* Vsb = &Vs[t & 1][0];

        // S^T = K Q^T: C[slot][q], lane holds q=lc, slot = ni*16 + quad*4 + r;
        // via sig-permuted staging, slot maps to kv so that lane-local packed
        // values form the PV A-fragment directly.
        f32x4 s[8];
        __builtin_amdgcn_s_setprio(1);
#pragma unroll
        for (int kk = 0; kk < 2; ++kk) {
            int off = ((kk * 4 + quad) ^ sw) * 8;
            bf16x8 aq = kk == 0 ? q0 : q1;
#pragma unroll
            for (int ni = 0; ni < 8; ++ni) {
                bf16x8 bk = *(const bf16x8*)&Ksb[(ni * 16 + lc) * 64 + off];
                if (kk == 0) {
                    f32x4 z = {0.f, 0.f, 0.f, 0.f};
                    s[ni] = MFMA(bk, aq, z, 0, 0, 0);
                } else {
                    s[ni] = MFMA(bk, aq, s[ni], 0, 0, 0);
                }
            }
        }
        __builtin_amdgcn_s_setprio(0);

        // softmax numerator: p = exp2(s), pack to bf16 pairs in regs
        u32 px[8], py[8];
#pragma unroll
        for (int ni = 0; ni < 8; ++ni) {
            float p0 = __builtin_amdgcn_exp2f(s[ni][0]);
            float p1 = __builtin_amdgcn_exp2f(s[ni][1]);
            float p2 = __builtin_amdgcn_exp2f(s[ni][2]);
            float p3 = __builtin_amdgcn_exp2f(s[ni][3]);
            px[ni] = pk_bf16(p0, p1);
            py[ni] = pk_bf16(p2, p3);
        }

        // PV: A-fragment for kv-chunk kk is {px[2kk],py[2kk],px[2kk+1],py[2kk+1]}
        // (lane-local, thanks to sig). Rowsum rides the same A-fragment.
        __builtin_amdgcn_s_setprio(1);
#pragma unroll
        for (int kk = 0; kk < 4; ++kk) {
            int gq = kk * 4 + quad;
            bf16x8 bv0 = *(const bf16x8*)&Vsb[( 0 + lc) * 128 + ((gq ^ lc) * 8)];
            bf16x8 bv1 = *(const bf16x8*)&Vsb[(16 + lc) * 128 + ((gq ^ lc) * 8)];
            bf16x8 bv2 = *(const bf16x8*)&Vsb[(32 + lc) * 128 + ((gq ^ lc) * 8)];
            bf16x8 bv3 = *(const bf16x8*)&Vsb[(48 + lc) * 128 + ((gq ^ lc) * 8)];
            union { u32 u[4]; bf16x8 v; } a;
            a.u[0] = px[2 * kk]; a.u[1] = py[2 * kk];
            a.u[2] = px[2 * kk + 1]; a.u[3] = py[2 * kk + 1];
            o0 = MFMA(a.v, bv0, o0, 0, 0, 0); o1 = MFMA(a.v, bv1, o1, 0, 0, 0);
            o2 = MFMA(a.v, bv2, o2, 0, 0, 0); o3 = MFMA(a.v, bv3, o3, 0, 0, 0);
            osum = MFMA(a.v, ones.v, osum, 0, 0, 0);
        }
        __builtin_amdgcn_s_setprio(0);
        // all waves done reading buf[t&1] before it is restaged at t+2
        asm volatile("" ::: "memory");
        __builtin_amdgcn_s_barrier();
    }

    // normalize in-register (rowsum identical across lc lanes) and write final
    // O bf16 in (BH, L, DH) "mix" layout; PV C-layout rows = quad*4+r
    f32x4 inv;
#pragma unroll
    for (int r = 0; r < 4; ++r) inv[r] = 1.f / osum[r];
#pragma unroll
    for (int nio = 0; nio < 4; ++nio) {
        const f32x4& ov = nio == 0 ? o0 : nio == 1 ? o1 : nio == 2 ? o2 : o3;
#pragma unroll
        for (int r = 0; r < 4; ++r) {
            int row = qt * 128 + wave * 16 + quad * 4 + r;
            O[((size_t)bh * L_ + row) * DH_ + nio * 16 + lc] = f2bf(ov[r] * inv[r]);
        }
    }
}

// -----------------------------------------------------------------------------
extern "C" void kernel_launch(void* const* d_in, const int* in_sizes, int n_in,
                              void* d_out, int out_size, void* d_ws, size_t ws_size,
                              hipStream_t stream) {
    (void)in_sizes; (void)n_in; (void)out_size; (void)ws_size;
    const float* x    = (const float*)d_in[0];
    const float* c    = (const float*)d_in[1];
    const float* Wq   = (const float*)d_in[2];
    const float* bq   = (const float*)d_in[3];
    const float* Wk   = (const float*)d_in[4];
    const float* bk   = (const float*)d_in[5];
    const float* Wv   = (const float*)d_in[6];
    const float* bv   = (const float*)d_in[7];
    const float* Wo   = (const float*)d_in[8];
    const float* bo   = (const float*)d_in[9];
    const float* W1   = (const float*)d_in[10];
    const float* b1   = (const float*)d_in[11];
    const float* W2   = (const float*)d_in[12];
    const float* b2   = (const float*)d_in[13];
    const float* Wada = (const float*)d_in[14];
    const float* bada = (const float*)d_in[15];

    char* w = (char*)d_ws;
    float*    ada  = (float*)(w + 0);                     // 49152 B
    ushort_t* Wqkv = (ushort_t*)(w + 49152);              // 6 MiB
    ushort_t* Wo_t = (ushort_t*)(w + 6340608);            // 2 MiB
    ushort_t* W1_t = (ushort_t*)(w + 8437760);            // 4 MiB
    ushort_t* W2_t = (ushort_t*)(w + 12632064);           // 4 MiB
    ushort_t* h    = (ushort_t*)(w + 16826368);           // 8 MiB (h / h2)
    ushort_t* Qb   = (ushort_t*)(w + 25214976);           // 8 MiB (Q)
    ushort_t* Kb   = (ushort_t*)(w + 33603584);           // 8 MiB (K)
    ushort_t* Ob   = (ushort_t*)(w + 41992192);           // 8 MiB (final O)
    ushort_t* Vtb  = (ushort_t*)(w + 50380800);           // 8 MiB (ada partials, then V^T)
    float*    x1   = (float*)(w + 58769408);              // 16 MiB (x1)
    ushort_t* m1   = Qb;            // MLP hidden (16 MiB = Qb+Kb, dead post-attn)
    float*    adap = (float*)Vtb;   // 786 KB split-k partials; dead before QKV gemm

    const int M = B_ * L_;  // 4096

    transpose_w_all<<<2048, 256, 0, stream>>>(Wq, Wk, Wv, Wo, W1, W2,
                                              Wqkv, Wo_t, W1_t, W2_t);

    ada_gemv<<<dim3(24, 16), 256, 0, stream>>>(c, Wada, adap);
    ada_reduce<<<24, 256, 0, stream>>>(adap, bada, ada);
    ln_mod<<<M, 256, 0, stream>>>(x, ada, 0, 1024, h);

    // QKV: Q,K -> (B,H,L,DH); V -> V^T (BH,DH,L) directly (transpose_v fused)
    EpiArgs e0 = {bq, bk, bv, Qb, Kb, Vtb, nullptr, nullptr, nullptr};
    gemm_bt<0><<<dim3(32, 24), 256, 0, stream>>>(h, Wqkv, M, 3072, D_, e0);

    // full-KV attention: final O, no partials, no merge; 8-wave dbuf blocks
    attn<<<512, 512, 0, stream>>>(Qb, Kb, Vtb, Ob);

    EpiArgs e1 = {bo, nullptr, nullptr, nullptr, nullptr, nullptr, x, ada + 2048, x1};
    gemm_bt64<2><<<dim3(64, 8), 256, 0, stream>>>(Ob, Wo_t, M, D_, D_, e1);

    ln_mod<<<M, 256, 0, stream>>>(x1, ada, 3072, 4096, h);

    EpiArgs e2 = {b1, nullptr, nullptr, m1, nullptr, nullptr, nullptr, nullptr, nullptr};
    gemm_bt64<1><<<dim3(64, 16), 256, 0, stream>>>(h, W1_t, M, FF_, D_, e2);

    EpiArgs e3 = {b2, nullptr, nullptr, nullptr, nullptr, nullptr, x1, ada + 5120, (float*)d_out};
    gemm_bt64<2><<<dim3(64, 8), 256, 0, stream>>>(m1, W2_t, M, D_, FF_, e3);
}